// Round 16
// 288.526 us; speedup vs baseline: 5.6630x; 1.0661x over previous
//
#include <hip/hip_runtime.h>
#include <hip/hip_bf16.h>

using bf16 = __hip_bfloat16;
using bf16x8 = __attribute__((ext_vector_type(8))) short;  // 8 bf16 (4 VGPRs)
using f32x4 = __attribute__((ext_vector_type(4))) float;

#define B_ 2
#define T_ 2048
#define C_ 1024
#define BT_ (B_*T_)
#define H_ 16
#define N_ 64
#define LCH 32            // scan chunk length
#define NCH (T_/LCH)      // 64 chunks per head
#define CHD (B_*H_*NCH)   // 2048 chunk-heads

__device__ __forceinline__ float allred64(float v) {
#pragma unroll
  for (int m = 1; m < 64; m <<= 1) v += __shfl_xor(v, m, 64);
  return v;
}

__device__ __forceinline__ bf16 tobf(float f) { return __float2bfloat16(f); }
__device__ __forceinline__ float frombf(bf16 b) { return __bfloat162float(b); }
__device__ __forceinline__ float bf2f(unsigned short u) {
  unsigned int x = ((unsigned int)u) << 16;
  return __builtin_bit_cast(float, x);
}
__device__ __forceinline__ unsigned short bfbits(float f) {
  return __builtin_bit_cast(unsigned short, __float2bfloat16(f));
}
__device__ __forceinline__ float rdlane(float v, int m) {
  return __builtin_bit_cast(float,
      __builtin_amdgcn_readlane(__builtin_bit_cast(int, v), m));
}
// overflow-safe fast tanh via hardware exp (<=4 ulp; outputs bf16-rounded)
__device__ __forceinline__ float fast_tanh(float x) {
  float t = __expf(-2.f * fabsf(x));
  float r = (1.f - t) / (1.f + t);
  return copysignf(r, x);
}

__device__ __forceinline__ f32x4 mfma16x16x32(bf16x8 a, bf16x8 b, f32x4 c) {
  return __builtin_amdgcn_mfma_f32_16x16x32_bf16(a, b, c, 0, 0, 0);
}

// async global->LDS, 16B per lane (dest = wave-uniform base + lane*16)
typedef const __attribute__((address_space(1))) unsigned int* gas_ptr;
typedef __attribute__((address_space(3))) unsigned int* las_ptr;
__device__ __forceinline__ void gload16(const void* g, void* l) {
  __builtin_amdgcn_global_load_lds((gas_ptr)g, (las_ptr)l, 16, 0, 0);
}

// ---------------- ws_size diagnostic ----------------------------------------
__global__ void ws_diag(float a, float b, float* out) { out[0] = a; out[1] = b; }

// ---------------- weight transpose + bf16 cast (19 jobs, one launch) -------
struct PrepArgs {
  const float* src[19];
  bf16* dst[19];
};
__constant__ int kTR[19] = {1024,1024,1024,1024, 1024, 32,32,32,32,32,32,
                            1024,64, 1024,64, 1024,64, 1024,128};
__constant__ int kTC[19] = {1024,1024,1024,1024, 192, 1024,1024,1024,1024,1024,1024,
                            64,1024, 64,1024, 64,1024, 128,1024};

__global__ __launch_bounds__(256) void prep_weights(PrepArgs pa) {
  const int job = blockIdx.y;
  const int R = kTR[job], Cc = kTC[job];
  const int ntx = Cc >> 5, nty = R >> 5;
  const int tile = blockIdx.x;
  if (tile >= ntx * nty) return;
  const int tx = tile % ntx, ty = tile / ntx;
  const float* __restrict__ src = pa.src[job];
  bf16* __restrict__ dst = pa.dst[job];
  __shared__ float tl[32][33];
  const int lx = threadIdx.x & 31, ly = threadIdx.x >> 5;  // 32 x 8
#pragma unroll
  for (int q = 0; q < 4; ++q)
    tl[ly + 8*q][lx] = src[(size_t)(ty*32 + ly + 8*q) * Cc + tx*32 + lx];
  __syncthreads();
#pragma unroll
  for (int q = 0; q < 4; ++q)
    dst[(size_t)(tx*32 + ly + 8*q) * R + ty*32 + lx] = tobf(tl[lx][ly + 8*q]);
}

// ------- GEMM 64-tile -------------------------------------------------------
template<int EPI>
__global__ __launch_bounds__(256) void gemm_bt(
    const bf16* __restrict__ A, int lda,
    const bf16* __restrict__ Bt, int ldb,
    void* __restrict__ Cout, int ldc, int K)
{
  __shared__ short As[64][40];
  __shared__ short Bs[64][40];
  const int bm0 = blockIdx.x * 64;
  const int bn0 = blockIdx.y * 64;
  const int tid = threadIdx.x;
  const int wave = tid >> 6, lane = tid & 63;
  const int lm = lane & 15, kg = lane >> 4;
  const int srow = tid >> 2, scol = (tid & 3) * 8;
  f32x4 acc[4] = {};
  const size_t abase = (size_t)(bm0 + srow) * lda + scol;
  const size_t bbase = (size_t)(bn0 + srow) * ldb + scol;
  for (int k0 = 0; k0 < K; k0 += 32) {
    *(uint4*)&As[srow][scol] = *(const uint4*)(A + abase + k0);
    *(uint4*)&Bs[srow][scol] = *(const uint4*)(Bt + bbase + k0);
    __syncthreads();
    bf16x8 af = *(const bf16x8*)&As[wave*16 + lm][kg*8];
#pragma unroll
    for (int f = 0; f < 4; ++f) {
      bf16x8 bfr = *(const bf16x8*)&Bs[f*16 + lm][kg*8];
      acc[f] = mfma16x16x32(af, bfr, acc[f]);
    }
    __syncthreads();
  }
  const int row0 = bm0 + wave*16 + kg*4;
  const int col0 = bn0 + lm;
#pragma unroll
  for (int f = 0; f < 4; ++f) {
#pragma unroll
    for (int q = 0; q < 4; ++q) {
      float val = acc[f][q];
      size_t o = (size_t)(row0 + q) * ldc + col0 + f*16;
      if (EPI == 0)      ((float*)Cout)[o] = val;
      else if (EPI == 1) ((bf16*)Cout)[o] = tobf(fast_tanh(val));
      else               ((bf16*)Cout)[o] = tobf(val);
    }
  }
}

// ------- batched small projections: k1/d1/a1 (N=64) + g1 (N=128) -----------
struct Proj4Args { const bf16* A[4]; const bf16* Bt[4]; bf16* out[4];
                   int N[4]; int tnh[4]; };
__global__ __launch_bounds__(256) void proj4(Proj4Args p4) {
  const int z = blockIdx.z;
  const int Nn = p4.N[z];
  const int bn0 = blockIdx.y * 64;
  if (bn0 >= Nn) return;
  __shared__ short As[64][40];
  __shared__ short Bs[64][40];
  const bf16* __restrict__ A  = p4.A[z];
  const bf16* __restrict__ Bt = p4.Bt[z];
  bf16* __restrict__ out = p4.out[z];
  const int tnh = p4.tnh[z];
  const int bm0 = blockIdx.x * 64;
  const int tid = threadIdx.x;
  const int wave = tid >> 6, lane = tid & 63;
  const int lm = lane & 15, kg = lane >> 4;
  const int srow = tid >> 2, scol = (tid & 3) * 8;
  f32x4 acc[4] = {};
  const size_t abase = (size_t)(bm0 + srow) * C_ + scol;
  const size_t bbase = (size_t)(bn0 + srow) * C_ + scol;
  for (int k0 = 0; k0 < C_; k0 += 32) {
    *(uint4*)&As[srow][scol] = *(const uint4*)(A + abase + k0);
    *(uint4*)&Bs[srow][scol] = *(const uint4*)(Bt + bbase + k0);
    __syncthreads();
    bf16x8 af = *(const bf16x8*)&As[wave*16 + lm][kg*8];
#pragma unroll
    for (int f = 0; f < 4; ++f) {
      bf16x8 bfr = *(const bf16x8*)&Bs[f*16 + lm][kg*8];
      acc[f] = mfma16x16x32(af, bfr, acc[f]);
    }
    __syncthreads();
  }
  const int row0 = bm0 + wave*16 + kg*4;
  const int col0 = bn0 + lm;
#pragma unroll
  for (int f = 0; f < 4; ++f) {
#pragma unroll
    for (int q = 0; q < 4; ++q) {
      float val = acc[f][q];
      size_t o = (size_t)(row0 + q) * Nn + col0 + f*16;
      out[o] = tobf(tnh ? fast_tanh(val) : val);
    }
  }
}

// ------- GEMM 128-tile, m97 structure (global_load_lds staging) -------------
// EPI: 0 f32 | 2 bf16
template<int EPI>
__global__ __launch_bounds__(256) void gemm128(
    const bf16* __restrict__ A, int lda,
    const bf16* __restrict__ Bt, int ldb,
    void* __restrict__ Cout, int ldc, int K)
{
  __shared__ bf16 As[128][32];     // linear (required by global_load_lds)
  __shared__ bf16 Bs[128][32];
  const int bm0 = blockIdx.x * 128, bn0 = blockIdx.y * 128;
  const int tid = threadIdx.x, wv = tid >> 6, ln = tid & 63;
  const int wr = wv >> 1, wc = wv & 1;
  const int lm = ln & 15, kg = ln >> 4;
  const int srow = ln >> 2, scol = (ln & 3) * 8;
  f32x4 acc[4][4] = {};
  for (int k0 = 0; k0 < K; k0 += 32) {
#pragma unroll
    for (int i = 0; i < 2; ++i) {
      const int r0 = wv*32 + i*16;
      gload16(A  + (size_t)(bm0 + r0 + srow) * lda + k0 + scol, &As[r0][0]);
      gload16(Bt + (size_t)(bn0 + r0 + srow) * ldb + k0 + scol, &Bs[r0][0]);
    }
    asm volatile("s_waitcnt vmcnt(0)" ::: "memory");
    __syncthreads();
    bf16x8 af[4], bfr[4];
#pragma unroll
    for (int m = 0; m < 4; ++m) af[m] = *(const bf16x8*)&As[wr*64 + m*16 + lm][kg*8];
#pragma unroll
    for (int n = 0; n < 4; ++n) bfr[n] = *(const bf16x8*)&Bs[wc*64 + n*16 + lm][kg*8];
#pragma unroll
    for (int m = 0; m < 4; ++m)
#pragma unroll
      for (int n = 0; n < 4; ++n)
        acc[m][n] = mfma16x16x32(af[m], bfr[n], acc[m][n]);
    __syncthreads();
  }
#pragma unroll
  for (int m = 0; m < 4; ++m) {
    const int row0 = bm0 + wr*64 + m*16 + kg*4;
#pragma unroll
    for (int n = 0; n < 4; ++n) {
      const int col = bn0 + wc*64 + n*16 + lm;
#pragma unroll
      for (int q = 0; q < 4; ++q) {
        float val = acc[m][n][q];
        size_t o = (size_t)(row0 + q) * ldc + col;
        if (EPI == 0) ((float*)Cout)[o] = val;
        else          ((bf16*)Cout)[o] = tobf(val);
      }
    }
  }
}

// batched r/k/v: same shape (M=4096, N=1024, K=1024), bf16 outputs
struct RkvArgs { const bf16* A[3]; const bf16* Bt[3]; bf16* Cq[3]; };
__global__ __launch_bounds__(256) void gemm128_rkv(RkvArgs ra) {
  __shared__ bf16 As[128][32];
  __shared__ bf16 Bs[128][32];
  const bf16* __restrict__ A  = ra.A[blockIdx.z];
  const bf16* __restrict__ Bt = ra.Bt[blockIdx.z];
  bf16* __restrict__ Cout = ra.Cq[blockIdx.z];
  const int bm0 = blockIdx.x * 128, bn0 = blockIdx.y * 128;
  const int tid = threadIdx.x, wv = tid >> 6, ln = tid & 63;
  const int wr = wv >> 1, wc = wv & 1;
  const int lm = ln & 15, kg = ln >> 4;
  const int srow = ln >> 2, scol = (ln & 3) * 8;
  f32x4 acc[4][4] = {};
  for (int k0 = 0; k0 < C_; k0 += 32) {
#pragma unroll
    for (int i = 0; i < 2; ++i) {
      const int r0 = wv*32 + i*16;
      gload16(A  + (size_t)(bm0 + r0 + srow) * C_ + k0 + scol, &As[r0][0]);
      gload16(Bt + (size_t)(bn0 + r0 + srow) * C_ + k0 + scol, &Bs[r0][0]);
    }
    asm volatile("s_waitcnt vmcnt(0)" ::: "memory");
    __syncthreads();
    bf16x8 af[4], bfr[4];
#pragma unroll
    for (int m = 0; m < 4; ++m) af[m] = *(const bf16x8*)&As[wr*64 + m*16 + lm][kg*8];
#pragma unroll
    for (int n = 0; n < 4; ++n) bfr[n] = *(const bf16x8*)&Bs[wc*64 + n*16 + lm][kg*8];
#pragma unroll
    for (int m = 0; m < 4; ++m)
#pragma unroll
      for (int n = 0; n < 4; ++n)
        acc[m][n] = mfma16x16x32(af[m], bfr[n], acc[m][n]);
    __syncthreads();
  }
#pragma unroll
  for (int m = 0; m < 4; ++m) {
    const int row0 = bm0 + wr*64 + m*16 + kg*4;
#pragma unroll
    for (int n = 0; n < 4; ++n) {
      const int col = bn0 + wc*64 + n*16 + lm;
#pragma unroll
      for (int q = 0; q < 4; ++q)
        Cout[(size_t)(row0 + q) * C_ + col] = tobf(acc[m][n][q]);
    }
  }
}

// ------- batched epilogue GEMMs: kk-add / w-finalize / a-sigmoid / g --------
// all M=4096, N=1024; K per z; epi: 2=bf16 raw, 4=sigmoid, 5=w-finalize
struct Ep4Args {
  const bf16* A[4]; const bf16* Bt[4]; bf16* Cout[4];
  int K[4]; int epi[4];
  const float* aux[4];          // z1: tdec, z2: aaaaa
  const bf16* kin; bf16* ksout; // z1: unscaled k in, scaled k out
};
__global__ __launch_bounds__(256) void gemm128_ep4(Ep4Args ea) {
  __shared__ bf16 As[128][32];
  __shared__ bf16 Bs[128][32];
  const int z = blockIdx.z;
  const bf16* __restrict__ A  = ea.A[z];
  const bf16* __restrict__ Bt = ea.Bt[z];
  bf16* __restrict__ Cout = ea.Cout[z];
  const int K = ea.K[z], epi = ea.epi[z];
  const float* __restrict__ aux = ea.aux[z];
  const int bm0 = blockIdx.x * 128, bn0 = blockIdx.y * 128;
  const int tid = threadIdx.x, wv = tid >> 6, ln = tid & 63;
  const int wr = wv >> 1, wc = wv & 1;
  const int lm = ln & 15, kg = ln >> 4;
  const int srow = ln >> 2, scol = (ln & 3) * 8;
  f32x4 acc[4][4] = {};
  for (int k0 = 0; k0 < K; k0 += 32) {
#pragma unroll
    for (int i = 0; i < 2; ++i) {
      const int r0 = wv*32 + i*16;
      gload16(A  + (size_t)(bm0 + r0 + srow) * K + k0 + scol, &As[r0][0]);
      gload16(Bt + (size_t)(bn0 + r0 + srow) * K + k0 + scol, &Bs[r0][0]);
    }
    asm volatile("s_waitcnt vmcnt(0)" ::: "memory");
    __syncthreads();
    bf16x8 af[4], bfr[4];
#pragma unroll
    for (int m = 0; m < 4; ++m) af[m] = *(const bf16x8*)&As[wr*64 + m*16 + lm][kg*8];
#pragma unroll
    for (int n = 0; n < 4; ++n) bfr[n] = *(const bf16x8*)&Bs[wc*64 + n*16 + lm][kg*8];
#pragma unroll
    for (int m = 0; m < 4; ++m)
#pragma unroll
      for (int n = 0; n < 4; ++n)
        acc[m][n] = mfma16x16x32(af[m], bfr[n], acc[m][n]);
    __syncthreads();
  }
#pragma unroll
  for (int m = 0; m < 4; ++m) {
    const int row0 = bm0 + wr*64 + m*16 + kg*4;
#pragma unroll
    for (int n = 0; n < 4; ++n) {
      const int col = bn0 + wc*64 + n*16 + lm;
#pragma unroll
      for (int q = 0; q < 4; ++q) {
        float val = acc[m][n][q];
        size_t o = (size_t)(row0 + q) * C_ + col;
        if (epi == 2) {
          Cout[o] = tobf(val);
        } else if (epi == 4) {
          float zz = aux[col] + val;
          Cout[o] = tobf(2.f / (1.f + __expf(-zz)));
        } else {  // epi == 5: w-finalize (fast transcendentals)
          float wr2 = val + aux[col];
          float sp = fmaxf(-wr2, 0.f) + __logf(1.f + __expf(-fabsf(wr2)));
          float w = -sp - 0.5f;
          Cout[o] = tobf(-__expf(w));                                  // lw
          ea.ksout[o] = tobf(frombf(ea.kin[o]) * __expf(fminf(0.5f*w, 0.f)));
        }
      }
    }
  }
}

// --------- fused 6-branch low-rank projection + combine (bf16 x copy) -------
struct Mix6Args { const float* maa[6]; bf16* out[6]; };

__global__ __launch_bounds__(256) void mix_combine(
    const bf16* __restrict__ mixb, const bf16* __restrict__ w2t,
    const bf16* __restrict__ xb, Mix6Args ma)
{
  __shared__ short As[64][40];
  __shared__ short Bs[64][40];
  const int s6 = blockIdx.z;
  const bf16* __restrict__ A  = mixb + s6*32;            // lda = 192
  const bf16* __restrict__ Bt = w2t + (size_t)s6*C_*32;  // ldb = 32
  const float* __restrict__ maa = ma.maa[s6];
  bf16* __restrict__ out = ma.out[s6];
  const int bm0 = blockIdx.x * 64, bn0 = blockIdx.y * 64;
  const int tid = threadIdx.x, wave = tid >> 6, lane = tid & 63;
  const int lm = lane & 15, kg = lane >> 4;
  const int srow = tid >> 2, scol = (tid & 3) * 8;
  *(uint4*)&As[srow][scol] = *(const uint4*)(A + (size_t)(bm0 + srow)*192 + scol);
  *(uint4*)&Bs[srow][scol] = *(const uint4*)(Bt + (size_t)(bn0 + srow)*32 + scol);
  __syncthreads();
  bf16x8 af = *(const bf16x8*)&As[wave*16 + lm][kg*8];
  f32x4 acc[4] = {};
#pragma unroll
  for (int f = 0; f < 4; ++f) {
    bf16x8 bfr = *(const bf16x8*)&Bs[f*16 + lm][kg*8];
    acc[f] = mfma16x16x32(af, bfr, acc[f]);
  }
  const int row0 = bm0 + wave*16 + kg*4;
  const int col0 = bn0 + lm;
#pragma unroll
  for (int f = 0; f < 4; ++f) {
#pragma unroll
    for (int q = 0; q < 4; ++q) {
      const int row = row0 + q, col = col0 + f*16;
      const size_t o = (size_t)row * C_ + col;
      float xv = frombf(xb[o]);
      float xp = (row & (T_ - 1)) ? frombf(xb[o - C_]) : 0.f;
      out[o] = tobf(xv + (xp - xv) * (maa[col] + acc[f][q]));
    }
  }
}

// ---------------- elementwise ----------------------------------------------
__global__ __launch_bounds__(256) void xin_k(
    const float* __restrict__ x, const float* __restrict__ maa_x,
    bf16* __restrict__ xinb, bf16* __restrict__ xb)
{
  size_t idx = (size_t)blockIdx.x * 256 + threadIdx.x;
  int c = idx & (C_ - 1);
  int t = (int)((idx >> 10) & (T_ - 1));
  float xv = x[idx];
  float xp = t ? x[idx - C_] : 0.f;
  xinb[idx] = tobf(xv + (xp - xv) * maa_x[c]);
  xb[idx] = tobf(xv);
}

__global__ __launch_bounds__(256) void kk_normalize(
    const bf16* __restrict__ kraw, const bf16* __restrict__ kkadd,
    bf16* __restrict__ kkout)
{
  const int bt = blockIdx.x;
  const int tid = threadIdx.x;
  const size_t o = (size_t)bt * C_;
  float vals[4]; float ss = 0.f;
#pragma unroll
  for (int q = 0; q < 4; ++q) {
    float u = frombf(kraw[o + tid + q*256]) + frombf(kkadd[o + tid + q*256]);
    vals[q] = u; ss += u * u;
  }
  ss = allred64(ss);
  __shared__ float red[4];
  const int wave = tid >> 6, lane = tid & 63;
  if (lane == 0) red[wave] = ss;
  __syncthreads();
  float tot = red[0] + red[1] + red[2] + red[3];
  float inv = 1.f / fmaxf(sqrtf(tot), 1e-12f);
#pragma unroll
  for (int q = 0; q < 4; ++q) kkout[o + tid + q*256] = tobf(vals[q] * inv);
}

// ============ Chunked RWKV-7 scan (fp32 recurrence, bf16 MFMA phases) =======
//   SA = (I-trilA)^{-1}(Achk S0^T + trilC V) = W S0^T + SA_loc
//   y[s] = rt_s S0^T + tril<=(ABy) SA + tril<=(CKy) V
//   S_L = S0 * M + U  with M = diag(dL) + (W^T Bt).*dL_j
// LDS alias: {aCb,rCb} (dead after solve-init) overlays {WT,SAT} -> 48 KB.

__global__ __launch_bounds__(256, 3) void rwkv_chunk_pre(
    const bf16* __restrict__ rr, const bf16* __restrict__ lw,
    const bf16* __restrict__ kk_s, const bf16* __restrict__ kkv,
    const bf16* __restrict__ aam, const bf16* __restrict__ vv,
    bf16* __restrict__ wbufb, bf16* __restrict__ sabufb,
    bf16* __restrict__ abybufb, bf16* __restrict__ ckybufb,
    bf16* __restrict__ ubufP, bf16* __restrict__ mbufT)
{
  __shared__ float Am[LCH][33], Cm[LCH][33];
  __shared__ float wtot[4][64];
  __shared__ float lcl[64];
  __shared__ float dll[64];
  __shared__ bf16 bTb[LCH][72], kTb[LCH][72], vLb[LCH][72];
  __shared__ bf16 bTT[64][40], kTT[64][40], vLT[64][40];
  __shared__ bf16 uni[5120];   // {aCb,rCb}[32][72] | {WT,SAT}[64][40]
  bf16 (*aCb)[72] = (bf16(*)[72])uni;
  bf16 (*rCb)[72] = (bf16(*)[72])(uni + 2304);
  bf16 (*WT)[40]  = (bf16(*)[40])uni;
  bf16 (*SAT)[40] = (bf16(*)[40])(uni + 2560);

  const int ch = blockIdx.x;
  const int c  = ch & (NCH - 1);
  const int bh = ch >> 6;
  const int b  = bh >> 4, h = bh & 15;
  const int tid = threadIdx.x, wv = tid >> 6, ln = tid & 63;
  const int lm = ln & 15, kg = ln >> 4;
  const size_t base = ((size_t)(b*T_ + c*LCH) * C_) + h*N_ + ln;

  // --- phase 1: cumulative log-decay + load/scale into LDS (both layouts) ---
  float lwr[8], lcE[8];
  {
    float run = 0.f;
#pragma unroll
    for (int q = 0; q < 8; ++q) {
      lwr[q] = frombf(lw[base + (size_t)(wv*8 + q) * C_]);
      lcE[q] = run; run += lwr[q];
    }
    wtot[wv][ln] = run;
  }
  __syncthreads();
  {
    float pre = 0.f;
    for (int w2 = 0; w2 < wv; ++w2) pre += wtot[w2][ln];
    if (wv == 0) lcl[ln] = wtot[0][ln] + wtot[1][ln] + wtot[2][ln] + wtot[3][ln];
#pragma unroll
    for (int q = 0; q < 8; ++q) lcE[q] += pre;
  }
#pragma unroll
  for (int q = 0; q < 8; ++q) {
    const int s = wv*8 + q;
    const size_t off = base + (size_t)s * C_;
    float kkx = frombf(kkv[off]), aax = frombf(aam[off]);
    float kx = frombf(kk_s[off]), rx = frombf(rr[off]);
    float lcI = lcE[q] + lwr[q];
    float eIm = __expf(-lcI);
    float eI  = __builtin_amdgcn_rcpf(eIm);   // exp(lcI) = 1/exp(-lcI)
    float av = -kkx * __expf(lcE[q]);
    float bv = kkx * aax * eIm;
    float kv2 = kx * eIm;
    float rv = rx * eI;
    bf16 vxb = vv[off];
    aCb[s][ln] = tobf(av);  rCb[s][ln] = tobf(rv);
    bTb[s][ln] = tobf(bv);  kTb[s][ln] = tobf(kv2);
    vLb[s][ln] = vxb;
    bTT[ln][s] = tobf(bv);  kTT[ln][s] = tobf(kv2);  vLT[ln][s] = vxb;
  }
  __syncthreads();
  if (tid < 64) dll[tid] = __expf(lcl[tid]);  // barriers below make it visible

  // --- phase 2: MFMA, one 32x32 (K=64) product per wave ---
  {
    const bf16 (*Ab)[72] = (wv < 2) ? aCb : rCb;
    const bf16 (*Bb)[72] = (wv & 1) ? kTb : bTb;
#pragma unroll
    for (int mt = 0; mt < 2; ++mt)
#pragma unroll
      for (int nt = 0; nt < 2; ++nt) {
        f32x4 acc = {};
#pragma unroll
        for (int ks = 0; ks < 2; ++ks) {
          bf16x8 af = *(const bf16x8*)&Ab[mt*16 + lm][ks*32 + kg*8];
          bf16x8 bq = *(const bf16x8*)&Bb[nt*16 + lm][ks*32 + kg*8];
          acc = mfma16x16x32(af, bq, acc);
        }
        const int row0 = mt*16 + kg*4, col = nt*16 + lm;
#pragma unroll
        for (int q = 0; q < 4; ++q) {
          float v = acc[q];
          if (wv == 0)      Am[row0+q][col] = v;
          else if (wv == 1) Cm[row0+q][col] = v;
          else {
            bf16 bv2 = tobf(col <= row0+q ? v : 0.f);  // tril<= mask
            if (wv == 2) abybufb[(size_t)ch*1024 + (row0+q)*32 + col] = bv2;
            else         ckybufb[(size_t)ch*1024 + (row0+q)*32 + col] = bv2;
          }
        }
      }
  }
  __syncthreads();

  // --- phase 3a: preload solve inputs to registers (aCb/Cm/vLb reads) ------
  float Xr[32], amr[32];
  if (wv == 0) {
#pragma unroll
    for (int s = 0; s < 32; ++s) amr[s] = Am[s][ln & 31];
#pragma unroll
    for (int s = 0; s < 32; ++s) Xr[s] = frombf(aCb[s][ln]);
  } else if (wv == 1) {
    float cmr[32];
#pragma unroll
    for (int s = 0; s < 32; ++s) { amr[s] = Am[s][ln & 31]; cmr[s] = Cm[s][ln & 31]; }
#pragma unroll
    for (int s = 0; s < 32; ++s) Xr[s] = 0.f;
#pragma unroll
    for (int u = 0; u < 31; ++u) {
      float v = frombf(vLb[u][ln]);
#pragma unroll
      for (int s = u + 1; s < 32; ++s) Xr[s] += rdlane(cmr[s], u) * v;
    }
  }
  __syncthreads();   // aCb reads complete before WT/SAT writes into alias

  // --- phase 3b: register forward-substitution; write WT/SAT --------------
  if (wv < 2) {
#pragma unroll
    for (int s = 1; s < 32; ++s) {
      float acc = Xr[s];
#pragma unroll
      for (int u = 0; u < s; ++u) acc += rdlane(amr[s], u) * Xr[u];
      Xr[s] = acc;
    }
    if (wv == 0) {
#pragma unroll
      for (int s = 0; s < 32; ++s) {
        bf16 bv = tobf(Xr[s]);
        WT[ln][s] = bv;
        wbufb[(size_t)ch*2048 + s*64 + ln] = bv;
      }
    } else {
#pragma unroll
      for (int s = 0; s < 32; ++s) {
        bf16 bv = tobf(Xr[s]);
        SAT[ln][s] = bv;
        sabufb[(size_t)ch*2048 + s*64 + ln] = bv;
      }
    }
  }
  __syncthreads();

  // --- phase 5: U, M (64x64, K=32) via MFMA; packed-layout b64 stores ------
  {
    const int mt = wv;
    bf16x8 aS = *(const bf16x8*)&SAT[mt*16 + lm][kg*8];
    bf16x8 aV = *(const bf16x8*)&vLT[mt*16 + lm][kg*8];
    bf16x8 aW = *(const bf16x8*)&WT[mt*16 + lm][kg*8];
#pragma unroll
    for (int nt = 0; nt < 4; ++nt) {
      bf16x8 bB = *(const bf16x8*)&bTT[nt*16 + lm][kg*8];
      bf16x8 bK = *(const bf16x8*)&kTT[nt*16 + lm][kg*8];
      f32x4 aU = {}, aG = {};
      aU = mfma16x16x32(aS, bB, aU);
      aU = mfma16x16x32(aV, bK, aU);
      aG = mfma16x16x32(aW, bB, aG);
      const int i0r = mt*16 + kg*4, col = nt*16 + lm;
      float dl = dll[col];
      uint2 up;
      up.x = (unsigned int)bfbits(aU[0]*dl) | ((unsigned int)bfbits(aU[1]*dl) << 16);
      up.y = (unsigned int)bfbits(aU[2]*dl) | ((unsigned int)bfbits(aU[3]*dl) << 16);
      *(uint2*)(ubufP + (size_t)ch*4096 + (mt*4 + nt)*256 + ln*4) = up;
      float m0 = (aG[0] + (i0r+0 == col ? 1.f : 0.f)) * dl;
      float m1 = (aG[1] + (i0r+1 == col ? 1.f : 0.f)) * dl;
      float m2 = (aG[2] + (i0r+2 == col ? 1.f : 0.f)) * dl;
      float m3 = (aG[3] + (i0r+3 == col ? 1.f : 0.f)) * dl;
      uint2 mp;
      mp.x = (unsigned int)bfbits(m0) | ((unsigned int)bfbits(m1) << 16);
      mp.y = (unsigned int)bfbits(m2) | ((unsigned int)bfbits(m3) << 16);
      const int laned = (((mt*2) + (kg >> 1)) & 3) * 16 + lm;
      *(uint2*)(mbufT + (size_t)ch*4096 + (nt*2 + (mt >> 1))*512
                + laned*8 + (kg & 1)*4) = mp;
    }
  }
}

// Phase B: serial over chunks; 32 blocks (one per bh) x 4 waves, no barriers.
__global__ __launch_bounds__(256) void rwkv_chunk_state(
    const bf16* __restrict__ mbufT, const bf16* __restrict__ ubufP,
    bf16* __restrict__ s0bufb)
{
  __shared__ bf16 Sst[4][16][72];
  const int bh = blockIdx.x;
  const int tid = threadIdx.x, wv = tid >> 6, ln = tid & 63;
  const int lm = ln & 15, kg = ln >> 4;

#pragma unroll
  for (int r = 0; r < 16; ++r) {
    Sst[wv][r][ln] = tobf(0.f);
    if (ln < 8) Sst[wv][r][64 + ln] = tobf(0.f);
  }

  bf16x8 BfA[4][2], BfB[4][2];
  uint2 UpA[4], UpB[4];
  auto prefetch = [&](bf16x8 (&Bf)[4][2], uint2 (&Up)[4], int c) {
    const size_t chp = (size_t)(bh*NCH + c) * 4096;
#pragma unroll
    for (int nt = 0; nt < 4; ++nt) {
      Bf[nt][0] = *(const bf16x8*)(mbufT + chp + (nt*2 + 0)*512 + ln*8);
      Bf[nt][1] = *(const bf16x8*)(mbufT + chp + (nt*2 + 1)*512 + ln*8);
      Up[nt]    = *(const uint2*) (ubufP + chp + (wv*4 + nt)*256 + ln*4);
    }
  };
  prefetch(BfA, UpA, 0);
  prefetch(BfB, UpB, 1);

  auto body = [&](bf16x8 (&Bf)[4][2], uint2 (&Up)[4], int c) {
    const size_t ch4 = (size_t)(bh*NCH + c) * 4096;
    const int sr = ln >> 2, sc = (ln & 3) * 16;
    uint4 v0 = *(const uint4*)&Sst[wv][sr][sc];
    uint4 v1 = *(const uint4*)&Sst[wv][sr][sc + 8];
    *(uint4*)(s0bufb + ch4 + (size_t)(wv*16 + sr)*64 + sc) = v0;
    *(uint4*)(s0bufb + ch4 + (size_t)(wv*16 + sr)*64 + sc + 8) = v1;
    bf16x8 A0 = *(const bf16x8*)&Sst[wv][lm][kg*8];
    bf16x8 A1 = *(const bf16x8*)&Sst[wv][lm][32 + kg*8];
    f32x4 acc[4];
#pragma unroll
    for (int nt = 0; nt < 4; ++nt) {
      acc[nt][0] = bf2f((unsigned short)(Up[nt].x & 0xffff));
      acc[nt][1] = bf2f((unsigned short)(Up[nt].x >> 16));
      acc[nt][2] = bf2f((unsigned short)(Up[nt].y & 0xffff));
      acc[nt][3] = bf2f((unsigned short)(Up[nt].y >> 16));
      acc[nt] = mfma16x16x32(A0, Bf[nt][0], acc[nt]);
      acc[nt] = mfma16x16x32(A1, Bf[nt][1], acc[nt]);
    }
    int cp = c + 2; if (cp > NCH - 1) cp = NCH - 1;
    prefetch(Bf, Up, cp);
#pragma unroll
    for (int nt = 0; nt < 4; ++nt)
#pragma unroll
      for (int q = 0; q < 4; ++q)
        Sst[wv][kg*4 + q][nt*16 + lm] = tobf(acc[nt][q]);
  };

  for (int cc = 0; cc < NCH; cc += 2) {
    body(BfA, UpA, cc);
    body(BfB, UpB, cc + 1);
  }
}

// Phase C: per chunk-head: SA = W*S0^T + SAll; y = Rt*S0^T + ABl*SAo + CKl*V;
// then FUSED groupnorm (group == head, size 64) + bonus + gate -> zb (bf16).
__global__ __launch_bounds__(256, 4) void rwkv_chunk_out(
    const bf16* __restrict__ rr, const bf16* __restrict__ lw,
    const bf16* __restrict__ vv, const bf16* __restrict__ kks,
    const bf16* __restrict__ gg, const bf16* __restrict__ s0bufb,
    const bf16* __restrict__ wbufb, const bf16* __restrict__ sabufb,
    const bf16* __restrict__ abybufb, const bf16* __restrict__ ckybufb,
    const float* __restrict__ faaaa, const float* __restrict__ lnw,
    const float* __restrict__ lnb, bf16* __restrict__ zb)
{
  __shared__ bf16 S0b[64][72];                    // B^T layout: [i][j]
  __shared__ bf16 ABl[LCH][40], CKl[LCH][40];     // A layouts: [s][u]
  __shared__ bf16 SAot[64][40], VlT[64][40];      // B^T layouts: [i][u]
  __shared__ float wtot[4][64];
  __shared__ float bonus[LCH];
  __shared__ float uni2f[2304];  // {Wb,Rlb}[32][72] bf16 | Yl[32][68] f32
  bf16 (*Wb)[72]  = (bf16(*)[72])uni2f;
  bf16 (*Rlb)[72] = (bf16(*)[72])((bf16*)uni2f + 2304);
  float (*Yl)[68] = (float(*)[68])uni2f;

  const int ch = blockIdx.x;
  const int c = ch & (NCH - 1), bh = ch >> 6, b = bh >> 4, h = bh & 15;
  const int tid = threadIdx.x, wv = tid >> 6, ln = tid & 63;
  const int lm = ln & 15, kg = ln >> 4;
  const size_t base = ((size_t)(b*T_ + c*LCH) * C_) + h*N_ + ln;

  float lwr[8], lcE[8];
  {
    float run = 0.f;
#pragma unroll
    for (int q = 0; q < 8; ++q) {
      lwr[q] = frombf(lw[base + (size_t)(wv*8 + q) * C_]);
      lcE[q] = run; run += lwr[q];
    }
    wtot[wv][ln] = run;
  }
  __syncthreads();
  {
    float pre = 0.f;
    for (int w2 = 0; w2 < wv; ++w2) pre += wtot[w2][ln];
#pragma unroll
    for (int q = 0; q < 8; ++q) lcE[q] += pre;
  }
  const float fa = faaaa[h*N_ + ln];
#pragma unroll
  for (int q = 0; q < 8; ++q) {
    const int s = wv*8 + q;
    const size_t off = base + (size_t)s * C_;
    float rf = frombf(rr[off]);
    Rlb[s][ln] = tobf(rf * __expf(lcE[q] + lwr[q]));
    VlT[ln][s] = vv[off];
    float rk = allred64(rf * frombf(kks[off]) * fa);   // bonus dot
    if (ln == 0) bonus[s] = rk;
  }
#pragma unroll
  for (int t = 0; t < 2; ++t) {
    int cc2 = tid*2 + t; int ri = cc2 >> 3, co = (cc2 & 7) * 8;
    *(uint4*)&S0b[ri][co] = *(const uint4*)(s0bufb + (size_t)ch*4096 + ri*64 + co);
  }
  { int ri = tid >> 3, co = (tid & 7) * 8;
    *(uint4*)&Wb[ri][co] = *(const uint4*)(wbufb + (size_t)ch*2048 + ri*64 + co); }
  if (tid < 128) {
    int ri = tid >> 2, co = (tid & 3) * 8;
    *(uint4*)&ABl[ri][co] = *(const uint4*)(abybufb + (size_t)ch*1024 + ri*32 + co);
  } else {
    int t2 = tid - 128; int ri = t2 >> 2, co = (t2 & 3) * 8;
    *(uint4*)&CKl[ri][co] = *(const uint4*)(ckybufb + (size_t)ch*1024 + ri*32 + co);
  }
  __syncthreads();

  const int mt = wv >> 1, ntb = (wv & 1) * 2;
#pragma unroll
  for (int t = 0; t < 2; ++t) {
    const int nt = ntb + t;
    const int row0 = mt*16 + kg*4, col = nt*16 + lm;
    f32x4 acc;
#pragma unroll
    for (int q = 0; q < 4; ++q)
      acc[q] = frombf(sabufb[(size_t)ch*2048 + (row0+q)*64 + col]);
#pragma unroll
    for (int ks = 0; ks < 2; ++ks) {
      bf16x8 af = *(const bf16x8*)&Wb[mt*16 + lm][ks*32 + kg*8];
      bf16x8 bq = *(const bf16x8*)&S0b[nt*16 + lm][ks*32 + kg*8];
      acc = mfma16x16x32(af, bq, acc);
    }
#pragma unroll
    for (int q = 0; q < 4; ++q) SAot[col][row0+q] = tobf(acc[q]);
  }
  __syncthreads();

  f32x4 yacc[2];
#pragma unroll
  for (int t = 0; t < 2; ++t) {
    const int nt = ntb + t;
    f32x4 acc = {};
#pragma unroll
    for (int ks = 0; ks < 2; ++ks) {
      bf16x8 af = *(const bf16x8*)&Rlb[mt*16 + lm][ks*32 + kg*8];
      bf16x8 bq = *(const bf16x8*)&S0b[nt*16 + lm][ks*32 + kg*8];
      acc = mfma16x16x32(af, bq, acc);
    }
    {
      bf16x8 af = *(const bf16x8*)&ABl[mt*16 + lm][kg*8];
      bf16x8 bq = *(const bf16x8*)&SAot[nt*16 + lm][kg*8];
      acc = mfma16x16x32(af, bq, acc);
    }
    {
      bf16x8 af = *(const bf16x8*)&CKl[mt*16 + lm][kg*8];
      bf16x8 bq = *(const bf16x8*)&VlT[nt*16 + lm][kg*8];
      acc = mfma16x16x32(af, bq, acc);
    }
    yacc[t] = acc;
  }
  __syncthreads();   // all Rlb reads done before Yl overwrites the alias

#pragma unroll
  for (int t = 0; t < 2; ++t) {
    const int nt = ntb + t;
    const int row0 = mt*16 + kg*4, col = nt*16 + lm;
#pragma unroll
    for (int q = 0; q < 4; ++q) Yl[row0 + q][col] = yacc[t][q];
  }
  __syncthreads();

  // fused groupnorm + bonus + gate: thread = (row s2, 8 cols)
  {
    const int s2 = tid >> 3, c0 = (tid & 7) * 8;
    float yv[8]; float sum = 0.f;
#pragma unroll
    for (int i = 0; i < 8; ++i) { yv[i] = Yl[s2][c0 + i]; sum += yv[i]; }
#pragma unroll
    for (int m = 1; m < 8; m <<= 1) sum += __shfl_xor(sum, m, 64);
    const float mean = sum * (1.f/64.f);
    float ss = 0.f;
#pragma unroll
    for (int i = 0; i < 8; ++i) { float d = yv[i] - mean; ss += d * d; }
#pragma unroll
    for (int m = 1; m < 8; m <<= 1) ss += __shfl_xor(ss, m, 64);
    const float inv = rsqrtf(ss * (1.f/64.f) + 6.4e-4f);
    const float bn = bonus[s2];
    const size_t trow = (size_t)(b*T_ + c*LCH + s2) * C_ + h*N_ + c0;
    bf16 zout[8];
#pragma unroll
    for (int i = 0; i < 8; ++i) {
      float gn = (yv[i] - mean) * inv * lnw[h*N_ + c0 + i] + lnb[h*N_ + c0 + i];
      float z = (gn + bn * frombf(VlT[c0 + i][s2])) * frombf(gg[trow + i]);
      zout[i] = tobf(z);
    }
    *(uint4*)(zb + trow) = *(const uint4*)&zout[0];
  }
}

// ---------------- driver ----------------------------------------------------
extern "C" void kernel_launch(void* const* d_in, const int* in_sizes, int n_in,
                              void* d_out, int out_size, void* d_ws, size_t ws_size,
                              hipStream_t stream)
{
  const float* x     = (const float*)d_in[0];
  const float* maa_x = (const float*)d_in[1];
  const float* maa_r = (const float*)d_in[2];
  const float* maa_w = (const float*)d_in[3];
  const float* maa_k = (const float*)d_in[4];
  const float* maa_v = (const float*)d_in[5];
  const float* maa_a = (const float*)d_in[6];
  const float* maa_g = (const float*)d_in[7];
  const float* tdec  = (const float*)d_in[8];
  const float* faaaa = (const float*)d_in[9];
  const float* aaaaa = (const float*)d_in[10];
  const float* maa_w1= (const float*)d_in[11];
  const float* maa_w2= (const float*)d_in[12];
  const float* dec_w1= (const float*)d_in[13];
  const float* dec_w2= (const float*)d_in[14];
  const float* aaa_w1= (const float*)d_in[15];
  const float* aaa_w2= (const float*)d_in[16];
  const float* kkk_w1= (const float*)d_in[17];
  const float* kkk_w2= (const float*)d_in[18];
  const float* gate_w1=(const float*)d_in[19];
  const float* gate_w2=(const float*)d_in[20];
  const float* W_r   = (const float*)d_in[21];
  const float* W_k   = (const float*)d_in[22];
  const float* W_v   = (const float*)d_in[23];
  const float* W_o   = (const float*)d_in[24];
  const float* lnw   = (const float*)d_in[25];
  const float* lnb   = (const float*)d_in[26];

  char* ws = (char*)d_ws;
  size_t cur = 0;
  auto alloc = [&](size_t bytes) -> void* {
    void* p = ws + cur; cur += (bytes + 255) & ~(size_t)255; return p;
  };
  const size_t HBT = (size_t)BT_ * C_ * 2;  // bf16 activation buffer

  // ---- persistent (activations bf16) ----
  bf16* rb   = (bf16*)alloc(HBT);
  bf16* kb   = (bf16*)alloc(HBT);   // UNscaled k (for kk_normalize)
  bf16* ksb  = (bf16*)alloc(HBT);   // scaled k (for scan + bonus)
  bf16* vb   = (bf16*)alloc(HBT);
  bf16* gbb  = (bf16*)alloc(HBT);
  bf16* WtR  = (bf16*)alloc((size_t)C_*C_*2);
  bf16* WtK  = (bf16*)alloc((size_t)C_*C_*2);
  bf16* WtV  = (bf16*)alloc((size_t)C_*C_*2);
  bf16* WtO  = (bf16*)alloc((size_t)C_*C_*2);
  bf16* w1t  = (bf16*)alloc((size_t)192*C_*2);
  bf16* w2t  = (bf16*)alloc((size_t)6*C_*32*2);
  bf16* d1t  = (bf16*)alloc((size_t)64*C_*2);
  bf16* d2t  = (bf16*)alloc((size_t)C_*64*2);
  bf16* a1t  = (bf16*)alloc((size_t)64*C_*2);
  bf16* a2t  = (bf16*)alloc((size_t)C_*64*2);
  bf16* k1t  = (bf16*)alloc((size_t)64*C_*2);
  bf16* k2t  = (bf16*)alloc((size_t)C_*64*2);
  bf16* g1t  = (bf16*)alloc((size_t)128*C_*2);
  bf16* g2t  = (bf16*)alloc((size_t)C_*128*2);
  bf16* lwb  = (bf16*)alloc(HBT);
  bf16* kkb  = (bf16*)alloc(HBT);
  bf16* aamt = (bf16*)alloc(HBT);
  bf16* s0bufb = kkb;                 // overlay: kkb+aamt dead after chunk_pre

  // ---- union region ----
  const size_t ubase = cur;
  bf16* mtmpb = (bf16*)alloc(HBT);
  bf16* xinb = (bf16*)alloc(HBT);
  bf16* xb   = (bf16*)alloc(HBT);
  bf16* mixb = (bf16*)alloc((size_t)BT_*192*2);
  bf16* xbr[6];
  for (int s = 0; s < 6; ++s) xbr[s] = (bf16*)alloc(HBT);
  bf16* h64k = (bf16*)alloc((size_t)BT_*64*2);
  bf16* h64d = (bf16*)alloc((size_t)BT_*64*2);
  bf16* h64a = (bf16*)alloc((size_t)BT_*64*2);
  bf16* h128b= (bf16*)alloc((size_t)BT_*128*2);
  const size_t tmp_end = cur;
  cur = ubase;  // overlay
  bf16*  wbufb   = (bf16*)alloc((size_t)CHD*2048*2);
  bf16*  sabufb  = (bf16*)alloc((size_t)CHD*2048*2);
  bf16*  abybufb = (bf16*)alloc((size_t)CHD*1024*2);
  bf16*  ckybufb = (bf16*)alloc((size_t)CHD*1024*2);
  bf16*  ubufP   = (bf16*)alloc((size_t)CHD*4096*2);
  bf16*  mbufT   = (bf16*)alloc((size_t)CHD*4096*2);
  bf16*  zb      = (bf16*)ubufP;   // alias: ubufP dead after chunk_state
  if (tmp_end > cur) cur = tmp_end;
  const size_t need = cur;
  (void)in_sizes; (void)n_in; (void)out_size;

  if (ws_size < need) {
    ws_diag<<<1, 1, 0, stream>>>((float)ws_size, (float)need, (float*)d_out);
    return;
  }

  PrepArgs pa;
  pa.src[0] = W_r;  pa.dst[0] = WtR;
  pa.src[1] = W_k;  pa.dst[1] = WtK;
  pa.src[2] = W_v;  pa.dst[2] = WtV;
  pa.src[3] = W_o;  pa.dst[3] = WtO;
  pa.src[4] = maa_w1; pa.dst[4] = w1t;
  for (int s = 0; s < 6; ++s) { pa.src[5+s] = maa_w2 + (size_t)s*32*C_; pa.dst[5+s] = w2t + (size_t)s*C_*32; }
  pa.src[11] = dec_w1; pa.dst[11] = d1t;
  pa.src[12] = dec_w2; pa.dst[12] = d2t;
  pa.src[13] = aaa_w1; pa.dst[13] = a1t;
  pa.src[14] = aaa_w2; pa.dst[14] = a2t;
  pa.src[15] = kkk_w1; pa.dst[15] = k1t;
  pa.src[16] = kkk_w2; pa.dst[16] = k2t;
  pa.src[17] = gate_w1; pa.dst[17] = g1t;
  pa.src[18] = gate_w2; pa.dst[18] = g2t;
  prep_weights<<<dim3(1024, 19), 256, 0, stream>>>(pa);

  const int EW_GRID = (BT_ * C_) / 256;  // 16384
  xin_k<<<EW_GRID, 256, 0, stream>>>(x, maa_x, xinb, xb);

  gemm_bt<1><<<dim3(64, 3), 256, 0, stream>>>(xinb, C_, w1t, C_, mixb, 192, C_);

  Mix6Args ma;
  ma.maa[0] = maa_r; ma.maa[1] = maa_w; ma.maa[2] = maa_k;
  ma.maa[3] = maa_v; ma.maa[4] = maa_a; ma.maa[5] = maa_g;
  for (int s = 0; s < 6; ++s) ma.out[s] = xbr[s];
  mix_combine<<<dim3(64, 16, 6), 256, 0, stream>>>(mixb, w2t, xb, ma);

  // r, k, v batched (one launch, bf16 out)
  RkvArgs ra;
  ra.A[0] = xbr[0]; ra.Bt[0] = WtR; ra.Cq[0] = rb;
  ra.A[1] = xbr[2]; ra.Bt[1] = WtK; ra.Cq[1] = kb;
  ra.A[2] = xbr[3]; ra.Bt[2] = WtV; ra.Cq[2] = vb;
  gemm128_rkv<<<dim3(32, 8, 3), 256, 0, stream>>>(ra);

  // batched small projections: k1 (tanh), d1 (tanh), a1 (raw), g1 (tanh)
  Proj4Args p4;
  p4.A[0] = xbr[2]; p4.Bt[0] = k1t; p4.out[0] = h64k; p4.N[0] = 64;  p4.tnh[0] = 1;
  p4.A[1] = xbr[1]; p4.Bt[1] = d1t; p4.out[1] = h64d; p4.N[1] = 64;  p4.tnh[1] = 1;
  p4.A[2] = xbr[4]; p4.Bt[2] = a1t; p4.out[2] = h64a; p4.N[2] = 64;  p4.tnh[2] = 0;
  p4.A[3] = xbr[5]; p4.Bt[3] = g1t; p4.out[3] = h128b; p4.N[3] = 128; p4.tnh[3] = 1;
  proj4<<<dim3(64, 2, 4), 256, 0, stream>>>(p4);

  // batched epilogue GEMMs: z0 kk-add, z1 w-finalize (kb->ksb), z2 a, z3 g
  Ep4Args ea;
  ea.A[0] = h64k;  ea.Bt[0] = k2t; ea.Cout[0] = mtmpb; ea.K[0] = 64;  ea.epi[0] = 2; ea.aux[0] = nullptr;
  ea.A[1] = h64d;  ea.Bt[1] = d2t; ea.Cout[1] = lwb;   ea.K[1] = 64;  ea.epi[1] = 5; ea.aux[1] = tdec;
  ea.A[2] = h64a;  ea.Bt[2] = a2t; ea.Cout[2] = aamt;  ea.K[2] = 64;  ea.epi[2] = 4; ea.aux[2] = aaaaa;
  ea.A[3] = h128b; ea.Bt[3] = g2t; ea.Cout[3] = gbb;   ea.K[3] = 128; ea.epi[3] = 2; ea.aux[3] = nullptr;
  ea.kin = kb; ea.ksout = ksb;
  gemm128_ep4<<<dim3(32, 8, 4), 256, 0, stream>>>(ea);

  kk_normalize<<<BT_, 256, 0, stream>>>(kb, mtmpb, kkb);

  // ---- chunked scan (scaled k = ksb) ----
  rwkv_chunk_pre<<<CHD, 256, 0, stream>>>(rb, lwb, ksb, kkb, aamt, vb,
      wbufb, sabufb, abybufb, ckybufb, ubufP, mbufT);
  rwkv_chunk_state<<<32, 256, 0, stream>>>(mbufT, ubufP, s0bufb);
  rwkv_chunk_out<<<CHD, 256, 0, stream>>>(rb, lwb, vb, ksb, gbb, s0bufb,
      wbufb, sabufb, abybufb, ckybufb, faaaa, lnw, lnb, zb);

  gemm128<0><<<dim3(32, 8), 256, 0, stream>>>(zb, C_, WtO, C_, d_out, C_, C_);
}

// Round 17
// 284.201 us; speedup vs baseline: 5.7491x; 1.0152x over previous
//
#include <hip/hip_runtime.h>
#include <hip/hip_bf16.h>

using bf16 = __hip_bfloat16;
using bf16x8 = __attribute__((ext_vector_type(8))) short;  // 8 bf16 (4 VGPRs)
using f32x4 = __attribute__((ext_vector_type(4))) float;

#define B_ 2
#define T_ 2048
#define C_ 1024
#define BT_ (B_*T_)
#define H_ 16
#define N_ 64
#define LCH 32            // scan chunk length
#define NCH (T_/LCH)      // 64 chunks per head
#define CHD (B_*H_*NCH)   // 2048 chunk-heads

__device__ __forceinline__ float allred64(float v) {
#pragma unroll
  for (int m = 1; m < 64; m <<= 1) v += __shfl_xor(v, m, 64);
  return v;
}

__device__ __forceinline__ bf16 tobf(float f) { return __float2bfloat16(f); }
__device__ __forceinline__ float frombf(bf16 b) { return __bfloat162float(b); }
__device__ __forceinline__ float bf2f(unsigned short u) {
  unsigned int x = ((unsigned int)u) << 16;
  return __builtin_bit_cast(float, x);
}
__device__ __forceinline__ unsigned short bfbits(float f) {
  return __builtin_bit_cast(unsigned short, __float2bfloat16(f));
}
__device__ __forceinline__ float rdlane(float v, int m) {
  return __builtin_bit_cast(float,
      __builtin_amdgcn_readlane(__builtin_bit_cast(int, v), m));
}
// overflow-safe fast tanh via hardware exp (<=4 ulp; outputs bf16-rounded)
__device__ __forceinline__ float fast_tanh(float x) {
  float t = __expf(-2.f * fabsf(x));
  float r = (1.f - t) / (1.f + t);
  return copysignf(r, x);
}

__device__ __forceinline__ f32x4 mfma16x16x32(bf16x8 a, bf16x8 b, f32x4 c) {
  return __builtin_amdgcn_mfma_f32_16x16x32_bf16(a, b, c, 0, 0, 0);
}

// async global->LDS, 16B per lane (dest = wave-uniform base + lane*16)
typedef const __attribute__((address_space(1))) unsigned int* gas_ptr;
typedef __attribute__((address_space(3))) unsigned int* las_ptr;
__device__ __forceinline__ void gload16(const void* g, void* l) {
  __builtin_amdgcn_global_load_lds((gas_ptr)g, (las_ptr)l, 16, 0, 0);
}

// ---------------- ws_size diagnostic ----------------------------------------
__global__ void ws_diag(float a, float b, float* out) { out[0] = a; out[1] = b; }

// ---------------- weight transpose + bf16 cast (19 jobs, one launch) -------
struct PrepArgs {
  const float* src[19];
  bf16* dst[19];
};
__constant__ int kTR[19] = {1024,1024,1024,1024, 1024, 32,32,32,32,32,32,
                            1024,64, 1024,64, 1024,64, 1024,128};
__constant__ int kTC[19] = {1024,1024,1024,1024, 192, 1024,1024,1024,1024,1024,1024,
                            64,1024, 64,1024, 64,1024, 128,1024};

__global__ __launch_bounds__(256) void prep_weights(PrepArgs pa) {
  const int job = blockIdx.y;
  const int R = kTR[job], Cc = kTC[job];
  const int ntx = Cc >> 5, nty = R >> 5;
  const int tile = blockIdx.x;
  if (tile >= ntx * nty) return;
  const int tx = tile % ntx, ty = tile / ntx;
  const float* __restrict__ src = pa.src[job];
  bf16* __restrict__ dst = pa.dst[job];
  __shared__ float tl[32][33];
  const int lx = threadIdx.x & 31, ly = threadIdx.x >> 5;  // 32 x 8
#pragma unroll
  for (int q = 0; q < 4; ++q)
    tl[ly + 8*q][lx] = src[(size_t)(ty*32 + ly + 8*q) * Cc + tx*32 + lx];
  __syncthreads();
#pragma unroll
  for (int q = 0; q < 4; ++q)
    dst[(size_t)(tx*32 + ly + 8*q) * R + ty*32 + lx] = tobf(tl[lx][ly + 8*q]);
}

// ------- GEMM 64-tile -------------------------------------------------------
template<int EPI>
__global__ __launch_bounds__(256) void gemm_bt(
    const bf16* __restrict__ A, int lda,
    const bf16* __restrict__ Bt, int ldb,
    void* __restrict__ Cout, int ldc, int K)
{
  __shared__ short As[64][40];
  __shared__ short Bs[64][40];
  const int bm0 = blockIdx.x * 64;
  const int bn0 = blockIdx.y * 64;
  const int tid = threadIdx.x;
  const int wave = tid >> 6, lane = tid & 63;
  const int lm = lane & 15, kg = lane >> 4;
  const int srow = tid >> 2, scol = (tid & 3) * 8;
  f32x4 acc[4] = {};
  const size_t abase = (size_t)(bm0 + srow) * lda + scol;
  const size_t bbase = (size_t)(bn0 + srow) * ldb + scol;
  for (int k0 = 0; k0 < K; k0 += 32) {
    *(uint4*)&As[srow][scol] = *(const uint4*)(A + abase + k0);
    *(uint4*)&Bs[srow][scol] = *(const uint4*)(Bt + bbase + k0);
    __syncthreads();
    bf16x8 af = *(const bf16x8*)&As[wave*16 + lm][kg*8];
#pragma unroll
    for (int f = 0; f < 4; ++f) {
      bf16x8 bfr = *(const bf16x8*)&Bs[f*16 + lm][kg*8];
      acc[f] = mfma16x16x32(af, bfr, acc[f]);
    }
    __syncthreads();
  }
  const int row0 = bm0 + wave*16 + kg*4;
  const int col0 = bn0 + lm;
#pragma unroll
  for (int f = 0; f < 4; ++f) {
#pragma unroll
    for (int q = 0; q < 4; ++q) {
      float val = acc[f][q];
      size_t o = (size_t)(row0 + q) * ldc + col0 + f*16;
      if (EPI == 0)      ((float*)Cout)[o] = val;
      else if (EPI == 1) ((bf16*)Cout)[o] = tobf(fast_tanh(val));
      else               ((bf16*)Cout)[o] = tobf(val);
    }
  }
}

// ------- batched small projections: k1/d1/a1 (N=64) + g1 (N=128) -----------
struct Proj4Args { const bf16* A[4]; const bf16* Bt[4]; bf16* out[4];
                   int N[4]; int tnh[4]; };
__global__ __launch_bounds__(256) void proj4(Proj4Args p4) {
  const int z = blockIdx.z;
  const int Nn = p4.N[z];
  const int bn0 = blockIdx.y * 64;
  if (bn0 >= Nn) return;
  __shared__ short As[64][40];
  __shared__ short Bs[64][40];
  const bf16* __restrict__ A  = p4.A[z];
  const bf16* __restrict__ Bt = p4.Bt[z];
  bf16* __restrict__ out = p4.out[z];
  const int tnh = p4.tnh[z];
  const int bm0 = blockIdx.x * 64;
  const int tid = threadIdx.x;
  const int wave = tid >> 6, lane = tid & 63;
  const int lm = lane & 15, kg = lane >> 4;
  const int srow = tid >> 2, scol = (tid & 3) * 8;
  f32x4 acc[4] = {};
  const size_t abase = (size_t)(bm0 + srow) * C_ + scol;
  const size_t bbase = (size_t)(bn0 + srow) * C_ + scol;
  for (int k0 = 0; k0 < C_; k0 += 32) {
    *(uint4*)&As[srow][scol] = *(const uint4*)(A + abase + k0);
    *(uint4*)&Bs[srow][scol] = *(const uint4*)(Bt + bbase + k0);
    __syncthreads();
    bf16x8 af = *(const bf16x8*)&As[wave*16 + lm][kg*8];
#pragma unroll
    for (int f = 0; f < 4; ++f) {
      bf16x8 bfr = *(const bf16x8*)&Bs[f*16 + lm][kg*8];
      acc[f] = mfma16x16x32(af, bfr, acc[f]);
    }
    __syncthreads();
  }
  const int row0 = bm0 + wave*16 + kg*4;
  const int col0 = bn0 + lm;
#pragma unroll
  for (int f = 0; f < 4; ++f) {
#pragma unroll
    for (int q = 0; q < 4; ++q) {
      float val = acc[f][q];
      size_t o = (size_t)(row0 + q) * Nn + col0 + f*16;
      out[o] = tobf(tnh ? fast_tanh(val) : val);
    }
  }
}

// ------- GEMM 128-tile, m97 structure (global_load_lds staging) -------------
// EPI: 0 f32 | 2 bf16
template<int EPI>
__global__ __launch_bounds__(256) void gemm128(
    const bf16* __restrict__ A, int lda,
    const bf16* __restrict__ Bt, int ldb,
    void* __restrict__ Cout, int ldc, int K)
{
  __shared__ bf16 As[128][32];     // linear (required by global_load_lds)
  __shared__ bf16 Bs[128][32];
  const int bm0 = blockIdx.x * 128, bn0 = blockIdx.y * 128;
  const int tid = threadIdx.x, wv = tid >> 6, ln = tid & 63;
  const int wr = wv >> 1, wc = wv & 1;
  const int lm = ln & 15, kg = ln >> 4;
  const int srow = ln >> 2, scol = (ln & 3) * 8;
  f32x4 acc[4][4] = {};
  for (int k0 = 0; k0 < K; k0 += 32) {
#pragma unroll
    for (int i = 0; i < 2; ++i) {
      const int r0 = wv*32 + i*16;
      gload16(A  + (size_t)(bm0 + r0 + srow) * lda + k0 + scol, &As[r0][0]);
      gload16(Bt + (size_t)(bn0 + r0 + srow) * ldb + k0 + scol, &Bs[r0][0]);
    }
    asm volatile("s_waitcnt vmcnt(0)" ::: "memory");
    __syncthreads();
    bf16x8 af[4], bfr[4];
#pragma unroll
    for (int m = 0; m < 4; ++m) af[m] = *(const bf16x8*)&As[wr*64 + m*16 + lm][kg*8];
#pragma unroll
    for (int n = 0; n < 4; ++n) bfr[n] = *(const bf16x8*)&Bs[wc*64 + n*16 + lm][kg*8];
#pragma unroll
    for (int m = 0; m < 4; ++m)
#pragma unroll
      for (int n = 0; n < 4; ++n)
        acc[m][n] = mfma16x16x32(af[m], bfr[n], acc[m][n]);
    __syncthreads();
  }
#pragma unroll
  for (int m = 0; m < 4; ++m) {
    const int row0 = bm0 + wr*64 + m*16 + kg*4;
#pragma unroll
    for (int n = 0; n < 4; ++n) {
      const int col = bn0 + wc*64 + n*16 + lm;
#pragma unroll
      for (int q = 0; q < 4; ++q) {
        float val = acc[m][n][q];
        size_t o = (size_t)(row0 + q) * ldc + col;
        if (EPI == 0) ((float*)Cout)[o] = val;
        else          ((bf16*)Cout)[o] = tobf(val);
      }
    }
  }
}

// batched r/k/v: same shape (M=4096, N=1024, K=1024), bf16 outputs
struct RkvArgs { const bf16* A[3]; const bf16* Bt[3]; bf16* Cq[3]; };
__global__ __launch_bounds__(256) void gemm128_rkv(RkvArgs ra) {
  __shared__ bf16 As[128][32];
  __shared__ bf16 Bs[128][32];
  const bf16* __restrict__ A  = ra.A[blockIdx.z];
  const bf16* __restrict__ Bt = ra.Bt[blockIdx.z];
  bf16* __restrict__ Cout = ra.Cq[blockIdx.z];
  const int bm0 = blockIdx.x * 128, bn0 = blockIdx.y * 128;
  const int tid = threadIdx.x, wv = tid >> 6, ln = tid & 63;
  const int wr = wv >> 1, wc = wv & 1;
  const int lm = ln & 15, kg = ln >> 4;
  const int srow = ln >> 2, scol = (ln & 3) * 8;
  f32x4 acc[4][4] = {};
  for (int k0 = 0; k0 < C_; k0 += 32) {
#pragma unroll
    for (int i = 0; i < 2; ++i) {
      const int r0 = wv*32 + i*16;
      gload16(A  + (size_t)(bm0 + r0 + srow) * C_ + k0 + scol, &As[r0][0]);
      gload16(Bt + (size_t)(bn0 + r0 + srow) * C_ + k0 + scol, &Bs[r0][0]);
    }
    asm volatile("s_waitcnt vmcnt(0)" ::: "memory");
    __syncthreads();
    bf16x8 af[4], bfr[4];
#pragma unroll
    for (int m = 0; m < 4; ++m) af[m] = *(const bf16x8*)&As[wr*64 + m*16 + lm][kg*8];
#pragma unroll
    for (int n = 0; n < 4; ++n) bfr[n] = *(const bf16x8*)&Bs[wc*64 + n*16 + lm][kg*8];
#pragma unroll
    for (int m = 0; m < 4; ++m)
#pragma unroll
      for (int n = 0; n < 4; ++n)
        acc[m][n] = mfma16x16x32(af[m], bfr[n], acc[m][n]);
    __syncthreads();
  }
#pragma unroll
  for (int m = 0; m < 4; ++m) {
    const int row0 = bm0 + wr*64 + m*16 + kg*4;
#pragma unroll
    for (int n = 0; n < 4; ++n) {
      const int col = bn0 + wc*64 + n*16 + lm;
#pragma unroll
      for (int q = 0; q < 4; ++q)
        Cout[(size_t)(row0 + q) * C_ + col] = tobf(acc[m][n][q]);
    }
  }
}

// ------- batched epilogue GEMMs: kk-add / w-finalize / a-sigmoid / g --------
// all M=4096, N=1024; K per z; epi: 2=bf16 raw, 4=sigmoid, 5=w-finalize
struct Ep4Args {
  const bf16* A[4]; const bf16* Bt[4]; bf16* Cout[4];
  int K[4]; int epi[4];
  const float* aux[4];          // z1: tdec, z2: aaaaa
  const bf16* kin; bf16* ksout; // z1: unscaled k in, scaled k out
};
__global__ __launch_bounds__(256) void gemm128_ep4(Ep4Args ea) {
  __shared__ bf16 As[128][32];
  __shared__ bf16 Bs[128][32];
  const int z = blockIdx.z;
  const bf16* __restrict__ A  = ea.A[z];
  const bf16* __restrict__ Bt = ea.Bt[z];
  bf16* __restrict__ Cout = ea.Cout[z];
  const int K = ea.K[z], epi = ea.epi[z];
  const float* __restrict__ aux = ea.aux[z];
  const int bm0 = blockIdx.x * 128, bn0 = blockIdx.y * 128;
  const int tid = threadIdx.x, wv = tid >> 6, ln = tid & 63;
  const int wr = wv >> 1, wc = wv & 1;
  const int lm = ln & 15, kg = ln >> 4;
  const int srow = ln >> 2, scol = (ln & 3) * 8;
  f32x4 acc[4][4] = {};
  for (int k0 = 0; k0 < K; k0 += 32) {
#pragma unroll
    for (int i = 0; i < 2; ++i) {
      const int r0 = wv*32 + i*16;
      gload16(A  + (size_t)(bm0 + r0 + srow) * K + k0 + scol, &As[r0][0]);
      gload16(Bt + (size_t)(bn0 + r0 + srow) * K + k0 + scol, &Bs[r0][0]);
    }
    asm volatile("s_waitcnt vmcnt(0)" ::: "memory");
    __syncthreads();
    bf16x8 af[4], bfr[4];
#pragma unroll
    for (int m = 0; m < 4; ++m) af[m] = *(const bf16x8*)&As[wr*64 + m*16 + lm][kg*8];
#pragma unroll
    for (int n = 0; n < 4; ++n) bfr[n] = *(const bf16x8*)&Bs[wc*64 + n*16 + lm][kg*8];
#pragma unroll
    for (int m = 0; m < 4; ++m)
#pragma unroll
      for (int n = 0; n < 4; ++n)
        acc[m][n] = mfma16x16x32(af[m], bfr[n], acc[m][n]);
    __syncthreads();
  }
#pragma unroll
  for (int m = 0; m < 4; ++m) {
    const int row0 = bm0 + wr*64 + m*16 + kg*4;
#pragma unroll
    for (int n = 0; n < 4; ++n) {
      const int col = bn0 + wc*64 + n*16 + lm;
#pragma unroll
      for (int q = 0; q < 4; ++q) {
        float val = acc[m][n][q];
        size_t o = (size_t)(row0 + q) * C_ + col;
        if (epi == 2) {
          Cout[o] = tobf(val);
        } else if (epi == 4) {
          float zz = aux[col] + val;
          Cout[o] = tobf(2.f / (1.f + __expf(-zz)));
        } else {  // epi == 5: w-finalize (fast transcendentals)
          float wr2 = val + aux[col];
          float sp = fmaxf(-wr2, 0.f) + __logf(1.f + __expf(-fabsf(wr2)));
          float w = -sp - 0.5f;
          Cout[o] = tobf(-__expf(w));                                  // lw
          ea.ksout[o] = tobf(frombf(ea.kin[o]) * __expf(fminf(0.5f*w, 0.f)));
        }
      }
    }
  }
}

// --------- fused 6-branch low-rank projection + combine (bf16 x copy) -------
struct Mix6Args { const float* maa[6]; bf16* out[6]; };

__global__ __launch_bounds__(256) void mix_combine(
    const bf16* __restrict__ mixb, const bf16* __restrict__ w2t,
    const bf16* __restrict__ xb, Mix6Args ma)
{
  __shared__ short As[64][40];
  __shared__ short Bs[64][40];
  const int s6 = blockIdx.z;
  const bf16* __restrict__ A  = mixb + s6*32;            // lda = 192
  const bf16* __restrict__ Bt = w2t + (size_t)s6*C_*32;  // ldb = 32
  const float* __restrict__ maa = ma.maa[s6];
  bf16* __restrict__ out = ma.out[s6];
  const int bm0 = blockIdx.x * 64, bn0 = blockIdx.y * 64;
  const int tid = threadIdx.x, wave = tid >> 6, lane = tid & 63;
  const int lm = lane & 15, kg = lane >> 4;
  const int srow = tid >> 2, scol = (tid & 3) * 8;
  *(uint4*)&As[srow][scol] = *(const uint4*)(A + (size_t)(bm0 + srow)*192 + scol);
  *(uint4*)&Bs[srow][scol] = *(const uint4*)(Bt + (size_t)(bn0 + srow)*32 + scol);
  __syncthreads();
  bf16x8 af = *(const bf16x8*)&As[wave*16 + lm][kg*8];
  f32x4 acc[4] = {};
#pragma unroll
  for (int f = 0; f < 4; ++f) {
    bf16x8 bfr = *(const bf16x8*)&Bs[f*16 + lm][kg*8];
    acc[f] = mfma16x16x32(af, bfr, acc[f]);
  }
  const int row0 = bm0 + wave*16 + kg*4;
  const int col0 = bn0 + lm;
#pragma unroll
  for (int f = 0; f < 4; ++f) {
#pragma unroll
    for (int q = 0; q < 4; ++q) {
      const int row = row0 + q, col = col0 + f*16;
      const size_t o = (size_t)row * C_ + col;
      float xv = frombf(xb[o]);
      float xp = (row & (T_ - 1)) ? frombf(xb[o - C_]) : 0.f;
      out[o] = tobf(xv + (xp - xv) * (maa[col] + acc[f][q]));
    }
  }
}

// ---------------- elementwise ----------------------------------------------
__global__ __launch_bounds__(256) void xin_k(
    const float* __restrict__ x, const float* __restrict__ maa_x,
    bf16* __restrict__ xinb, bf16* __restrict__ xb)
{
  size_t idx = (size_t)blockIdx.x * 256 + threadIdx.x;
  int c = idx & (C_ - 1);
  int t = (int)((idx >> 10) & (T_ - 1));
  float xv = x[idx];
  float xp = t ? x[idx - C_] : 0.f;
  xinb[idx] = tobf(xv + (xp - xv) * maa_x[c]);
  xb[idx] = tobf(xv);
}

__global__ __launch_bounds__(256) void kk_normalize(
    const bf16* __restrict__ kraw, const bf16* __restrict__ kkadd,
    bf16* __restrict__ kkout)
{
  const int bt = blockIdx.x;
  const int tid = threadIdx.x;
  const size_t o = (size_t)bt * C_;
  float vals[4]; float ss = 0.f;
#pragma unroll
  for (int q = 0; q < 4; ++q) {
    float u = frombf(kraw[o + tid + q*256]) + frombf(kkadd[o + tid + q*256]);
    vals[q] = u; ss += u * u;
  }
  ss = allred64(ss);
  __shared__ float red[4];
  const int wave = tid >> 6, lane = tid & 63;
  if (lane == 0) red[wave] = ss;
  __syncthreads();
  float tot = red[0] + red[1] + red[2] + red[3];
  float inv = 1.f / fmaxf(sqrtf(tot), 1e-12f);
#pragma unroll
  for (int q = 0; q < 4; ++q) kkout[o + tid + q*256] = tobf(vals[q] * inv);
}

// ============ Chunked RWKV-7 scan (fp32 recurrence, bf16 MFMA phases) =======
//   SA = (I-trilA)^{-1}(Achk S0^T + trilC V) = W S0^T + SA_loc
//   y[s] = rt_s S0^T + tril<=(ABy) SA + tril<=(CKy) V
//   S_L = S0 * M + U  with M = diag(dL) + (W^T Bt).*dL_j
// LDS 40.7 KB -> 4 blocks/CU: {aCb,rCb}|{WT,SAT} alias; vLb dropped (use vLT
// transposed for the solve); Am/Cm stored bf16.

__global__ __launch_bounds__(256, 4) void rwkv_chunk_pre(
    const bf16* __restrict__ rr, const bf16* __restrict__ lw,
    const bf16* __restrict__ kk_s, const bf16* __restrict__ kkv,
    const bf16* __restrict__ aam, const bf16* __restrict__ vv,
    bf16* __restrict__ wbufb, bf16* __restrict__ sabufb,
    bf16* __restrict__ abybufb, bf16* __restrict__ ckybufb,
    bf16* __restrict__ ubufP, bf16* __restrict__ mbufT)
{
  __shared__ bf16 Amb[LCH][34], Cmb[LCH][34];
  __shared__ float wtot[4][64];
  __shared__ float lcl[64];
  __shared__ float dll[64];
  __shared__ bf16 bTb[LCH][72], kTb[LCH][72];
  __shared__ bf16 bTT[64][40], kTT[64][40], vLT[64][40];
  __shared__ bf16 uni[5120];   // {aCb,rCb}[32][72] | {WT,SAT}[64][40]
  bf16 (*aCb)[72] = (bf16(*)[72])uni;
  bf16 (*rCb)[72] = (bf16(*)[72])(uni + 2304);
  bf16 (*WT)[40]  = (bf16(*)[40])uni;
  bf16 (*SAT)[40] = (bf16(*)[40])(uni + 2560);

  const int ch = blockIdx.x;
  const int c  = ch & (NCH - 1);
  const int bh = ch >> 6;
  const int b  = bh >> 4, h = bh & 15;
  const int tid = threadIdx.x, wv = tid >> 6, ln = tid & 63;
  const int lm = ln & 15, kg = ln >> 4;
  const size_t base = ((size_t)(b*T_ + c*LCH) * C_) + h*N_ + ln;

  // --- phase 1: cumulative log-decay + load/scale into LDS (both layouts) ---
  float lwr[8], lcE[8];
  {
    float run = 0.f;
#pragma unroll
    for (int q = 0; q < 8; ++q) {
      lwr[q] = frombf(lw[base + (size_t)(wv*8 + q) * C_]);
      lcE[q] = run; run += lwr[q];
    }
    wtot[wv][ln] = run;
  }
  __syncthreads();
  {
    float pre = 0.f;
    for (int w2 = 0; w2 < wv; ++w2) pre += wtot[w2][ln];
    if (wv == 0) lcl[ln] = wtot[0][ln] + wtot[1][ln] + wtot[2][ln] + wtot[3][ln];
#pragma unroll
    for (int q = 0; q < 8; ++q) lcE[q] += pre;
  }
#pragma unroll
  for (int q = 0; q < 8; ++q) {
    const int s = wv*8 + q;
    const size_t off = base + (size_t)s * C_;
    float kkx = frombf(kkv[off]), aax = frombf(aam[off]);
    float kx = frombf(kk_s[off]), rx = frombf(rr[off]);
    float lcI = lcE[q] + lwr[q];
    float eIm = __expf(-lcI);
    float eI  = __builtin_amdgcn_rcpf(eIm);   // exp(lcI) = 1/exp(-lcI)
    float av = -kkx * __expf(lcE[q]);
    float bv = kkx * aax * eIm;
    float kv2 = kx * eIm;
    float rv = rx * eI;
    bf16 vxb = vv[off];
    aCb[s][ln] = tobf(av);  rCb[s][ln] = tobf(rv);
    bTb[s][ln] = tobf(bv);  kTb[s][ln] = tobf(kv2);
    bTT[ln][s] = tobf(bv);  kTT[ln][s] = tobf(kv2);  vLT[ln][s] = vxb;
  }
  __syncthreads();
  if (tid < 64) dll[tid] = __expf(lcl[tid]);  // barriers below make it visible

  // --- phase 2: MFMA, one 32x32 (K=64) product per wave ---
  {
    const bf16 (*Ab)[72] = (wv < 2) ? aCb : rCb;
    const bf16 (*Bb)[72] = (wv & 1) ? kTb : bTb;
#pragma unroll
    for (int mt = 0; mt < 2; ++mt)
#pragma unroll
      for (int nt = 0; nt < 2; ++nt) {
        f32x4 acc = {};
#pragma unroll
        for (int ks = 0; ks < 2; ++ks) {
          bf16x8 af = *(const bf16x8*)&Ab[mt*16 + lm][ks*32 + kg*8];
          bf16x8 bq = *(const bf16x8*)&Bb[nt*16 + lm][ks*32 + kg*8];
          acc = mfma16x16x32(af, bq, acc);
        }
        const int row0 = mt*16 + kg*4, col = nt*16 + lm;
#pragma unroll
        for (int q = 0; q < 4; ++q) {
          float v = acc[q];
          if (wv == 0)      Amb[row0+q][col] = tobf(v);
          else if (wv == 1) Cmb[row0+q][col] = tobf(v);
          else {
            bf16 bv2 = tobf(col <= row0+q ? v : 0.f);  // tril<= mask
            if (wv == 2) abybufb[(size_t)ch*1024 + (row0+q)*32 + col] = bv2;
            else         ckybufb[(size_t)ch*1024 + (row0+q)*32 + col] = bv2;
          }
        }
      }
  }
  __syncthreads();

  // --- phase 3a: preload solve inputs to registers (aCb/Cmb/vLT reads) -----
  float Xr[32], amr[32];
  if (wv == 0) {
#pragma unroll
    for (int s = 0; s < 32; ++s) amr[s] = frombf(Amb[s][ln & 31]);
#pragma unroll
    for (int s = 0; s < 32; ++s) Xr[s] = frombf(aCb[s][ln]);
  } else if (wv == 1) {
    float cmr[32];
#pragma unroll
    for (int s = 0; s < 32; ++s) {
      amr[s] = frombf(Amb[s][ln & 31]);
      cmr[s] = frombf(Cmb[s][ln & 31]);
    }
#pragma unroll
    for (int s = 0; s < 32; ++s) Xr[s] = 0.f;
#pragma unroll
    for (int u = 0; u < 31; ++u) {
      float v = frombf(vLT[ln][u]);   // == V[u][ln]
#pragma unroll
      for (int s = u + 1; s < 32; ++s) Xr[s] += rdlane(cmr[s], u) * v;
    }
  }
  __syncthreads();   // aCb reads complete before WT/SAT writes into alias

  // --- phase 3b: register forward-substitution; write WT/SAT --------------
  if (wv < 2) {
#pragma unroll
    for (int s = 1; s < 32; ++s) {
      float acc = Xr[s];
#pragma unroll
      for (int u = 0; u < s; ++u) acc += rdlane(amr[s], u) * Xr[u];
      Xr[s] = acc;
    }
    if (wv == 0) {
#pragma unroll
      for (int s = 0; s < 32; ++s) {
        bf16 bv = tobf(Xr[s]);
        WT[ln][s] = bv;
        wbufb[(size_t)ch*2048 + s*64 + ln] = bv;
      }
    } else {
#pragma unroll
      for (int s = 0; s < 32; ++s) {
        bf16 bv = tobf(Xr[s]);
        SAT[ln][s] = bv;
        sabufb[(size_t)ch*2048 + s*64 + ln] = bv;
      }
    }
  }
  __syncthreads();

  // --- phase 5: U, M (64x64, K=32) via MFMA; packed-layout b64 stores ------
  {
    const int mt = wv;
    bf16x8 aS = *(const bf16x8*)&SAT[mt*16 + lm][kg*8];
    bf16x8 aV = *(const bf16x8*)&vLT[mt*16 + lm][kg*8];
    bf16x8 aW = *(const bf16x8*)&WT[mt*16 + lm][kg*8];
#pragma unroll
    for (int nt = 0; nt < 4; ++nt) {
      bf16x8 bB = *(const bf16x8*)&bTT[nt*16 + lm][kg*8];
      bf16x8 bK = *(const bf16x8*)&kTT[nt*16 + lm][kg*8];
      f32x4 aU = {}, aG = {};
      aU = mfma16x16x32(aS, bB, aU);
      aU = mfma16x16x32(aV, bK, aU);
      aG = mfma16x16x32(aW, bB, aG);
      const int i0r = mt*16 + kg*4, col = nt*16 + lm;
      float dl = dll[col];
      uint2 up;
      up.x = (unsigned int)bfbits(aU[0]*dl) | ((unsigned int)bfbits(aU[1]*dl) << 16);
      up.y = (unsigned int)bfbits(aU[2]*dl) | ((unsigned int)bfbits(aU[3]*dl) << 16);
      *(uint2*)(ubufP + (size_t)ch*4096 + (mt*4 + nt)*256 + ln*4) = up;
      float m0 = (aG[0] + (i0r+0 == col ? 1.f : 0.f)) * dl;
      float m1 = (aG[1] + (i0r+1 == col ? 1.f : 0.f)) * dl;
      float m2 = (aG[2] + (i0r+2 == col ? 1.f : 0.f)) * dl;
      float m3 = (aG[3] + (i0r+3 == col ? 1.f : 0.f)) * dl;
      uint2 mp;
      mp.x = (unsigned int)bfbits(m0) | ((unsigned int)bfbits(m1) << 16);
      mp.y = (unsigned int)bfbits(m2) | ((unsigned int)bfbits(m3) << 16);
      const int laned = (((mt*2) + (kg >> 1)) & 3) * 16 + lm;
      *(uint2*)(mbufT + (size_t)ch*4096 + (nt*2 + (mt >> 1))*512
                + laned*8 + (kg & 1)*4) = mp;
    }
  }
}

// Phase B: serial over chunks; 32 blocks (one per bh) x 4 waves, no barriers.
__global__ __launch_bounds__(256) void rwkv_chunk_state(
    const bf16* __restrict__ mbufT, const bf16* __restrict__ ubufP,
    bf16* __restrict__ s0bufb)
{
  __shared__ bf16 Sst[4][16][72];
  const int bh = blockIdx.x;
  const int tid = threadIdx.x, wv = tid >> 6, ln = tid & 63;
  const int lm = ln & 15, kg = ln >> 4;

#pragma unroll
  for (int r = 0; r < 16; ++r) {
    Sst[wv][r][ln] = tobf(0.f);
    if (ln < 8) Sst[wv][r][64 + ln] = tobf(0.f);
  }

  bf16x8 BfA[4][2], BfB[4][2];
  uint2 UpA[4], UpB[4];
  auto prefetch = [&](bf16x8 (&Bf)[4][2], uint2 (&Up)[4], int c) {
    const size_t chp = (size_t)(bh*NCH + c) * 4096;
#pragma unroll
    for (int nt = 0; nt < 4; ++nt) {
      Bf[nt][0] = *(const bf16x8*)(mbufT + chp + (nt*2 + 0)*512 + ln*8);
      Bf[nt][1] = *(const bf16x8*)(mbufT + chp + (nt*2 + 1)*512 + ln*8);
      Up[nt]    = *(const uint2*) (ubufP + chp + (wv*4 + nt)*256 + ln*4);
    }
  };
  prefetch(BfA, UpA, 0);
  prefetch(BfB, UpB, 1);

  auto body = [&](bf16x8 (&Bf)[4][2], uint2 (&Up)[4], int c) {
    const size_t ch4 = (size_t)(bh*NCH + c) * 4096;
    const int sr = ln >> 2, sc = (ln & 3) * 16;
    uint4 v0 = *(const uint4*)&Sst[wv][sr][sc];
    uint4 v1 = *(const uint4*)&Sst[wv][sr][sc + 8];
    *(uint4*)(s0bufb + ch4 + (size_t)(wv*16 + sr)*64 + sc) = v0;
    *(uint4*)(s0bufb + ch4 + (size_t)(wv*16 + sr)*64 + sc + 8) = v1;
    bf16x8 A0 = *(const bf16x8*)&Sst[wv][lm][kg*8];
    bf16x8 A1 = *(const bf16x8*)&Sst[wv][lm][32 + kg*8];
    f32x4 acc[4];
#pragma unroll
    for (int nt = 0; nt < 4; ++nt) {
      acc[nt][0] = bf2f((unsigned short)(Up[nt].x & 0xffff));
      acc[nt][1] = bf2f((unsigned short)(Up[nt].x >> 16));
      acc[nt][2] = bf2f((unsigned short)(Up[nt].y & 0xffff));
      acc[nt][3] = bf2f((unsigned short)(Up[nt].y >> 16));
      acc[nt] = mfma16x16x32(A0, Bf[nt][0], acc[nt]);
      acc[nt] = mfma16x16x32(A1, Bf[nt][1], acc[nt]);
    }
    int cp = c + 2; if (cp > NCH - 1) cp = NCH - 1;
    prefetch(Bf, Up, cp);
#pragma unroll
    for (int nt = 0; nt < 4; ++nt)
#pragma unroll
      for (int q = 0; q < 4; ++q)
        Sst[wv][kg*4 + q][nt*16 + lm] = tobf(acc[nt][q]);
  };

  for (int cc = 0; cc < NCH; cc += 2) {
    body(BfA, UpA, cc);
    body(BfB, UpB, cc + 1);
  }
}

// Phase C: per chunk-head: SA = W*S0^T + SAll; y = Rt*S0^T + ABl*SAo + CKl*V;
// then FUSED groupnorm (group == head, size 64) + bonus + gate -> zb (bf16).
__global__ __launch_bounds__(256, 4) void rwkv_chunk_out(
    const bf16* __restrict__ rr, const bf16* __restrict__ lw,
    const bf16* __restrict__ vv, const bf16* __restrict__ kks,
    const bf16* __restrict__ gg, const bf16* __restrict__ s0bufb,
    const bf16* __restrict__ wbufb, const bf16* __restrict__ sabufb,
    const bf16* __restrict__ abybufb, const bf16* __restrict__ ckybufb,
    const float* __restrict__ faaaa, const float* __restrict__ lnw,
    const float* __restrict__ lnb, bf16* __restrict__ zb)
{
  __shared__ bf16 S0b[64][72];                    // B^T layout: [i][j]
  __shared__ bf16 ABl[LCH][40], CKl[LCH][40];     // A layouts: [s][u]
  __shared__ bf16 SAot[64][40], VlT[64][40];      // B^T layouts: [i][u]
  __shared__ float wtot[4][64];
  __shared__ float bonus[LCH];
  __shared__ float uni2f[2304];  // {Wb,Rlb}[32][72] bf16 | Yl[32][68] f32
  bf16 (*Wb)[72]  = (bf16(*)[72])uni2f;
  bf16 (*Rlb)[72] = (bf16(*)[72])((bf16*)uni2f + 2304);
  float (*Yl)[68] = (float(*)[68])uni2f;

  const int ch = blockIdx.x;
  const int c = ch & (NCH - 1), bh = ch >> 6, b = bh >> 4, h = bh & 15;
  const int tid = threadIdx.x, wv = tid >> 6, ln = tid & 63;
  const int lm = ln & 15, kg = ln >> 4;
  const size_t base = ((size_t)(b*T_ + c*LCH) * C_) + h*N_ + ln;

  float lwr[8], lcE[8];
  {
    float run = 0.f;
#pragma unroll
    for (int q = 0; q < 8; ++q) {
      lwr[q] = frombf(lw[base + (size_t)(wv*8 + q) * C_]);
      lcE[q] = run; run += lwr[q];
    }
    wtot[wv][ln] = run;
  }
  __syncthreads();
  {
    float pre = 0.f;
    for (int w2 = 0; w2 < wv; ++w2) pre += wtot[w2][ln];
#pragma unroll
    for (int q = 0; q < 8; ++q) lcE[q] += pre;
  }
  const float fa = faaaa[h*N_ + ln];
#pragma unroll
  for (int q = 0; q < 8; ++q) {
    const int s = wv*8 + q;
    const size_t off = base + (size_t)s * C_;
    float rf = frombf(rr[off]);
    Rlb[s][ln] = tobf(rf * __expf(lcE[q] + lwr[q]));
    VlT[ln][s] = vv[off];
    float rk = allred64(rf * frombf(kks[off]) * fa);   // bonus dot
    if (ln == 0) bonus[s] = rk;
  }
#pragma unroll
  for (int t = 0; t < 2; ++t) {
    int cc2 = tid*2 + t; int ri = cc2 >> 3, co = (cc2 & 7) * 8;
    *(uint4*)&S0b[ri][co] = *(const uint4*)(s0bufb + (size_t)ch*4096 + ri*64 + co);
  }
  { int ri = tid >> 3, co = (tid & 7) * 8;
    *(uint4*)&Wb[ri][co] = *(const uint4*)(wbufb + (size_t)ch*2048 + ri*64 + co); }
  if (tid < 128) {
    int ri = tid >> 2, co = (tid & 3) * 8;
    *(uint4*)&ABl[ri][co] = *(const uint4*)(abybufb + (size_t)ch*1024 + ri*32 + co);
  } else {
    int t2 = tid - 128; int ri = t2 >> 2, co = (t2 & 3) * 8;
    *(uint4*)&CKl[ri][co] = *(const uint4*)(ckybufb + (size_t)ch*1024 + ri*32 + co);
  }
  __syncthreads();

  const int mt = wv >> 1, ntb = (wv & 1) * 2;
#pragma unroll
  for (int t = 0; t < 2; ++t) {
    const int nt = ntb + t;
    const int row0 = mt*16 + kg*4, col = nt*16 + lm;
    f32x4 acc;
#pragma unroll
    for (int q = 0; q < 4; ++q)
      acc[q] = frombf(sabufb[(size_t)ch*2048 + (row0+q)*64 + col]);
#pragma unroll
    for (int ks = 0; ks < 2; ++ks) {
      bf16x8 af = *(const bf16x8*)&Wb[mt*16 + lm][ks*32 + kg*8];
      bf16x8 bq = *(const bf16x8*)&S0b[nt*16 + lm][ks*32 + kg*8];
      acc = mfma16x16x32(af, bq, acc);
    }
#pragma unroll
    for (int q = 0; q < 4; ++q) SAot[col][row0+q] = tobf(acc[q]);
  }
  __syncthreads();

  f32x4 yacc[2];
#pragma unroll
  for (int t = 0; t < 2; ++t) {
    const int nt = ntb + t;
    f32x4 acc = {};
#pragma unroll
    for (int ks = 0; ks < 2; ++ks) {
      bf16x8 af = *(const bf16x8*)&Rlb[mt*16 + lm][ks*32 + kg*8];
      bf16x8 bq = *(const bf16x8*)&S0b[nt*16 + lm][ks*32 + kg*8];
      acc = mfma16x16x32(af, bq, acc);
    }
    {
      bf16x8 af = *(const bf16x8*)&ABl[mt*16 + lm][kg*8];
      bf16x8 bq = *(const bf16x8*)&SAot[nt*16 + lm][kg*8];
      acc = mfma16x16x32(af, bq, acc);
    }
    {
      bf16x8 af = *(const bf16x8*)&CKl[mt*16 + lm][kg*8];
      bf16x8 bq = *(const bf16x8*)&VlT[nt*16 + lm][kg*8];
      acc = mfma16x16x32(af, bq, acc);
    }
    yacc[t] = acc;
  }
  __syncthreads();   // all Rlb reads done before Yl overwrites the alias

#pragma unroll
  for (int t = 0; t < 2; ++t) {
    const int nt = ntb + t;
    const int row0 = mt*16 + kg*4, col = nt*16 + lm;
#pragma unroll
    for (int q = 0; q < 4; ++q) Yl[row0 + q][col] = yacc[t][q];
  }
  __syncthreads();

  // fused groupnorm + bonus + gate: thread = (row s2, 8 cols)
  {
    const int s2 = tid >> 3, c0 = (tid & 7) * 8;
    float yv[8]; float sum = 0.f;
#pragma unroll
    for (int i = 0; i < 8; ++i) { yv[i] = Yl[s2][c0 + i]; sum += yv[i]; }
#pragma unroll
    for (int m = 1; m < 8; m <<= 1) sum += __shfl_xor(sum, m, 64);
    const float mean = sum * (1.f/64.f);
    float ss = 0.f;
#pragma unroll
    for (int i = 0; i < 8; ++i) { float d = yv[i] - mean; ss += d * d; }
#pragma unroll
    for (int m = 1; m < 8; m <<= 1) ss += __shfl_xor(ss, m, 64);
    const float inv = rsqrtf(ss * (1.f/64.f) + 6.4e-4f);
    const float bn = bonus[s2];
    const size_t trow = (size_t)(b*T_ + c*LCH + s2) * C_ + h*N_ + c0;
    bf16 zout[8];
#pragma unroll
    for (int i = 0; i < 8; ++i) {
      float gn = (yv[i] - mean) * inv * lnw[h*N_ + c0 + i] + lnb[h*N_ + c0 + i];
      float z = (gn + bn * frombf(VlT[c0 + i][s2])) * frombf(gg[trow + i]);
      zout[i] = tobf(z);
    }
    *(uint4*)(zb + trow) = *(const uint4*)&zout[0];
  }
}

// ---------------- driver ----------------------------------------------------
extern "C" void kernel_launch(void* const* d_in, const int* in_sizes, int n_in,
                              void* d_out, int out_size, void* d_ws, size_t ws_size,
                              hipStream_t stream)
{
  const float* x     = (const float*)d_in[0];
  const float* maa_x = (const float*)d_in[1];
  const float* maa_r = (const float*)d_in[2];
  const float* maa_w = (const float*)d_in[3];
  const float* maa_k = (const float*)d_in[4];
  const float* maa_v = (const float*)d_in[5];
  const float* maa_a = (const float*)d_in[6];
  const float* maa_g = (const float*)d_in[7];
  const float* tdec  = (const float*)d_in[8];
  const float* faaaa = (const float*)d_in[9];
  const float* aaaaa = (const float*)d_in[10];
  const float* maa_w1= (const float*)d_in[11];
  const float* maa_w2= (const float*)d_in[12];
  const float* dec_w1= (const float*)d_in[13];
  const float* dec_w2= (const float*)d_in[14];
  const float* aaa_w1= (const float*)d_in[15];
  const float* aaa_w2= (const float*)d_in[16];
  const float* kkk_w1= (const float*)d_in[17];
  const float* kkk_w2= (const float*)d_in[18];
  const float* gate_w1=(const float*)d_in[19];
  const float* gate_w2=(const float*)d_in[20];
  const float* W_r   = (const float*)d_in[21];
  const float* W_k   = (const float*)d_in[22];
  const float* W_v   = (const float*)d_in[23];
  const float* W_o   = (const float*)d_in[24];
  const float* lnw   = (const float*)d_in[25];
  const float* lnb   = (const float*)d_in[26];

  char* ws = (char*)d_ws;
  size_t cur = 0;
  auto alloc = [&](size_t bytes) -> void* {
    void* p = ws + cur; cur += (bytes + 255) & ~(size_t)255; return p;
  };
  const size_t HBT = (size_t)BT_ * C_ * 2;  // bf16 activation buffer

  // ---- persistent (activations bf16) ----
  bf16* rb   = (bf16*)alloc(HBT);
  bf16* kb   = (bf16*)alloc(HBT);   // UNscaled k (for kk_normalize)
  bf16* ksb  = (bf16*)alloc(HBT);   // scaled k (for scan + bonus)
  bf16* vb   = (bf16*)alloc(HBT);
  bf16* gbb  = (bf16*)alloc(HBT);
  bf16* WtR  = (bf16*)alloc((size_t)C_*C_*2);
  bf16* WtK  = (bf16*)alloc((size_t)C_*C_*2);
  bf16* WtV  = (bf16*)alloc((size_t)C_*C_*2);
  bf16* WtO  = (bf16*)alloc((size_t)C_*C_*2);
  bf16* w1t  = (bf16*)alloc((size_t)192*C_*2);
  bf16* w2t  = (bf16*)alloc((size_t)6*C_*32*2);
  bf16* d1t  = (bf16*)alloc((size_t)64*C_*2);
  bf16* d2t  = (bf16*)alloc((size_t)C_*64*2);
  bf16* a1t  = (bf16*)alloc((size_t)64*C_*2);
  bf16* a2t  = (bf16*)alloc((size_t)C_*64*2);
  bf16* k1t  = (bf16*)alloc((size_t)64*C_*2);
  bf16* k2t  = (bf16*)alloc((size_t)C_*64*2);
  bf16* g1t  = (bf16*)alloc((size_t)128*C_*2);
  bf16* g2t  = (bf16*)alloc((size_t)C_*128*2);
  bf16* lwb  = (bf16*)alloc(HBT);
  bf16* kkb  = (bf16*)alloc(HBT);
  bf16* aamt = (bf16*)alloc(HBT);
  bf16* s0bufb = kkb;                 // overlay: kkb+aamt dead after chunk_pre

  // ---- union region ----
  const size_t ubase = cur;
  bf16* mtmpb = (bf16*)alloc(HBT);
  bf16* xinb = (bf16*)alloc(HBT);
  bf16* xb   = (bf16*)alloc(HBT);
  bf16* mixb = (bf16*)alloc((size_t)BT_*192*2);
  bf16* xbr[6];
  for (int s = 0; s < 6; ++s) xbr[s] = (bf16*)alloc(HBT);
  bf16* h64k = (bf16*)alloc((size_t)BT_*64*2);
  bf16* h64d = (bf16*)alloc((size_t)BT_*64*2);
  bf16* h64a = (bf16*)alloc((size_t)BT_*64*2);
  bf16* h128b= (bf16*)alloc((size_t)BT_*128*2);
  const size_t tmp_end = cur;
  cur = ubase;  // overlay
  bf16*  wbufb   = (bf16*)alloc((size_t)CHD*2048*2);
  bf16*  sabufb  = (bf16*)alloc((size_t)CHD*2048*2);
  bf16*  abybufb = (bf16*)alloc((size_t)CHD*1024*2);
  bf16*  ckybufb = (bf16*)alloc((size_t)CHD*1024*2);
  bf16*  ubufP   = (bf16*)alloc((size_t)CHD*4096*2);
  bf16*  mbufT   = (bf16*)alloc((size_t)CHD*4096*2);
  bf16*  zb      = (bf16*)ubufP;   // alias: ubufP dead after chunk_state
  if (tmp_end > cur) cur = tmp_end;
  const size_t need = cur;
  (void)in_sizes; (void)n_in; (void)out_size;

  if (ws_size < need) {
    ws_diag<<<1, 1, 0, stream>>>((float)ws_size, (float)need, (float*)d_out);
    return;
  }

  PrepArgs pa;
  pa.src[0] = W_r;  pa.dst[0] = WtR;
  pa.src[1] = W_k;  pa.dst[1] = WtK;
  pa.src[2] = W_v;  pa.dst[2] = WtV;
  pa.src[3] = W_o;  pa.dst[3] = WtO;
  pa.src[4] = maa_w1; pa.dst[4] = w1t;
  for (int s = 0; s < 6; ++s) { pa.src[5+s] = maa_w2 + (size_t)s*32*C_; pa.dst[5+s] = w2t + (size_t)s*C_*32; }
  pa.src[11] = dec_w1; pa.dst[11] = d1t;
  pa.src[12] = dec_w2; pa.dst[12] = d2t;
  pa.src[13] = aaa_w1; pa.dst[13] = a1t;
  pa.src[14] = aaa_w2; pa.dst[14] = a2t;
  pa.src[15] = kkk_w1; pa.dst[15] = k1t;
  pa.src[16] = kkk_w2; pa.dst[16] = k2t;
  pa.src[17] = gate_w1; pa.dst[17] = g1t;
  pa.src[18] = gate_w2; pa.dst[18] = g2t;
  prep_weights<<<dim3(1024, 19), 256, 0, stream>>>(pa);

  const int EW_GRID = (BT_ * C_) / 256;  // 16384
  xin_k<<<EW_GRID, 256, 0, stream>>>(x, maa_x, xinb, xb);

  gemm_bt<1><<<dim3(64, 3), 256, 0, stream>>>(xinb, C_, w1t, C_, mixb, 192, C_);

  Mix6Args ma;
  ma.maa[0] = maa_r; ma.maa[1] = maa_w; ma.maa[2] = maa_k;
  ma.maa[3] = maa_v; ma.maa[4] = maa_a; ma.maa[5] = maa_g;
  for (int s = 0; s < 6; ++s) ma.out[s] = xbr[s];
  mix_combine<<<dim3(64, 16, 6), 256, 0, stream>>>(mixb, w2t, xb, ma);

  // r, k, v batched (one launch, bf16 out)
  RkvArgs ra;
  ra.A[0] = xbr[0]; ra.Bt[0] = WtR; ra.Cq[0] = rb;
  ra.A[1] = xbr[2]; ra.Bt[1] = WtK; ra.Cq[1] = kb;
  ra.A[2] = xbr[3]; ra.Bt[2] = WtV; ra.Cq[2] = vb;
  gemm128_rkv<<<dim3(32, 8, 3), 256, 0, stream>>>(ra);

  // batched small projections: k1 (tanh), d1 (tanh), a1 (raw), g1 (tanh)
  Proj4Args p4;
  p4.A[0] = xbr[2]; p4.Bt[0] = k1t; p4.out[0] = h64k; p4.N[0] = 64;  p4.tnh[0] = 1;
  p4.A[1] = xbr[1]; p4.Bt[1] = d1t; p4.out[1] = h64d; p4.N[1] = 64;  p4.tnh[1] = 1;
  p4.A[2] = xbr[4]; p4.Bt[2] = a1t; p4.out[2] = h64a; p4.N[2] = 64;  p4.tnh[2] = 0;
  p4.A[3] = xbr[5]; p4.Bt[3] = g1t; p4.out[3] = h128b; p4.N[3] = 128; p4.tnh[3] = 1;
  proj4<<<dim3(64, 2, 4), 256, 0, stream>>>(p4);

  // batched epilogue GEMMs: z0 kk-add, z1 w-finalize (kb->ksb), z2 a, z3 g
  Ep4Args ea;
  ea.A[0] = h64k;  ea.Bt[0] = k2t; ea.Cout[0] = mtmpb; ea.K[0] = 64;  ea.epi[0] = 2; ea.aux[0] = nullptr;
  ea.A[1] = h64d;  ea.Bt[1] = d2t; ea.Cout[1] = lwb;   ea.K[1] = 64;  ea.epi[1] = 5; ea.aux[1] = tdec;
  ea.A[2] = h64a;  ea.Bt[2] = a2t; ea.Cout[2] = aamt;  ea.K[2] = 64;  ea.epi[2] = 4; ea.aux[2] = aaaaa;
  ea.A[3] = h128b; ea.Bt[3] = g2t; ea.Cout[3] = gbb;   ea.K[3] = 128; ea.epi[3] = 2; ea.aux[3] = nullptr;
  ea.kin = kb; ea.ksout = ksb;
  gemm128_ep4<<<dim3(32, 8, 4), 256, 0, stream>>>(ea);

  kk_normalize<<<BT_, 256, 0, stream>>>(kb, mtmpb, kkb);

  // ---- chunked scan (scaled k = ksb) ----
  rwkv_chunk_pre<<<CHD, 256, 0, stream>>>(rb, lwb, ksb, kkb, aamt, vb,
      wbufb, sabufb, abybufb, ckybufb, ubufP, mbufT);
  rwkv_chunk_state<<<32, 256, 0, stream>>>(mbufT, ubufP, s0bufb);
  rwkv_chunk_out<<<CHD, 256, 0, stream>>>(rb, lwb, vb, ksb, gbb, s0bufb,
      wbufb, sabufb, abybufb, ckybufb, faaaa, lnw, lnb, zb);

  gemm128<0><<<dim3(32, 8), 256, 0, stream>>>(zb, C_, WtO, C_, d_out, C_, C_);
}

// Round 18
// 281.884 us; speedup vs baseline: 5.7964x; 1.0082x over previous
//
#include <hip/hip_runtime.h>
#include <hip/hip_bf16.h>

using bf16 = __hip_bfloat16;
using bf16x8 = __attribute__((ext_vector_type(8))) short;  // 8 bf16 (4 VGPRs)
using f32x4 = __attribute__((ext_vector_type(4))) float;

#define B_ 2
#define T_ 2048
#define C_ 1024
#define BT_ (B_*T_)
#define H_ 16
#define N_ 64
#define LCH 32            // scan chunk length
#define NCH (T_/LCH)      // 64 chunks per head
#define CHD (B_*H_*NCH)   // 2048 chunk-heads

__device__ __forceinline__ float allred64(float v) {
#pragma unroll
  for (int m = 1; m < 64; m <<= 1) v += __shfl_xor(v, m, 64);
  return v;
}

__device__ __forceinline__ bf16 tobf(float f) { return __float2bfloat16(f); }
__device__ __forceinline__ float frombf(bf16 b) { return __bfloat162float(b); }
__device__ __forceinline__ float bf2f(unsigned short u) {
  unsigned int x = ((unsigned int)u) << 16;
  return __builtin_bit_cast(float, x);
}
__device__ __forceinline__ unsigned short bfbits(float f) {
  return __builtin_bit_cast(unsigned short, __float2bfloat16(f));
}
__device__ __forceinline__ float rdlane(float v, int m) {
  return __builtin_bit_cast(float,
      __builtin_amdgcn_readlane(__builtin_bit_cast(int, v), m));
}
// overflow-safe fast tanh via hardware exp (<=4 ulp; outputs bf16-rounded)
__device__ __forceinline__ float fast_tanh(float x) {
  float t = __expf(-2.f * fabsf(x));
  float r = (1.f - t) / (1.f + t);
  return copysignf(r, x);
}

__device__ __forceinline__ f32x4 mfma16x16x32(bf16x8 a, bf16x8 b, f32x4 c) {
  return __builtin_amdgcn_mfma_f32_16x16x32_bf16(a, b, c, 0, 0, 0);
}

// async global->LDS, 16B per lane (dest = wave-uniform base + lane*16)
typedef const __attribute__((address_space(1))) unsigned int* gas_ptr;
typedef __attribute__((address_space(3))) unsigned int* las_ptr;
__device__ __forceinline__ void gload16(const void* g, void* l) {
  __builtin_amdgcn_global_load_lds((gas_ptr)g, (las_ptr)l, 16, 0, 0);
}

// ---------------- ws_size diagnostic ----------------------------------------
__global__ void ws_diag(float a, float b, float* out) { out[0] = a; out[1] = b; }

// ---------------- weight transpose + bf16 cast (19 jobs, one launch) -------
struct PrepArgs {
  const float* src[19];
  bf16* dst[19];
};
__constant__ int kTR[19] = {1024,1024,1024,1024, 1024, 32,32,32,32,32,32,
                            1024,64, 1024,64, 1024,64, 1024,128};
__constant__ int kTC[19] = {1024,1024,1024,1024, 192, 1024,1024,1024,1024,1024,1024,
                            64,1024, 64,1024, 64,1024, 128,1024};

__global__ __launch_bounds__(256) void prep_weights(PrepArgs pa) {
  const int job = blockIdx.y;
  const int R = kTR[job], Cc = kTC[job];
  const int ntx = Cc >> 5, nty = R >> 5;
  const int tile = blockIdx.x;
  if (tile >= ntx * nty) return;
  const int tx = tile % ntx, ty = tile / ntx;
  const float* __restrict__ src = pa.src[job];
  bf16* __restrict__ dst = pa.dst[job];
  __shared__ float tl[32][33];
  const int lx = threadIdx.x & 31, ly = threadIdx.x >> 5;  // 32 x 8
#pragma unroll
  for (int q = 0; q < 4; ++q)
    tl[ly + 8*q][lx] = src[(size_t)(ty*32 + ly + 8*q) * Cc + tx*32 + lx];
  __syncthreads();
#pragma unroll
  for (int q = 0; q < 4; ++q)
    dst[(size_t)(tx*32 + ly + 8*q) * R + ty*32 + lx] = tobf(tl[lx][ly + 8*q]);
}

// ------- GEMM 64-tile -------------------------------------------------------
template<int EPI>
__global__ __launch_bounds__(256) void gemm_bt(
    const bf16* __restrict__ A, int lda,
    const bf16* __restrict__ Bt, int ldb,
    void* __restrict__ Cout, int ldc, int K)
{
  __shared__ short As[64][40];
  __shared__ short Bs[64][40];
  const int bm0 = blockIdx.x * 64;
  const int bn0 = blockIdx.y * 64;
  const int tid = threadIdx.x;
  const int wave = tid >> 6, lane = tid & 63;
  const int lm = lane & 15, kg = lane >> 4;
  const int srow = tid >> 2, scol = (tid & 3) * 8;
  f32x4 acc[4] = {};
  const size_t abase = (size_t)(bm0 + srow) * lda + scol;
  const size_t bbase = (size_t)(bn0 + srow) * ldb + scol;
  for (int k0 = 0; k0 < K; k0 += 32) {
    *(uint4*)&As[srow][scol] = *(const uint4*)(A + abase + k0);
    *(uint4*)&Bs[srow][scol] = *(const uint4*)(Bt + bbase + k0);
    __syncthreads();
    bf16x8 af = *(const bf16x8*)&As[wave*16 + lm][kg*8];
#pragma unroll
    for (int f = 0; f < 4; ++f) {
      bf16x8 bfr = *(const bf16x8*)&Bs[f*16 + lm][kg*8];
      acc[f] = mfma16x16x32(af, bfr, acc[f]);
    }
    __syncthreads();
  }
  const int row0 = bm0 + wave*16 + kg*4;
  const int col0 = bn0 + lm;
#pragma unroll
  for (int f = 0; f < 4; ++f) {
#pragma unroll
    for (int q = 0; q < 4; ++q) {
      float val = acc[f][q];
      size_t o = (size_t)(row0 + q) * ldc + col0 + f*16;
      if (EPI == 0)      ((float*)Cout)[o] = val;
      else if (EPI == 1) ((bf16*)Cout)[o] = tobf(fast_tanh(val));
      else               ((bf16*)Cout)[o] = tobf(val);
    }
  }
}

// ------- batched small projections: k1/d1/a1 (N=64) + g1 (N=128) -----------
struct Proj4Args { const bf16* A[4]; const bf16* Bt[4]; bf16* out[4];
                   int N[4]; int tnh[4]; };
__global__ __launch_bounds__(256) void proj4(Proj4Args p4) {
  const int z = blockIdx.z;
  const int Nn = p4.N[z];
  const int bn0 = blockIdx.y * 64;
  if (bn0 >= Nn) return;
  __shared__ short As[64][40];
  __shared__ short Bs[64][40];
  const bf16* __restrict__ A  = p4.A[z];
  const bf16* __restrict__ Bt = p4.Bt[z];
  bf16* __restrict__ out = p4.out[z];
  const int tnh = p4.tnh[z];
  const int bm0 = blockIdx.x * 64;
  const int tid = threadIdx.x;
  const int wave = tid >> 6, lane = tid & 63;
  const int lm = lane & 15, kg = lane >> 4;
  const int srow = tid >> 2, scol = (tid & 3) * 8;
  f32x4 acc[4] = {};
  const size_t abase = (size_t)(bm0 + srow) * C_ + scol;
  const size_t bbase = (size_t)(bn0 + srow) * C_ + scol;
  for (int k0 = 0; k0 < C_; k0 += 32) {
    *(uint4*)&As[srow][scol] = *(const uint4*)(A + abase + k0);
    *(uint4*)&Bs[srow][scol] = *(const uint4*)(Bt + bbase + k0);
    __syncthreads();
    bf16x8 af = *(const bf16x8*)&As[wave*16 + lm][kg*8];
#pragma unroll
    for (int f = 0; f < 4; ++f) {
      bf16x8 bfr = *(const bf16x8*)&Bs[f*16 + lm][kg*8];
      acc[f] = mfma16x16x32(af, bfr, acc[f]);
    }
    __syncthreads();
  }
  const int row0 = bm0 + wave*16 + kg*4;
  const int col0 = bn0 + lm;
#pragma unroll
  for (int f = 0; f < 4; ++f) {
#pragma unroll
    for (int q = 0; q < 4; ++q) {
      float val = acc[f][q];
      size_t o = (size_t)(row0 + q) * Nn + col0 + f*16;
      out[o] = tobf(tnh ? fast_tanh(val) : val);
    }
  }
}

// ------- GEMM 128-tile, m97 structure (global_load_lds staging) -------------
// EPI: 0 f32 | 2 bf16
template<int EPI>
__global__ __launch_bounds__(256) void gemm128(
    const bf16* __restrict__ A, int lda,
    const bf16* __restrict__ Bt, int ldb,
    void* __restrict__ Cout, int ldc, int K)
{
  __shared__ bf16 As[128][32];     // linear (required by global_load_lds)
  __shared__ bf16 Bs[128][32];
  const int bm0 = blockIdx.x * 128, bn0 = blockIdx.y * 128;
  const int tid = threadIdx.x, wv = tid >> 6, ln = tid & 63;
  const int wr = wv >> 1, wc = wv & 1;
  const int lm = ln & 15, kg = ln >> 4;
  const int srow = ln >> 2, scol = (ln & 3) * 8;
  f32x4 acc[4][4] = {};
  for (int k0 = 0; k0 < K; k0 += 32) {
#pragma unroll
    for (int i = 0; i < 2; ++i) {
      const int r0 = wv*32 + i*16;
      gload16(A  + (size_t)(bm0 + r0 + srow) * lda + k0 + scol, &As[r0][0]);
      gload16(Bt + (size_t)(bn0 + r0 + srow) * ldb + k0 + scol, &Bs[r0][0]);
    }
    asm volatile("s_waitcnt vmcnt(0)" ::: "memory");
    __syncthreads();
    bf16x8 af[4], bfr[4];
#pragma unroll
    for (int m = 0; m < 4; ++m) af[m] = *(const bf16x8*)&As[wr*64 + m*16 + lm][kg*8];
#pragma unroll
    for (int n = 0; n < 4; ++n) bfr[n] = *(const bf16x8*)&Bs[wc*64 + n*16 + lm][kg*8];
#pragma unroll
    for (int m = 0; m < 4; ++m)
#pragma unroll
      for (int n = 0; n < 4; ++n)
        acc[m][n] = mfma16x16x32(af[m], bfr[n], acc[m][n]);
    __syncthreads();
  }
#pragma unroll
  for (int m = 0; m < 4; ++m) {
    const int row0 = bm0 + wr*64 + m*16 + kg*4;
#pragma unroll
    for (int n = 0; n < 4; ++n) {
      const int col = bn0 + wc*64 + n*16 + lm;
#pragma unroll
      for (int q = 0; q < 4; ++q) {
        float val = acc[m][n][q];
        size_t o = (size_t)(row0 + q) * ldc + col;
        if (EPI == 0) ((float*)Cout)[o] = val;
        else          ((bf16*)Cout)[o] = tobf(val);
      }
    }
  }
}

// batched r/k/v: same shape (M=4096, N=1024, K=1024), bf16 outputs
struct RkvArgs { const bf16* A[3]; const bf16* Bt[3]; bf16* Cq[3]; };
__global__ __launch_bounds__(256) void gemm128_rkv(RkvArgs ra) {
  __shared__ bf16 As[128][32];
  __shared__ bf16 Bs[128][32];
  const bf16* __restrict__ A  = ra.A[blockIdx.z];
  const bf16* __restrict__ Bt = ra.Bt[blockIdx.z];
  bf16* __restrict__ Cout = ra.Cq[blockIdx.z];
  const int bm0 = blockIdx.x * 128, bn0 = blockIdx.y * 128;
  const int tid = threadIdx.x, wv = tid >> 6, ln = tid & 63;
  const int wr = wv >> 1, wc = wv & 1;
  const int lm = ln & 15, kg = ln >> 4;
  const int srow = ln >> 2, scol = (ln & 3) * 8;
  f32x4 acc[4][4] = {};
  for (int k0 = 0; k0 < C_; k0 += 32) {
#pragma unroll
    for (int i = 0; i < 2; ++i) {
      const int r0 = wv*32 + i*16;
      gload16(A  + (size_t)(bm0 + r0 + srow) * C_ + k0 + scol, &As[r0][0]);
      gload16(Bt + (size_t)(bn0 + r0 + srow) * C_ + k0 + scol, &Bs[r0][0]);
    }
    asm volatile("s_waitcnt vmcnt(0)" ::: "memory");
    __syncthreads();
    bf16x8 af[4], bfr[4];
#pragma unroll
    for (int m = 0; m < 4; ++m) af[m] = *(const bf16x8*)&As[wr*64 + m*16 + lm][kg*8];
#pragma unroll
    for (int n = 0; n < 4; ++n) bfr[n] = *(const bf16x8*)&Bs[wc*64 + n*16 + lm][kg*8];
#pragma unroll
    for (int m = 0; m < 4; ++m)
#pragma unroll
      for (int n = 0; n < 4; ++n)
        acc[m][n] = mfma16x16x32(af[m], bfr[n], acc[m][n]);
    __syncthreads();
  }
#pragma unroll
  for (int m = 0; m < 4; ++m) {
    const int row0 = bm0 + wr*64 + m*16 + kg*4;
#pragma unroll
    for (int n = 0; n < 4; ++n) {
      const int col = bn0 + wc*64 + n*16 + lm;
#pragma unroll
      for (int q = 0; q < 4; ++q)
        Cout[(size_t)(row0 + q) * C_ + col] = tobf(acc[m][n][q]);
    }
  }
}

// ------- batched epilogue GEMMs: kk-sum / w-finalize / a-sigmoid / g --------
// all M=4096, N=1024; K per z; epi: 2=bf16 raw, 4=sigmoid, 5=w-finalize,
// 6=kk-sum (adds kin elementwise -> k+kkadd)
struct Ep4Args {
  const bf16* A[4]; const bf16* Bt[4]; bf16* Cout[4];
  int K[4]; int epi[4];
  const float* aux[4];          // z1: tdec, z2: aaaaa
  const bf16* kin; bf16* ksout; // kb unscaled in; z1 writes scaled k
};
__global__ __launch_bounds__(256) void gemm128_ep4(Ep4Args ea) {
  __shared__ bf16 As[128][32];
  __shared__ bf16 Bs[128][32];
  const int z = blockIdx.z;
  const bf16* __restrict__ A  = ea.A[z];
  const bf16* __restrict__ Bt = ea.Bt[z];
  bf16* __restrict__ Cout = ea.Cout[z];
  const int K = ea.K[z], epi = ea.epi[z];
  const float* __restrict__ aux = ea.aux[z];
  const int bm0 = blockIdx.x * 128, bn0 = blockIdx.y * 128;
  const int tid = threadIdx.x, wv = tid >> 6, ln = tid & 63;
  const int wr = wv >> 1, wc = wv & 1;
  const int lm = ln & 15, kg = ln >> 4;
  const int srow = ln >> 2, scol = (ln & 3) * 8;
  f32x4 acc[4][4] = {};
  for (int k0 = 0; k0 < K; k0 += 32) {
#pragma unroll
    for (int i = 0; i < 2; ++i) {
      const int r0 = wv*32 + i*16;
      gload16(A  + (size_t)(bm0 + r0 + srow) * K + k0 + scol, &As[r0][0]);
      gload16(Bt + (size_t)(bn0 + r0 + srow) * K + k0 + scol, &Bs[r0][0]);
    }
    asm volatile("s_waitcnt vmcnt(0)" ::: "memory");
    __syncthreads();
    bf16x8 af[4], bfr[4];
#pragma unroll
    for (int m = 0; m < 4; ++m) af[m] = *(const bf16x8*)&As[wr*64 + m*16 + lm][kg*8];
#pragma unroll
    for (int n = 0; n < 4; ++n) bfr[n] = *(const bf16x8*)&Bs[wc*64 + n*16 + lm][kg*8];
#pragma unroll
    for (int m = 0; m < 4; ++m)
#pragma unroll
      for (int n = 0; n < 4; ++n)
        acc[m][n] = mfma16x16x32(af[m], bfr[n], acc[m][n]);
    __syncthreads();
  }
#pragma unroll
  for (int m = 0; m < 4; ++m) {
    const int row0 = bm0 + wr*64 + m*16 + kg*4;
#pragma unroll
    for (int n = 0; n < 4; ++n) {
      const int col = bn0 + wc*64 + n*16 + lm;
#pragma unroll
      for (int q = 0; q < 4; ++q) {
        float val = acc[m][n][q];
        size_t o = (size_t)(row0 + q) * C_ + col;
        if (epi == 2) {
          Cout[o] = tobf(val);
        } else if (epi == 6) {          // kk-sum: k + kkadd
          Cout[o] = tobf(val + frombf(ea.kin[o]));
        } else if (epi == 4) {
          float zz = aux[col] + val;
          Cout[o] = tobf(2.f / (1.f + __expf(-zz)));
        } else {  // epi == 5: w-finalize (fast transcendentals)
          float wr2 = val + aux[col];
          float sp = fmaxf(-wr2, 0.f) + __logf(1.f + __expf(-fabsf(wr2)));
          float w = -sp - 0.5f;
          Cout[o] = tobf(-__expf(w));                                  // lw
          ea.ksout[o] = tobf(frombf(ea.kin[o]) * __expf(fminf(0.5f*w, 0.f)));
        }
      }
    }
  }
}

// --------- fused 6-branch low-rank projection + combine (x staged ONCE) -----
struct Mix6Args { const float* maa[6]; bf16* out[6]; };

__global__ __launch_bounds__(256) void mix_combine(
    const bf16* __restrict__ mixb, const bf16* __restrict__ w2t,
    const bf16* __restrict__ xb, Mix6Args ma)
{
  __shared__ short As[64][40];
  __shared__ short Bs[64][40];
  __shared__ bf16 Xt[65][72];   // rows bm0-1 .. bm0+63, cols bn0..+63
  const int bm0 = blockIdx.x * 64, bn0 = blockIdx.y * 64;
  const int tid = threadIdx.x, wave = tid >> 6, lane = tid & 63;
  const int lm = lane & 15, kg = lane >> 4;
  const int srow = tid >> 2, scol = (tid & 3) * 8;
  // stage x tile once (65 rows x 64 cols, 4 bf16 per load)
  for (int i = tid; i < 65*16; i += 256) {
    const int row = i >> 4, c4 = (i & 15) * 4;
    int gr = bm0 - 1 + row; if (gr < 0) gr = 0;   // row -1 only when bm0==0 (unused)
    *(uint2*)&Xt[row][c4] = *(const uint2*)(xb + (size_t)gr * C_ + bn0 + c4);
  }
  const int row0 = bm0 + wave*16 + kg*4;
  const int col0 = bn0 + lm;
  for (int s6 = 0; s6 < 6; ++s6) {
    __syncthreads();   // Xt ready (iter 0); prior MFMA reads of As/Bs done
    *(uint4*)&As[srow][scol] =
        *(const uint4*)(mixb + s6*32 + (size_t)(bm0 + srow)*192 + scol);
    *(uint4*)&Bs[srow][scol] =
        *(const uint4*)(w2t + (size_t)s6*C_*32 + (size_t)(bn0 + srow)*32 + scol);
    __syncthreads();
    bf16x8 af = *(const bf16x8*)&As[wave*16 + lm][kg*8];
    f32x4 acc[4] = {};
#pragma unroll
    for (int f = 0; f < 4; ++f) {
      bf16x8 bfr = *(const bf16x8*)&Bs[f*16 + lm][kg*8];
      acc[f] = mfma16x16x32(af, bfr, acc[f]);
    }
    const float* __restrict__ maa = ma.maa[s6];
    bf16* __restrict__ out = ma.out[s6];
#pragma unroll
    for (int f = 0; f < 4; ++f) {
#pragma unroll
      for (int q = 0; q < 4; ++q) {
        const int row = row0 + q, col = col0 + f*16;
        const int lr = row - bm0, lc = col - bn0;
        float xv = frombf(Xt[lr + 1][lc]);
        float xp = ((row & (T_ - 1)) == 0) ? 0.f : frombf(Xt[lr][lc]);
        out[(size_t)row * C_ + col] = tobf(xv + (xp - xv) * (maa[col] + acc[f][q]));
      }
    }
  }
}

// ---------------- elementwise ----------------------------------------------
__global__ __launch_bounds__(256) void xin_k(
    const float* __restrict__ x, const float* __restrict__ maa_x,
    bf16* __restrict__ xinb, bf16* __restrict__ xb)
{
  size_t idx = (size_t)blockIdx.x * 256 + threadIdx.x;
  int c = idx & (C_ - 1);
  int t = (int)((idx >> 10) & (T_ - 1));
  float xv = x[idx];
  float xp = t ? x[idx - C_] : 0.f;
  xinb[idx] = tobf(xv + (xp - xv) * maa_x[c]);
  xb[idx] = tobf(xv);
}

// kk = sum / max(||sum||_2 over C, 1e-12), sum precomputed (epi 6)
__global__ __launch_bounds__(256) void kk_normalize(
    const bf16* __restrict__ ksum, bf16* __restrict__ kkout)
{
  const int bt = blockIdx.x;
  const int tid = threadIdx.x;
  const size_t o = (size_t)bt * C_;
  float vals[4]; float ss = 0.f;
#pragma unroll
  for (int q = 0; q < 4; ++q) {
    float u = frombf(ksum[o + tid + q*256]);
    vals[q] = u; ss += u * u;
  }
  ss = allred64(ss);
  __shared__ float red[4];
  const int wave = tid >> 6, lane = tid & 63;
  if (lane == 0) red[wave] = ss;
  __syncthreads();
  float tot = red[0] + red[1] + red[2] + red[3];
  float inv = 1.f / fmaxf(sqrtf(tot), 1e-12f);
#pragma unroll
  for (int q = 0; q < 4; ++q) kkout[o + tid + q*256] = tobf(vals[q] * inv);
}

// ============ Chunked RWKV-7 scan (fp32 recurrence, bf16 MFMA phases) =======
//   SA = (I-trilA)^{-1}(Achk S0^T + trilC V) = W S0^T + SA_loc
//   y[s] = rt_s S0^T + tril<=(ABy) SA + tril<=(CKy) V
//   S_L = S0 * M + U  with M = diag(dL) + (W^T Bt).*dL_j
// LDS 40.7 KB -> 4 blocks/CU: {aCb,rCb}|{WT,SAT} alias; vLT doubles as solve
// input; Am/Cm stored bf16.

__global__ __launch_bounds__(256, 4) void rwkv_chunk_pre(
    const bf16* __restrict__ rr, const bf16* __restrict__ lw,
    const bf16* __restrict__ kk_s, const bf16* __restrict__ kkv,
    const bf16* __restrict__ aam, const bf16* __restrict__ vv,
    bf16* __restrict__ wbufb, bf16* __restrict__ sabufb,
    bf16* __restrict__ abybufb, bf16* __restrict__ ckybufb,
    bf16* __restrict__ ubufP, bf16* __restrict__ mbufT)
{
  __shared__ bf16 Amb[LCH][34], Cmb[LCH][34];
  __shared__ float wtot[4][64];
  __shared__ float lcl[64];
  __shared__ float dll[64];
  __shared__ bf16 bTb[LCH][72], kTb[LCH][72];
  __shared__ bf16 bTT[64][40], kTT[64][40], vLT[64][40];
  __shared__ bf16 uni[5120];   // {aCb,rCb}[32][72] | {WT,SAT}[64][40]
  bf16 (*aCb)[72] = (bf16(*)[72])uni;
  bf16 (*rCb)[72] = (bf16(*)[72])(uni + 2304);
  bf16 (*WT)[40]  = (bf16(*)[40])uni;
  bf16 (*SAT)[40] = (bf16(*)[40])(uni + 2560);

  const int ch = blockIdx.x;
  const int c  = ch & (NCH - 1);
  const int bh = ch >> 6;
  const int b  = bh >> 4, h = bh & 15;
  const int tid = threadIdx.x, wv = tid >> 6, ln = tid & 63;
  const int lm = ln & 15, kg = ln >> 4;
  const size_t base = ((size_t)(b*T_ + c*LCH) * C_) + h*N_ + ln;

  // --- phase 1: cumulative log-decay + load/scale into LDS (both layouts) ---
  float lwr[8], lcE[8];
  {
    float run = 0.f;
#pragma unroll
    for (int q = 0; q < 8; ++q) {
      lwr[q] = frombf(lw[base + (size_t)(wv*8 + q) * C_]);
      lcE[q] = run; run += lwr[q];
    }
    wtot[wv][ln] = run;
  }
  __syncthreads();
  {
    float pre = 0.f;
    for (int w2 = 0; w2 < wv; ++w2) pre += wtot[w2][ln];
    if (wv == 0) lcl[ln] = wtot[0][ln] + wtot[1][ln] + wtot[2][ln] + wtot[3][ln];
#pragma unroll
    for (int q = 0; q < 8; ++q) lcE[q] += pre;
  }
#pragma unroll
  for (int q = 0; q < 8; ++q) {
    const int s = wv*8 + q;
    const size_t off = base + (size_t)s * C_;
    float kkx = frombf(kkv[off]), aax = frombf(aam[off]);
    float kx = frombf(kk_s[off]), rx = frombf(rr[off]);
    float lcI = lcE[q] + lwr[q];
    float eIm = __expf(-lcI);
    float eI  = __builtin_amdgcn_rcpf(eIm);   // exp(lcI) = 1/exp(-lcI)
    float av = -kkx * __expf(lcE[q]);
    float bv = kkx * aax * eIm;
    float kv2 = kx * eIm;
    float rv = rx * eI;
    bf16 vxb = vv[off];
    aCb[s][ln] = tobf(av);  rCb[s][ln] = tobf(rv);
    bTb[s][ln] = tobf(bv);  kTb[s][ln] = tobf(kv2);
    bTT[ln][s] = tobf(bv);  kTT[ln][s] = tobf(kv2);  vLT[ln][s] = vxb;
  }
  __syncthreads();
  if (tid < 64) dll[tid] = __expf(lcl[tid]);  // barriers below make it visible

  // --- phase 2: MFMA, one 32x32 (K=64) product per wave ---
  {
    const bf16 (*Ab)[72] = (wv < 2) ? aCb : rCb;
    const bf16 (*Bb)[72] = (wv & 1) ? kTb : bTb;
#pragma unroll
    for (int mt = 0; mt < 2; ++mt)
#pragma unroll
      for (int nt = 0; nt < 2; ++nt) {
        f32x4 acc = {};
#pragma unroll
        for (int ks = 0; ks < 2; ++ks) {
          bf16x8 af = *(const bf16x8*)&Ab[mt*16 + lm][ks*32 + kg*8];
          bf16x8 bq = *(const bf16x8*)&Bb[nt*16 + lm][ks*32 + kg*8];
          acc = mfma16x16x32(af, bq, acc);
        }
        const int row0 = mt*16 + kg*4, col = nt*16 + lm;
#pragma unroll
        for (int q = 0; q < 4; ++q) {
          float v = acc[q];
          if (wv == 0)      Amb[row0+q][col] = tobf(v);
          else if (wv == 1) Cmb[row0+q][col] = tobf(v);
          else {
            bf16 bv2 = tobf(col <= row0+q ? v : 0.f);  // tril<= mask
            if (wv == 2) abybufb[(size_t)ch*1024 + (row0+q)*32 + col] = bv2;
            else         ckybufb[(size_t)ch*1024 + (row0+q)*32 + col] = bv2;
          }
        }
      }
  }
  __syncthreads();

  // --- phase 3a: preload solve inputs to registers (aCb/Cmb/vLT reads) -----
  float Xr[32], amr[32];
  if (wv == 0) {
#pragma unroll
    for (int s = 0; s < 32; ++s) amr[s] = frombf(Amb[s][ln & 31]);
#pragma unroll
    for (int s = 0; s < 32; ++s) Xr[s] = frombf(aCb[s][ln]);
  } else if (wv == 1) {
    float cmr[32];
#pragma unroll
    for (int s = 0; s < 32; ++s) {
      amr[s] = frombf(Amb[s][ln & 31]);
      cmr[s] = frombf(Cmb[s][ln & 31]);
    }
#pragma unroll
    for (int s = 0; s < 32; ++s) Xr[s] = 0.f;
#pragma unroll
    for (int u = 0; u < 31; ++u) {
      float v = frombf(vLT[ln][u]);   // == V[u][ln]
#pragma unroll
      for (int s = u + 1; s < 32; ++s) Xr[s] += rdlane(cmr[s], u) * v;
    }
  }
  __syncthreads();   // aCb reads complete before WT/SAT writes into alias

  // --- phase 3b: register forward-substitution; write WT/SAT --------------
  if (wv < 2) {
#pragma unroll
    for (int s = 1; s < 32; ++s) {
      float acc = Xr[s];
#pragma unroll
      for (int u = 0; u < s; ++u) acc += rdlane(amr[s], u) * Xr[u];
      Xr[s] = acc;
    }
    if (wv == 0) {
#pragma unroll
      for (int s = 0; s < 32; ++s) {
        bf16 bv = tobf(Xr[s]);
        WT[ln][s] = bv;
        wbufb[(size_t)ch*2048 + s*64 + ln] = bv;
      }
    } else {
#pragma unroll
      for (int s = 0; s < 32; ++s) {
        bf16 bv = tobf(Xr[s]);
        SAT[ln][s] = bv;
        sabufb[(size_t)ch*2048 + s*64 + ln] = bv;
      }
    }
  }
  __syncthreads();

  // --- phase 5: U, M (64x64, K=32) via MFMA; packed-layout b64 stores ------
  {
    const int mt = wv;
    bf16x8 aS = *(const bf16x8*)&SAT[mt*16 + lm][kg*8];
    bf16x8 aV = *(const bf16x8*)&vLT[mt*16 + lm][kg*8];
    bf16x8 aW = *(const bf16x8*)&WT[mt*16 + lm][kg*8];
#pragma unroll
    for (int nt = 0; nt < 4; ++nt) {
      bf16x8 bB = *(const bf16x8*)&bTT[nt*16 + lm][kg*8];
      bf16x8 bK = *(const bf16x8*)&kTT[nt*16 + lm][kg*8];
      f32x4 aU = {}, aG = {};
      aU = mfma16x16x32(aS, bB, aU);
      aU = mfma16x16x32(aV, bK, aU);
      aG = mfma16x16x32(aW, bB, aG);
      const int i0r = mt*16 + kg*4, col = nt*16 + lm;
      float dl = dll[col];
      uint2 up;
      up.x = (unsigned int)bfbits(aU[0]*dl) | ((unsigned int)bfbits(aU[1]*dl) << 16);
      up.y = (unsigned int)bfbits(aU[2]*dl) | ((unsigned int)bfbits(aU[3]*dl) << 16);
      *(uint2*)(ubufP + (size_t)ch*4096 + (mt*4 + nt)*256 + ln*4) = up;
      float m0 = (aG[0] + (i0r+0 == col ? 1.f : 0.f)) * dl;
      float m1 = (aG[1] + (i0r+1 == col ? 1.f : 0.f)) * dl;
      float m2 = (aG[2] + (i0r+2 == col ? 1.f : 0.f)) * dl;
      float m3 = (aG[3] + (i0r+3 == col ? 1.f : 0.f)) * dl;
      uint2 mp;
      mp.x = (unsigned int)bfbits(m0) | ((unsigned int)bfbits(m1) << 16);
      mp.y = (unsigned int)bfbits(m2) | ((unsigned int)bfbits(m3) << 16);
      const int laned = (((mt*2) + (kg >> 1)) & 3) * 16 + lm;
      *(uint2*)(mbufT + (size_t)ch*4096 + (nt*2 + (mt >> 1))*512
                + laned*8 + (kg & 1)*4) = mp;
    }
  }
}

// Phase B: serial over chunks; 32 blocks (one per bh) x 4 waves, no barriers.
__global__ __launch_bounds__(256) void rwkv_chunk_state(
    const bf16* __restrict__ mbufT, const bf16* __restrict__ ubufP,
    bf16* __restrict__ s0bufb)
{
  __shared__ bf16 Sst[4][16][72];
  const int bh = blockIdx.x;
  const int tid = threadIdx.x, wv = tid >> 6, ln = tid & 63;
  const int lm = ln & 15, kg = ln >> 4;

#pragma unroll
  for (int r = 0; r < 16; ++r) {
    Sst[wv][r][ln] = tobf(0.f);
    if (ln < 8) Sst[wv][r][64 + ln] = tobf(0.f);
  }

  bf16x8 BfA[4][2], BfB[4][2];
  uint2 UpA[4], UpB[4];
  auto prefetch = [&](bf16x8 (&Bf)[4][2], uint2 (&Up)[4], int c) {
    const size_t chp = (size_t)(bh*NCH + c) * 4096;
#pragma unroll
    for (int nt = 0; nt < 4; ++nt) {
      Bf[nt][0] = *(const bf16x8*)(mbufT + chp + (nt*2 + 0)*512 + ln*8);
      Bf[nt][1] = *(const bf16x8*)(mbufT + chp + (nt*2 + 1)*512 + ln*8);
      Up[nt]    = *(const uint2*) (ubufP + chp + (wv*4 + nt)*256 + ln*4);
    }
  };
  prefetch(BfA, UpA, 0);
  prefetch(BfB, UpB, 1);

  auto body = [&](bf16x8 (&Bf)[4][2], uint2 (&Up)[4], int c) {
    const size_t ch4 = (size_t)(bh*NCH + c) * 4096;
    const int sr = ln >> 2, sc = (ln & 3) * 16;
    uint4 v0 = *(const uint4*)&Sst[wv][sr][sc];
    uint4 v1 = *(const uint4*)&Sst[wv][sr][sc + 8];
    *(uint4*)(s0bufb + ch4 + (size_t)(wv*16 + sr)*64 + sc) = v0;
    *(uint4*)(s0bufb + ch4 + (size_t)(wv*16 + sr)*64 + sc + 8) = v1;
    bf16x8 A0 = *(const bf16x8*)&Sst[wv][lm][kg*8];
    bf16x8 A1 = *(const bf16x8*)&Sst[wv][lm][32 + kg*8];
    f32x4 acc[4];
#pragma unroll
    for (int nt = 0; nt < 4; ++nt) {
      acc[nt][0] = bf2f((unsigned short)(Up[nt].x & 0xffff));
      acc[nt][1] = bf2f((unsigned short)(Up[nt].x >> 16));
      acc[nt][2] = bf2f((unsigned short)(Up[nt].y & 0xffff));
      acc[nt][3] = bf2f((unsigned short)(Up[nt].y >> 16));
      acc[nt] = mfma16x16x32(A0, Bf[nt][0], acc[nt]);
      acc[nt] = mfma16x16x32(A1, Bf[nt][1], acc[nt]);
    }
    int cp = c + 2; if (cp > NCH - 1) cp = NCH - 1;
    prefetch(Bf, Up, cp);
#pragma unroll
    for (int nt = 0; nt < 4; ++nt)
#pragma unroll
      for (int q = 0; q < 4; ++q)
        Sst[wv][kg*4 + q][nt*16 + lm] = tobf(acc[nt][q]);
  };

  for (int cc = 0; cc < NCH; cc += 2) {
    body(BfA, UpA, cc);
    body(BfB, UpB, cc + 1);
  }
}

// Phase C: per chunk-head: SA = W*S0^T + SAll; y = Rt*S0^T + ABl*SAo + CKl*V;
// then FUSED groupnorm (group == head, size 64) + bonus + gate -> zb (bf16).
__global__ __launch_bounds__(256, 4) void rwkv_chunk_out(
    const bf16* __restrict__ rr, const bf16* __restrict__ lw,
    const bf16* __restrict__ vv, const bf16* __restrict__ kks,
    const bf16* __restrict__ gg, const bf16* __restrict__ s0bufb,
    const bf16* __restrict__ wbufb, const bf16* __restrict__ sabufb,
    const bf16* __restrict__ abybufb, const bf16* __restrict__ ckybufb,
    const float* __restrict__ faaaa, const float* __restrict__ lnw,
    const float* __restrict__ lnb, bf16* __restrict__ zb)
{
  __shared__ bf16 S0b[64][72];                    // B^T layout: [i][j]
  __shared__ bf16 ABl[LCH][40], CKl[LCH][40];     // A layouts: [s][u]
  __shared__ bf16 SAot[64][40], VlT[64][40];      // B^T layouts: [i][u]
  __shared__ float wtot[4][64];
  __shared__ float bonus[LCH];
  __shared__ float uni2f[2304];  // {Wb,Rlb}[32][72] bf16 | Yl[32][68] f32
  bf16 (*Wb)[72]  = (bf16(*)[72])uni2f;
  bf16 (*Rlb)[72] = (bf16(*)[72])((bf16*)uni2f + 2304);
  float (*Yl)[68] = (float(*)[68])uni2f;

  const int ch = blockIdx.x;
  const int c = ch & (NCH - 1), bh = ch >> 6, b = bh >> 4, h = bh & 15;
  const int tid = threadIdx.x, wv = tid >> 6, ln = tid & 63;
  const int lm = ln & 15, kg = ln >> 4;
  const size_t base = ((size_t)(b*T_ + c*LCH) * C_) + h*N_ + ln;

  float lwr[8], lcE[8];
  {
    float run = 0.f;
#pragma unroll
    for (int q = 0; q < 8; ++q) {
      lwr[q] = frombf(lw[base + (size_t)(wv*8 + q) * C_]);
      lcE[q] = run; run += lwr[q];
    }
    wtot[wv][ln] = run;
  }
  __syncthreads();
  {
    float pre = 0.f;
    for (int w2 = 0; w2 < wv; ++w2) pre += wtot[w2][ln];
#pragma unroll
    for (int q = 0; q < 8; ++q) lcE[q] += pre;
  }
  const float fa = faaaa[h*N_ + ln];
#pragma unroll
  for (int q = 0; q < 8; ++q) {
    const int s = wv*8 + q;
    const size_t off = base + (size_t)s * C_;
    float rf = frombf(rr[off]);
    Rlb[s][ln] = tobf(rf * __expf(lcE[q] + lwr[q]));
    VlT[ln][s] = vv[off];
    float rk = allred64(rf * frombf(kks[off]) * fa);   // bonus dot
    if (ln == 0) bonus[s] = rk;
  }
#pragma unroll
  for (int t = 0; t < 2; ++t) {
    int cc2 = tid*2 + t; int ri = cc2 >> 3, co = (cc2 & 7) * 8;
    *(uint4*)&S0b[ri][co] = *(const uint4*)(s0bufb + (size_t)ch*4096 + ri*64 + co);
  }
  { int ri = tid >> 3, co = (tid & 7) * 8;
    *(uint4*)&Wb[ri][co] = *(const uint4*)(wbufb + (size_t)ch*2048 + ri*64 + co); }
  if (tid < 128) {
    int ri = tid >> 2, co = (tid & 3) * 8;
    *(uint4*)&ABl[ri][co] = *(const uint4*)(abybufb + (size_t)ch*1024 + ri*32 + co);
  } else {
    int t2 = tid - 128; int ri = t2 >> 2, co = (t2 & 3) * 8;
    *(uint4*)&CKl[ri][co] = *(const uint4*)(ckybufb + (size_t)ch*1024 + ri*32 + co);
  }
  __syncthreads();

  const int mt = wv >> 1, ntb = (wv & 1) * 2;
#pragma unroll
  for (int t = 0; t < 2; ++t) {
    const int nt = ntb + t;
    const int row0 = mt*16 + kg*4, col = nt*16 + lm;
    f32x4 acc;
#pragma unroll
    for (int q = 0; q < 4; ++q)
      acc[q] = frombf(sabufb[(size_t)ch*2048 + (row0+q)*64 + col]);
#pragma unroll
    for (int ks = 0; ks < 2; ++ks) {
      bf16x8 af = *(const bf16x8*)&Wb[mt*16 + lm][ks*32 + kg*8];
      bf16x8 bq = *(const bf16x8*)&S0b[nt*16 + lm][ks*32 + kg*8];
      acc = mfma16x16x32(af, bq, acc);
    }
#pragma unroll
    for (int q = 0; q < 4; ++q) SAot[col][row0+q] = tobf(acc[q]);
  }
  __syncthreads();

  f32x4 yacc[2];
#pragma unroll
  for (int t = 0; t < 2; ++t) {
    const int nt = ntb + t;
    f32x4 acc = {};
#pragma unroll
    for (int ks = 0; ks < 2; ++ks) {
      bf16x8 af = *(const bf16x8*)&Rlb[mt*16 + lm][ks*32 + kg*8];
      bf16x8 bq = *(const bf16x8*)&S0b[nt*16 + lm][ks*32 + kg*8];
      acc = mfma16x16x32(af, bq, acc);
    }
    {
      bf16x8 af = *(const bf16x8*)&ABl[mt*16 + lm][kg*8];
      bf16x8 bq = *(const bf16x8*)&SAot[nt*16 + lm][kg*8];
      acc = mfma16x16x32(af, bq, acc);
    }
    {
      bf16x8 af = *(const bf16x8*)&CKl[mt*16 + lm][kg*8];
      bf16x8 bq = *(const bf16x8*)&VlT[nt*16 + lm][kg*8];
      acc = mfma16x16x32(af, bq, acc);
    }
    yacc[t] = acc;
  }
  __syncthreads();   // all Rlb reads done before Yl overwrites the alias

#pragma unroll
  for (int t = 0; t < 2; ++t) {
    const int nt = ntb + t;
    const int row0 = mt*16 + kg*4, col = nt*16 + lm;
#pragma unroll
    for (int q = 0; q < 4; ++q) Yl[row0 + q][col] = yacc[t][q];
  }
  __syncthreads();

  // fused groupnorm + bonus + gate: thread = (row s2, 8 cols)
  {
    const int s2 = tid >> 3, c0 = (tid & 7) * 8;
    float yv[8]; float sum = 0.f;
#pragma unroll
    for (int i = 0; i < 8; ++i) { yv[i] = Yl[s2][c0 + i]; sum += yv[i]; }
#pragma unroll
    for (int m = 1; m < 8; m <<= 1) sum += __shfl_xor(sum, m, 64);
    const float mean = sum * (1.f/64.f);
    float ss = 0.f;
#pragma unroll
    for (int i = 0; i < 8; ++i) { float d = yv[i] - mean; ss += d * d; }
#pragma unroll
    for (int m = 1; m < 8; m <<= 1) ss += __shfl_xor(ss, m, 64);
    const float inv = rsqrtf(ss * (1.f/64.f) + 6.4e-4f);
    const float bn = bonus[s2];
    const size_t trow = (size_t)(b*T_ + c*LCH + s2) * C_ + h*N_ + c0;
    bf16 zout[8];
#pragma unroll
    for (int i = 0; i < 8; ++i) {
      float gn = (yv[i] - mean) * inv * lnw[h*N_ + c0 + i] + lnb[h*N_ + c0 + i];
      float z = (gn + bn * frombf(VlT[c0 + i][s2])) * frombf(gg[trow + i]);
      zout[i] = tobf(z);
    }
    *(uint4*)(zb + trow) = *(const uint4*)&zout[0];
  }
}

// ---------------- driver ----------------------------------------------------
extern "C" void kernel_launch(void* const* d_in, const int* in_sizes, int n_in,
                              void* d_out, int out_size, void* d_ws, size_t ws_size,
                              hipStream_t stream)
{
  const float* x     = (const float*)d_in[0];
  const float* maa_x = (const float*)d_in[1];
  const float* maa_r = (const float*)d_in[2];
  const float* maa_w = (const float*)d_in[3];
  const float* maa_k = (const float*)d_in[4];
  const float* maa_v = (const float*)d_in[5];
  const float* maa_a = (const float*)d_in[6];
  const float* maa_g = (const float*)d_in[7];
  const float* tdec  = (const float*)d_in[8];
  const float* faaaa = (const float*)d_in[9];
  const float* aaaaa = (const float*)d_in[10];
  const float* maa_w1= (const float*)d_in[11];
  const float* maa_w2= (const float*)d_in[12];
  const float* dec_w1= (const float*)d_in[13];
  const float* dec_w2= (const float*)d_in[14];
  const float* aaa_w1= (const float*)d_in[15];
  const float* aaa_w2= (const float*)d_in[16];
  const float* kkk_w1= (const float*)d_in[17];
  const float* kkk_w2= (const float*)d_in[18];
  const float* gate_w1=(const float*)d_in[19];
  const float* gate_w2=(const float*)d_in[20];
  const float* W_r   = (const float*)d_in[21];
  const float* W_k   = (const float*)d_in[22];
  const float* W_v   = (const float*)d_in[23];
  const float* W_o   = (const float*)d_in[24];
  const float* lnw   = (const float*)d_in[25];
  const float* lnb   = (const float*)d_in[26];

  char* ws = (char*)d_ws;
  size_t cur = 0;
  auto alloc = [&](size_t bytes) -> void* {
    void* p = ws + cur; cur += (bytes + 255) & ~(size_t)255; return p;
  };
  const size_t HBT = (size_t)BT_ * C_ * 2;  // bf16 activation buffer

  // ---- persistent (activations bf16) ----
  bf16* rb   = (bf16*)alloc(HBT);
  bf16* kb   = (bf16*)alloc(HBT);   // UNscaled k
  bf16* ksb  = (bf16*)alloc(HBT);   // scaled k (for scan + bonus)
  bf16* vb   = (bf16*)alloc(HBT);
  bf16* gbb  = (bf16*)alloc(HBT);
  bf16* WtR  = (bf16*)alloc((size_t)C_*C_*2);
  bf16* WtK  = (bf16*)alloc((size_t)C_*C_*2);
  bf16* WtV  = (bf16*)alloc((size_t)C_*C_*2);
  bf16* WtO  = (bf16*)alloc((size_t)C_*C_*2);
  bf16* w1t  = (bf16*)alloc((size_t)192*C_*2);
  bf16* w2t  = (bf16*)alloc((size_t)6*C_*32*2);
  bf16* d1t  = (bf16*)alloc((size_t)64*C_*2);
  bf16* d2t  = (bf16*)alloc((size_t)C_*64*2);
  bf16* a1t  = (bf16*)alloc((size_t)64*C_*2);
  bf16* a2t  = (bf16*)alloc((size_t)C_*64*2);
  bf16* k1t  = (bf16*)alloc((size_t)64*C_*2);
  bf16* k2t  = (bf16*)alloc((size_t)C_*64*2);
  bf16* g1t  = (bf16*)alloc((size_t)128*C_*2);
  bf16* g2t  = (bf16*)alloc((size_t)C_*128*2);
  bf16* lwb  = (bf16*)alloc(HBT);
  bf16* kkb  = (bf16*)alloc(HBT);
  bf16* aamt = (bf16*)alloc(HBT);
  bf16* s0bufb = kkb;                 // overlay: kkb+aamt dead after chunk_pre

  // ---- union region ----
  const size_t ubase = cur;
  bf16* mtmpb = (bf16*)alloc(HBT);
  bf16* xinb = (bf16*)alloc(HBT);
  bf16* xb   = (bf16*)alloc(HBT);
  bf16* mixb = (bf16*)alloc((size_t)BT_*192*2);
  bf16* xbr[6];
  for (int s = 0; s < 6; ++s) xbr[s] = (bf16*)alloc(HBT);
  bf16* h64k = (bf16*)alloc((size_t)BT_*64*2);
  bf16* h64d = (bf16*)alloc((size_t)BT_*64*2);
  bf16* h64a = (bf16*)alloc((size_t)BT_*64*2);
  bf16* h128b= (bf16*)alloc((size_t)BT_*128*2);
  const size_t tmp_end = cur;
  cur = ubase;  // overlay
  bf16*  wbufb   = (bf16*)alloc((size_t)CHD*2048*2);
  bf16*  sabufb  = (bf16*)alloc((size_t)CHD*2048*2);
  bf16*  abybufb = (bf16*)alloc((size_t)CHD*1024*2);
  bf16*  ckybufb = (bf16*)alloc((size_t)CHD*1024*2);
  bf16*  ubufP   = (bf16*)alloc((size_t)CHD*4096*2);
  bf16*  mbufT   = (bf16*)alloc((size_t)CHD*4096*2);
  bf16*  zb      = (bf16*)ubufP;   // alias: ubufP dead after chunk_state
  if (tmp_end > cur) cur = tmp_end;
  const size_t need = cur;
  (void)in_sizes; (void)n_in; (void)out_size;

  if (ws_size < need) {
    ws_diag<<<1, 1, 0, stream>>>((float)ws_size, (float)need, (float*)d_out);
    return;
  }

  PrepArgs pa;
  pa.src[0] = W_r;  pa.dst[0] = WtR;
  pa.src[1] = W_k;  pa.dst[1] = WtK;
  pa.src[2] = W_v;  pa.dst[2] = WtV;
  pa.src[3] = W_o;  pa.dst[3] = WtO;
  pa.src[4] = maa_w1; pa.dst[4] = w1t;
  for (int s = 0; s < 6; ++s) { pa.src[5+s] = maa_w2 + (size_t)s*32*C_; pa.dst[5+s] = w2t + (size_t)s*C_*32; }
  pa.src[11] = dec_w1; pa.dst[11] = d1t;
  pa.src[12] = dec_w2; pa.dst[12] = d2t;
  pa.src[13] = aaa_w1; pa.dst[13] = a1t;
  pa.src[14] = aaa_w2; pa.dst[14] = a2t;
  pa.src[15] = kkk_w1; pa.dst[15] = k1t;
  pa.src[16] = kkk_w2; pa.dst[16] = k2t;
  pa.src[17] = gate_w1; pa.dst[17] = g1t;
  pa.src[18] = gate_w2; pa.dst[18] = g2t;
  prep_weights<<<dim3(1024, 19), 256, 0, stream>>>(pa);

  const int EW_GRID = (BT_ * C_) / 256;  // 16384
  xin_k<<<EW_GRID, 256, 0, stream>>>(x, maa_x, xinb, xb);

  gemm_bt<1><<<dim3(64, 3), 256, 0, stream>>>(xinb, C_, w1t, C_, mixb, 192, C_);

  Mix6Args ma;
  ma.maa[0] = maa_r; ma.maa[1] = maa_w; ma.maa[2] = maa_k;
  ma.maa[3] = maa_v; ma.maa[4] = maa_a; ma.maa[5] = maa_g;
  for (int s = 0; s < 6; ++s) ma.out[s] = xbr[s];
  mix_combine<<<dim3(64, 16), 256, 0, stream>>>(mixb, w2t, xb, ma);

  // r, k, v batched (one launch, bf16 out)
  RkvArgs ra;
  ra.A[0] = xbr[0]; ra.Bt[0] = WtR; ra.Cq[0] = rb;
  ra.A[1] = xbr[2]; ra.Bt[1] = WtK; ra.Cq[1] = kb;
  ra.A[2] = xbr[3]; ra.Bt[2] = WtV; ra.Cq[2] = vb;
  gemm128_rkv<<<dim3(32, 8, 3), 256, 0, stream>>>(ra);

  // batched small projections: k1 (tanh), d1 (tanh), a1 (raw), g1 (tanh)
  Proj4Args p4;
  p4.A[0] = xbr[2]; p4.Bt[0] = k1t; p4.out[0] = h64k; p4.N[0] = 64;  p4.tnh[0] = 1;
  p4.A[1] = xbr[1]; p4.Bt[1] = d1t; p4.out[1] = h64d; p4.N[1] = 64;  p4.tnh[1] = 1;
  p4.A[2] = xbr[4]; p4.Bt[2] = a1t; p4.out[2] = h64a; p4.N[2] = 64;  p4.tnh[2] = 0;
  p4.A[3] = xbr[5]; p4.Bt[3] = g1t; p4.out[3] = h128b; p4.N[3] = 128; p4.tnh[3] = 1;
  proj4<<<dim3(64, 2, 4), 256, 0, stream>>>(p4);

  // batched epilogue GEMMs: z0 kk-SUM (k+kkadd), z1 w-finalize, z2 a, z3 g
  Ep4Args ea;
  ea.A[0] = h64k;  ea.Bt[0] = k2t; ea.Cout[0] = mtmpb; ea.K[0] = 64;  ea.epi[0] = 6; ea.aux[0] = nullptr;
  ea.A[1] = h64d;  ea.Bt[1] = d2t; ea.Cout[1] = lwb;   ea.K[1] = 64;  ea.epi[1] = 5; ea.aux[1] = tdec;
  ea.A[2] = h64a;  ea.Bt[2] = a2t; ea.Cout[2] = aamt;  ea.K[2] = 64;  ea.epi[2] = 4; ea.aux[2] = aaaaa;
  ea.A[3] = h128b; ea.Bt[3] = g2t; ea.Cout[3] = gbb;   ea.K[3] = 128; ea.epi[3] = 2; ea.aux[3] = nullptr;
  ea.kin = kb; ea.ksout = ksb;
  gemm128_ep4<<<dim3(32, 8, 4), 256, 0, stream>>>(ea);

  kk_normalize<<<BT_, 256, 0, stream>>>(mtmpb, kkb);

  // ---- chunked scan (scaled k = ksb) ----
  rwkv_chunk_pre<<<CHD, 256, 0, stream>>>(rb, lwb, ksb, kkb, aamt, vb,
      wbufb, sabufb, abybufb, ckybufb, ubufP, mbufT);
  rwkv_chunk_state<<<32, 256, 0, stream>>>(mbufT, ubufP, s0bufb);
  rwkv_chunk_out<<<CHD, 256, 0, stream>>>(rb, lwb, vb, ksb, gbb, s0bufb,
      wbufb, sabufb, abybufb, ckybufb, faaaa, lnw, lnb, zb);

  gemm128<0><<<dim3(32, 8), 256, 0, stream>>>(zb, C_, WtO, C_, d_out, C_, C_);
}

// Round 19
// 280.911 us; speedup vs baseline: 5.8165x; 1.0035x over previous
//
#include <hip/hip_runtime.h>
#include <hip/hip_bf16.h>

using bf16 = __hip_bfloat16;
using bf16x8 = __attribute__((ext_vector_type(8))) short;  // 8 bf16 (4 VGPRs)
using f32x4 = __attribute__((ext_vector_type(4))) float;

#define B_ 2
#define T_ 2048
#define C_ 1024
#define BT_ (B_*T_)
#define H_ 16
#define N_ 64
#define LCH 32            // scan chunk length
#define NCH (T_/LCH)      // 64 chunks per head
#define CHD (B_*H_*NCH)   // 2048 chunk-heads

__device__ __forceinline__ float allred64(float v) {
#pragma unroll
  for (int m = 1; m < 64; m <<= 1) v += __shfl_xor(v, m, 64);
  return v;
}

__device__ __forceinline__ bf16 tobf(float f) { return __float2bfloat16(f); }
__device__ __forceinline__ float frombf(bf16 b) { return __bfloat162float(b); }
__device__ __forceinline__ float bf2f(unsigned short u) {
  unsigned int x = ((unsigned int)u) << 16;
  return __builtin_bit_cast(float, x);
}
__device__ __forceinline__ unsigned short bfbits(float f) {
  return __builtin_bit_cast(unsigned short, __float2bfloat16(f));
}
__device__ __forceinline__ float rdlane(float v, int m) {
  return __builtin_bit_cast(float,
      __builtin_amdgcn_readlane(__builtin_bit_cast(int, v), m));
}
// overflow-safe fast tanh via hardware exp (<=4 ulp; outputs bf16-rounded)
__device__ __forceinline__ float fast_tanh(float x) {
  float t = __expf(-2.f * fabsf(x));
  float r = (1.f - t) / (1.f + t);
  return copysignf(r, x);
}

__device__ __forceinline__ f32x4 mfma16x16x32(bf16x8 a, bf16x8 b, f32x4 c) {
  return __builtin_amdgcn_mfma_f32_16x16x32_bf16(a, b, c, 0, 0, 0);
}

// async global->LDS, 16B per lane (dest = wave-uniform base + lane*16)
typedef const __attribute__((address_space(1))) unsigned int* gas_ptr;
typedef __attribute__((address_space(3))) unsigned int* las_ptr;
__device__ __forceinline__ void gload16(const void* g, void* l) {
  __builtin_amdgcn_global_load_lds((gas_ptr)g, (las_ptr)l, 16, 0, 0);
}

// ---------------- ws_size diagnostic ----------------------------------------
__global__ void ws_diag(float a, float b, float* out) { out[0] = a; out[1] = b; }

// ---------------- weight transpose + bf16 cast (19 jobs, one launch) -------
struct PrepArgs {
  const float* src[19];
  bf16* dst[19];
};
__constant__ int kTR[19] = {1024,1024,1024,1024, 1024, 32,32,32,32,32,32,
                            1024,64, 1024,64, 1024,64, 1024,128};
__constant__ int kTC[19] = {1024,1024,1024,1024, 192, 1024,1024,1024,1024,1024,1024,
                            64,1024, 64,1024, 64,1024, 128,1024};

__global__ __launch_bounds__(256) void prep_weights(PrepArgs pa) {
  const int job = blockIdx.y;
  const int R = kTR[job], Cc = kTC[job];
  const int ntx = Cc >> 5, nty = R >> 5;
  const int tile = blockIdx.x;
  if (tile >= ntx * nty) return;
  const int tx = tile % ntx, ty = tile / ntx;
  const float* __restrict__ src = pa.src[job];
  bf16* __restrict__ dst = pa.dst[job];
  __shared__ float tl[32][33];
  const int lx = threadIdx.x & 31, ly = threadIdx.x >> 5;  // 32 x 8
#pragma unroll
  for (int q = 0; q < 4; ++q)
    tl[ly + 8*q][lx] = src[(size_t)(ty*32 + ly + 8*q) * Cc + tx*32 + lx];
  __syncthreads();
#pragma unroll
  for (int q = 0; q < 4; ++q)
    dst[(size_t)(tx*32 + ly + 8*q) * R + ty*32 + lx] = tobf(tl[lx][ly + 8*q]);
}

// ------- GEMM 64-tile -------------------------------------------------------
template<int EPI>
__global__ __launch_bounds__(256) void gemm_bt(
    const bf16* __restrict__ A, int lda,
    const bf16* __restrict__ Bt, int ldb,
    void* __restrict__ Cout, int ldc, int K)
{
  __shared__ short As[64][40];
  __shared__ short Bs[64][40];
  const int bm0 = blockIdx.x * 64;
  const int bn0 = blockIdx.y * 64;
  const int tid = threadIdx.x;
  const int wave = tid >> 6, lane = tid & 63;
  const int lm = lane & 15, kg = lane >> 4;
  const int srow = tid >> 2, scol = (tid & 3) * 8;
  f32x4 acc[4] = {};
  const size_t abase = (size_t)(bm0 + srow) * lda + scol;
  const size_t bbase = (size_t)(bn0 + srow) * ldb + scol;
  for (int k0 = 0; k0 < K; k0 += 32) {
    *(uint4*)&As[srow][scol] = *(const uint4*)(A + abase + k0);
    *(uint4*)&Bs[srow][scol] = *(const uint4*)(Bt + bbase + k0);
    __syncthreads();
    bf16x8 af = *(const bf16x8*)&As[wave*16 + lm][kg*8];
#pragma unroll
    for (int f = 0; f < 4; ++f) {
      bf16x8 bfr = *(const bf16x8*)&Bs[f*16 + lm][kg*8];
      acc[f] = mfma16x16x32(af, bfr, acc[f]);
    }
    __syncthreads();
  }
  const int row0 = bm0 + wave*16 + kg*4;
  const int col0 = bn0 + lm;
#pragma unroll
  for (int f = 0; f < 4; ++f) {
#pragma unroll
    for (int q = 0; q < 4; ++q) {
      float val = acc[f][q];
      size_t o = (size_t)(row0 + q) * ldc + col0 + f*16;
      if (EPI == 0)      ((float*)Cout)[o] = val;
      else if (EPI == 1) ((bf16*)Cout)[o] = tobf(fast_tanh(val));
      else               ((bf16*)Cout)[o] = tobf(val);
    }
  }
}

// ------- batched small projections: k1/d1/a1 (N=64) + g1 (N=128) -----------
struct Proj4Args { const bf16* A[4]; const bf16* Bt[4]; bf16* out[4];
                   int N[4]; int tnh[4]; };
__global__ __launch_bounds__(256) void proj4(Proj4Args p4) {
  const int z = blockIdx.z;
  const int Nn = p4.N[z];
  const int bn0 = blockIdx.y * 64;
  if (bn0 >= Nn) return;
  __shared__ short As[64][40];
  __shared__ short Bs[64][40];
  const bf16* __restrict__ A  = p4.A[z];
  const bf16* __restrict__ Bt = p4.Bt[z];
  bf16* __restrict__ out = p4.out[z];
  const int tnh = p4.tnh[z];
  const int bm0 = blockIdx.x * 64;
  const int tid = threadIdx.x;
  const int wave = tid >> 6, lane = tid & 63;
  const int lm = lane & 15, kg = lane >> 4;
  const int srow = tid >> 2, scol = (tid & 3) * 8;
  f32x4 acc[4] = {};
  const size_t abase = (size_t)(bm0 + srow) * C_ + scol;
  const size_t bbase = (size_t)(bn0 + srow) * C_ + scol;
  for (int k0 = 0; k0 < C_; k0 += 32) {
    *(uint4*)&As[srow][scol] = *(const uint4*)(A + abase + k0);
    *(uint4*)&Bs[srow][scol] = *(const uint4*)(Bt + bbase + k0);
    __syncthreads();
    bf16x8 af = *(const bf16x8*)&As[wave*16 + lm][kg*8];
#pragma unroll
    for (int f = 0; f < 4; ++f) {
      bf16x8 bfr = *(const bf16x8*)&Bs[f*16 + lm][kg*8];
      acc[f] = mfma16x16x32(af, bfr, acc[f]);
    }
    __syncthreads();
  }
  const int row0 = bm0 + wave*16 + kg*4;
  const int col0 = bn0 + lm;
#pragma unroll
  for (int f = 0; f < 4; ++f) {
#pragma unroll
    for (int q = 0; q < 4; ++q) {
      float val = acc[f][q];
      size_t o = (size_t)(row0 + q) * Nn + col0 + f*16;
      out[o] = tobf(tnh ? fast_tanh(val) : val);
    }
  }
}

// ------- GEMM 128-tile, m97 structure (global_load_lds staging) -------------
// EPI: 0 f32 | 2 bf16
template<int EPI>
__global__ __launch_bounds__(256) void gemm128(
    const bf16* __restrict__ A, int lda,
    const bf16* __restrict__ Bt, int ldb,
    void* __restrict__ Cout, int ldc, int K)
{
  __shared__ bf16 As[128][32];     // linear (required by global_load_lds)
  __shared__ bf16 Bs[128][32];
  const int bm0 = blockIdx.x * 128, bn0 = blockIdx.y * 128;
  const int tid = threadIdx.x, wv = tid >> 6, ln = tid & 63;
  const int wr = wv >> 1, wc = wv & 1;
  const int lm = ln & 15, kg = ln >> 4;
  const int srow = ln >> 2, scol = (ln & 3) * 8;
  f32x4 acc[4][4] = {};
  for (int k0 = 0; k0 < K; k0 += 32) {
#pragma unroll
    for (int i = 0; i < 2; ++i) {
      const int r0 = wv*32 + i*16;
      gload16(A  + (size_t)(bm0 + r0 + srow) * lda + k0 + scol, &As[r0][0]);
      gload16(Bt + (size_t)(bn0 + r0 + srow) * ldb + k0 + scol, &Bs[r0][0]);
    }
    asm volatile("s_waitcnt vmcnt(0)" ::: "memory");
    __syncthreads();
    bf16x8 af[4], bfr[4];
#pragma unroll
    for (int m = 0; m < 4; ++m) af[m] = *(const bf16x8*)&As[wr*64 + m*16 + lm][kg*8];
#pragma unroll
    for (int n = 0; n < 4; ++n) bfr[n] = *(const bf16x8*)&Bs[wc*64 + n*16 + lm][kg*8];
#pragma unroll
    for (int m = 0; m < 4; ++m)
#pragma unroll
      for (int n = 0; n < 4; ++n)
        acc[m][n] = mfma16x16x32(af[m], bfr[n], acc[m][n]);
    __syncthreads();
  }
#pragma unroll
  for (int m = 0; m < 4; ++m) {
    const int row0 = bm0 + wr*64 + m*16 + kg*4;
#pragma unroll
    for (int n = 0; n < 4; ++n) {
      const int col = bn0 + wc*64 + n*16 + lm;
#pragma unroll
      for (int q = 0; q < 4; ++q) {
        float val = acc[m][n][q];
        size_t o = (size_t)(row0 + q) * ldc + col;
        if (EPI == 0) ((float*)Cout)[o] = val;
        else          ((bf16*)Cout)[o] = tobf(val);
      }
    }
  }
}

// batched r/k/v: same shape (M=4096, N=1024, K=1024), bf16 outputs
struct RkvArgs { const bf16* A[3]; const bf16* Bt[3]; bf16* Cq[3]; };
__global__ __launch_bounds__(256) void gemm128_rkv(RkvArgs ra) {
  __shared__ bf16 As[128][32];
  __shared__ bf16 Bs[128][32];
  const bf16* __restrict__ A  = ra.A[blockIdx.z];
  const bf16* __restrict__ Bt = ra.Bt[blockIdx.z];
  bf16* __restrict__ Cout = ra.Cq[blockIdx.z];
  const int bm0 = blockIdx.x * 128, bn0 = blockIdx.y * 128;
  const int tid = threadIdx.x, wv = tid >> 6, ln = tid & 63;
  const int wr = wv >> 1, wc = wv & 1;
  const int lm = ln & 15, kg = ln >> 4;
  const int srow = ln >> 2, scol = (ln & 3) * 8;
  f32x4 acc[4][4] = {};
  for (int k0 = 0; k0 < C_; k0 += 32) {
#pragma unroll
    for (int i = 0; i < 2; ++i) {
      const int r0 = wv*32 + i*16;
      gload16(A  + (size_t)(bm0 + r0 + srow) * C_ + k0 + scol, &As[r0][0]);
      gload16(Bt + (size_t)(bn0 + r0 + srow) * C_ + k0 + scol, &Bs[r0][0]);
    }
    asm volatile("s_waitcnt vmcnt(0)" ::: "memory");
    __syncthreads();
    bf16x8 af[4], bfr[4];
#pragma unroll
    for (int m = 0; m < 4; ++m) af[m] = *(const bf16x8*)&As[wr*64 + m*16 + lm][kg*8];
#pragma unroll
    for (int n = 0; n < 4; ++n) bfr[n] = *(const bf16x8*)&Bs[wc*64 + n*16 + lm][kg*8];
#pragma unroll
    for (int m = 0; m < 4; ++m)
#pragma unroll
      for (int n = 0; n < 4; ++n)
        acc[m][n] = mfma16x16x32(af[m], bfr[n], acc[m][n]);
    __syncthreads();
  }
#pragma unroll
  for (int m = 0; m < 4; ++m) {
    const int row0 = bm0 + wr*64 + m*16 + kg*4;
#pragma unroll
    for (int n = 0; n < 4; ++n) {
      const int col = bn0 + wc*64 + n*16 + lm;
#pragma unroll
      for (int q = 0; q < 4; ++q)
        Cout[(size_t)(row0 + q) * C_ + col] = tobf(acc[m][n][q]);
    }
  }
}

// ------- batched epilogue GEMMs: kk-sum / w-finalize / a-sigmoid / g --------
// all M=4096, N=1024; K per z; epi: 2=bf16 raw, 4=sigmoid, 5=w-finalize,
// 6=kk-sum (adds kin elementwise -> k+kkadd)
struct Ep4Args {
  const bf16* A[4]; const bf16* Bt[4]; bf16* Cout[4];
  int K[4]; int epi[4];
  const float* aux[4];          // z1: tdec, z2: aaaaa
  const bf16* kin; bf16* ksout; // kb unscaled in; z1 writes scaled k
};
__global__ __launch_bounds__(256) void gemm128_ep4(Ep4Args ea) {
  __shared__ bf16 As[128][32];
  __shared__ bf16 Bs[128][32];
  const int z = blockIdx.z;
  const bf16* __restrict__ A  = ea.A[z];
  const bf16* __restrict__ Bt = ea.Bt[z];
  bf16* __restrict__ Cout = ea.Cout[z];
  const int K = ea.K[z], epi = ea.epi[z];
  const float* __restrict__ aux = ea.aux[z];
  const int bm0 = blockIdx.x * 128, bn0 = blockIdx.y * 128;
  const int tid = threadIdx.x, wv = tid >> 6, ln = tid & 63;
  const int wr = wv >> 1, wc = wv & 1;
  const int lm = ln & 15, kg = ln >> 4;
  const int srow = ln >> 2, scol = (ln & 3) * 8;
  f32x4 acc[4][4] = {};
  for (int k0 = 0; k0 < K; k0 += 32) {
#pragma unroll
    for (int i = 0; i < 2; ++i) {
      const int r0 = wv*32 + i*16;
      gload16(A  + (size_t)(bm0 + r0 + srow) * K + k0 + scol, &As[r0][0]);
      gload16(Bt + (size_t)(bn0 + r0 + srow) * K + k0 + scol, &Bs[r0][0]);
    }
    asm volatile("s_waitcnt vmcnt(0)" ::: "memory");
    __syncthreads();
    bf16x8 af[4], bfr[4];
#pragma unroll
    for (int m = 0; m < 4; ++m) af[m] = *(const bf16x8*)&As[wr*64 + m*16 + lm][kg*8];
#pragma unroll
    for (int n = 0; n < 4; ++n) bfr[n] = *(const bf16x8*)&Bs[wc*64 + n*16 + lm][kg*8];
#pragma unroll
    for (int m = 0; m < 4; ++m)
#pragma unroll
      for (int n = 0; n < 4; ++n)
        acc[m][n] = mfma16x16x32(af[m], bfr[n], acc[m][n]);
    __syncthreads();
  }
#pragma unroll
  for (int m = 0; m < 4; ++m) {
    const int row0 = bm0 + wr*64 + m*16 + kg*4;
#pragma unroll
    for (int n = 0; n < 4; ++n) {
      const int col = bn0 + wc*64 + n*16 + lm;
#pragma unroll
      for (int q = 0; q < 4; ++q) {
        float val = acc[m][n][q];
        size_t o = (size_t)(row0 + q) * C_ + col;
        if (epi == 2) {
          Cout[o] = tobf(val);
        } else if (epi == 6) {          // kk-sum: k + kkadd
          Cout[o] = tobf(val + frombf(ea.kin[o]));
        } else if (epi == 4) {
          float zz = aux[col] + val;
          Cout[o] = tobf(2.f / (1.f + __expf(-zz)));
        } else {  // epi == 5: w-finalize (fast transcendentals)
          float wr2 = val + aux[col];
          float sp = fmaxf(-wr2, 0.f) + __logf(1.f + __expf(-fabsf(wr2)));
          float w = -sp - 0.5f;
          Cout[o] = tobf(-__expf(w));                                  // lw
          ea.ksout[o] = tobf(frombf(ea.kin[o]) * __expf(fminf(0.5f*w, 0.f)));
        }
      }
    }
  }
}

// --------- fused 6-branch low-rank projection + combine (x staged ONCE) -----
struct Mix6Args { const float* maa[6]; bf16* out[6]; };

__global__ __launch_bounds__(256) void mix_combine(
    const bf16* __restrict__ mixb, const bf16* __restrict__ w2t,
    const bf16* __restrict__ xb, Mix6Args ma)
{
  __shared__ short As[64][40];
  __shared__ short Bs[64][40];
  __shared__ bf16 Xt[65][72];   // rows bm0-1 .. bm0+63, cols bn0..+63
  const int bm0 = blockIdx.x * 64, bn0 = blockIdx.y * 64;
  const int tid = threadIdx.x, wave = tid >> 6, lane = tid & 63;
  const int lm = lane & 15, kg = lane >> 4;
  const int srow = tid >> 2, scol = (tid & 3) * 8;
  // stage x tile once (65 rows x 64 cols, 4 bf16 per load)
  for (int i = tid; i < 65*16; i += 256) {
    const int row = i >> 4, c4 = (i & 15) * 4;
    int gr = bm0 - 1 + row; if (gr < 0) gr = 0;   // row -1 only when bm0==0 (unused)
    *(uint2*)&Xt[row][c4] = *(const uint2*)(xb + (size_t)gr * C_ + bn0 + c4);
  }
  const int row0 = bm0 + wave*16 + kg*4;
  const int col0 = bn0 + lm;
  for (int s6 = 0; s6 < 6; ++s6) {
    __syncthreads();   // Xt ready (iter 0); prior MFMA reads of As/Bs done
    *(uint4*)&As[srow][scol] =
        *(const uint4*)(mixb + s6*32 + (size_t)(bm0 + srow)*192 + scol);
    *(uint4*)&Bs[srow][scol] =
        *(const uint4*)(w2t + (size_t)s6*C_*32 + (size_t)(bn0 + srow)*32 + scol);
    __syncthreads();
    bf16x8 af = *(const bf16x8*)&As[wave*16 + lm][kg*8];
    f32x4 acc[4] = {};
#pragma unroll
    for (int f = 0; f < 4; ++f) {
      bf16x8 bfr = *(const bf16x8*)&Bs[f*16 + lm][kg*8];
      acc[f] = mfma16x16x32(af, bfr, acc[f]);
    }
    const float* __restrict__ maa = ma.maa[s6];
    bf16* __restrict__ out = ma.out[s6];
#pragma unroll
    for (int f = 0; f < 4; ++f) {
#pragma unroll
      for (int q = 0; q < 4; ++q) {
        const int row = row0 + q, col = col0 + f*16;
        const int lr = row - bm0, lc = col - bn0;
        float xv = frombf(Xt[lr + 1][lc]);
        float xp = ((row & (T_ - 1)) == 0) ? 0.f : frombf(Xt[lr][lc]);
        out[(size_t)row * C_ + col] = tobf(xv + (xp - xv) * (maa[col] + acc[f][q]));
      }
    }
  }
}

// ---------------- elementwise ----------------------------------------------
__global__ __launch_bounds__(256) void xin_k(
    const float* __restrict__ x, const float* __restrict__ maa_x,
    bf16* __restrict__ xinb, bf16* __restrict__ xb)
{
  size_t idx = (size_t)blockIdx.x * 256 + threadIdx.x;
  int c = idx & (C_ - 1);
  int t = (int)((idx >> 10) & (T_ - 1));
  float xv = x[idx];
  float xp = t ? x[idx - C_] : 0.f;
  xinb[idx] = tobf(xv + (xp - xv) * maa_x[c]);
  xb[idx] = tobf(xv);
}

// kk = sum / max(||sum||_2 over C, 1e-12), sum precomputed (epi 6)
__global__ __launch_bounds__(256) void kk_normalize(
    const bf16* __restrict__ ksum, bf16* __restrict__ kkout)
{
  const int bt = blockIdx.x;
  const int tid = threadIdx.x;
  const size_t o = (size_t)bt * C_;
  float vals[4]; float ss = 0.f;
#pragma unroll
  for (int q = 0; q < 4; ++q) {
    float u = frombf(ksum[o + tid + q*256]);
    vals[q] = u; ss += u * u;
  }
  ss = allred64(ss);
  __shared__ float red[4];
  const int wave = tid >> 6, lane = tid & 63;
  if (lane == 0) red[wave] = ss;
  __syncthreads();
  float tot = red[0] + red[1] + red[2] + red[3];
  float inv = 1.f / fmaxf(sqrtf(tot), 1e-12f);
#pragma unroll
  for (int q = 0; q < 4; ++q) kkout[o + tid + q*256] = tobf(vals[q] * inv);
}

// ============ Chunked RWKV-7 scan (fp32 recurrence, bf16 MFMA phases) =======
//   SA = (I-trilA)^{-1}(Achk S0^T + trilC V) = W S0^T + SA_loc
//   y[s] = rt_s S0^T + tril<=(ABy) SA + tril<=(CKy) V
//   S_L = S0 * M + U  with M = diag(dL) + (W^T Bt).*dL_j
// LDS 40.7 KB -> 4 blocks/CU. All 6 input streams register-prefetched at
// kernel entry so HBM latency overlaps the cumsum phase.

__global__ __launch_bounds__(256, 4) void rwkv_chunk_pre(
    const bf16* __restrict__ rr, const bf16* __restrict__ lw,
    const bf16* __restrict__ kk_s, const bf16* __restrict__ kkv,
    const bf16* __restrict__ aam, const bf16* __restrict__ vv,
    bf16* __restrict__ wbufb, bf16* __restrict__ sabufb,
    bf16* __restrict__ abybufb, bf16* __restrict__ ckybufb,
    bf16* __restrict__ ubufP, bf16* __restrict__ mbufT)
{
  __shared__ bf16 Amb[LCH][34], Cmb[LCH][34];
  __shared__ float wtot[4][64];
  __shared__ float lcl[64];
  __shared__ float dll[64];
  __shared__ bf16 bTb[LCH][72], kTb[LCH][72];
  __shared__ bf16 bTT[64][40], kTT[64][40], vLT[64][40];
  __shared__ bf16 uni[5120];   // {aCb,rCb}[32][72] | {WT,SAT}[64][40]
  bf16 (*aCb)[72] = (bf16(*)[72])uni;
  bf16 (*rCb)[72] = (bf16(*)[72])(uni + 2304);
  bf16 (*WT)[40]  = (bf16(*)[40])uni;
  bf16 (*SAT)[40] = (bf16(*)[40])(uni + 2560);

  const int ch = blockIdx.x;
  const int c  = ch & (NCH - 1);
  const int bh = ch >> 6;
  const int b  = bh >> 4, h = bh & 15;
  const int tid = threadIdx.x, wv = tid >> 6, ln = tid & 63;
  const int lm = ln & 15, kg = ln >> 4;
  const size_t base = ((size_t)(b*T_ + c*LCH) * C_) + h*N_ + ln;

  // --- prefetch ALL inputs to registers (overlap latency with cumsum) ------
  bf16 pKK[8], pAA[8], pKS[8], pRR[8], pVV[8];
  float lwr[8];
#pragma unroll
  for (int q = 0; q < 8; ++q) {
    const size_t off = base + (size_t)(wv*8 + q) * C_;
    lwr[q] = frombf(lw[off]);
    pKK[q] = kkv[off];  pAA[q] = aam[off];  pKS[q] = kk_s[off];
    pRR[q] = rr[off];   pVV[q] = vv[off];
  }
  float lcE[8];
  {
    float run = 0.f;
#pragma unroll
    for (int q = 0; q < 8; ++q) { lcE[q] = run; run += lwr[q]; }
    wtot[wv][ln] = run;
  }
  __syncthreads();
  {
    float pre = 0.f;
    for (int w2 = 0; w2 < wv; ++w2) pre += wtot[w2][ln];
    if (wv == 0) lcl[ln] = wtot[0][ln] + wtot[1][ln] + wtot[2][ln] + wtot[3][ln];
#pragma unroll
    for (int q = 0; q < 8; ++q) lcE[q] += pre;
  }
#pragma unroll
  for (int q = 0; q < 8; ++q) {
    const int s = wv*8 + q;
    float kkx = frombf(pKK[q]), aax = frombf(pAA[q]);
    float kx = frombf(pKS[q]), rx = frombf(pRR[q]);
    float lcI = lcE[q] + lwr[q];
    float eIm = __expf(-lcI);
    float eI  = __builtin_amdgcn_rcpf(eIm);   // exp(lcI) = 1/exp(-lcI)
    float av = -kkx * __expf(lcE[q]);
    float bv = kkx * aax * eIm;
    float kv2 = kx * eIm;
    float rv = rx * eI;
    aCb[s][ln] = tobf(av);  rCb[s][ln] = tobf(rv);
    bTb[s][ln] = tobf(bv);  kTb[s][ln] = tobf(kv2);
    bTT[ln][s] = tobf(bv);  kTT[ln][s] = tobf(kv2);  vLT[ln][s] = pVV[q];
  }
  __syncthreads();
  if (tid < 64) dll[tid] = __expf(lcl[tid]);  // barriers below make it visible

  // --- phase 2: MFMA, one 32x32 (K=64) product per wave ---
  {
    const bf16 (*Ab)[72] = (wv < 2) ? aCb : rCb;
    const bf16 (*Bb)[72] = (wv & 1) ? kTb : bTb;
#pragma unroll
    for (int mt = 0; mt < 2; ++mt)
#pragma unroll
      for (int nt = 0; nt < 2; ++nt) {
        f32x4 acc = {};
#pragma unroll
        for (int ks = 0; ks < 2; ++ks) {
          bf16x8 af = *(const bf16x8*)&Ab[mt*16 + lm][ks*32 + kg*8];
          bf16x8 bq = *(const bf16x8*)&Bb[nt*16 + lm][ks*32 + kg*8];
          acc = mfma16x16x32(af, bq, acc);
        }
        const int row0 = mt*16 + kg*4, col = nt*16 + lm;
#pragma unroll
        for (int q = 0; q < 4; ++q) {
          float v = acc[q];
          if (wv == 0)      Amb[row0+q][col] = tobf(v);
          else if (wv == 1) Cmb[row0+q][col] = tobf(v);
          else {
            bf16 bv2 = tobf(col <= row0+q ? v : 0.f);  // tril<= mask
            if (wv == 2) abybufb[(size_t)ch*1024 + (row0+q)*32 + col] = bv2;
            else         ckybufb[(size_t)ch*1024 + (row0+q)*32 + col] = bv2;
          }
        }
      }
  }
  __syncthreads();

  // --- phase 3a: preload solve inputs to registers (aCb/Cmb/vLT reads) -----
  float Xr[32], amr[32];
  if (wv == 0) {
#pragma unroll
    for (int s = 0; s < 32; ++s) amr[s] = frombf(Amb[s][ln & 31]);
#pragma unroll
    for (int s = 0; s < 32; ++s) Xr[s] = frombf(aCb[s][ln]);
  } else if (wv == 1) {
    float cmr[32];
#pragma unroll
    for (int s = 0; s < 32; ++s) {
      amr[s] = frombf(Amb[s][ln & 31]);
      cmr[s] = frombf(Cmb[s][ln & 31]);
    }
#pragma unroll
    for (int s = 0; s < 32; ++s) Xr[s] = 0.f;
#pragma unroll
    for (int u = 0; u < 31; ++u) {
      float v = frombf(vLT[ln][u]);   // == V[u][ln]
#pragma unroll
      for (int s = u + 1; s < 32; ++s) Xr[s] += rdlane(cmr[s], u) * v;
    }
  }
  __syncthreads();   // aCb reads complete before WT/SAT writes into alias

  // --- phase 3b: register forward-substitution; write WT/SAT --------------
  if (wv < 2) {
#pragma unroll
    for (int s = 1; s < 32; ++s) {
      float acc = Xr[s];
#pragma unroll
      for (int u = 0; u < s; ++u) acc += rdlane(amr[s], u) * Xr[u];
      Xr[s] = acc;
    }
    if (wv == 0) {
#pragma unroll
      for (int s = 0; s < 32; ++s) {
        bf16 bv = tobf(Xr[s]);
        WT[ln][s] = bv;
        wbufb[(size_t)ch*2048 + s*64 + ln] = bv;
      }
    } else {
#pragma unroll
      for (int s = 0; s < 32; ++s) {
        bf16 bv = tobf(Xr[s]);
        SAT[ln][s] = bv;
        sabufb[(size_t)ch*2048 + s*64 + ln] = bv;
      }
    }
  }
  __syncthreads();

  // --- phase 5: U, M (64x64, K=32) via MFMA; packed-layout b64 stores ------
  {
    const int mt = wv;
    bf16x8 aS = *(const bf16x8*)&SAT[mt*16 + lm][kg*8];
    bf16x8 aV = *(const bf16x8*)&vLT[mt*16 + lm][kg*8];
    bf16x8 aW = *(const bf16x8*)&WT[mt*16 + lm][kg*8];
#pragma unroll
    for (int nt = 0; nt < 4; ++nt) {
      bf16x8 bB = *(const bf16x8*)&bTT[nt*16 + lm][kg*8];
      bf16x8 bK = *(const bf16x8*)&kTT[nt*16 + lm][kg*8];
      f32x4 aU = {}, aG = {};
      aU = mfma16x16x32(aS, bB, aU);
      aU = mfma16x16x32(aV, bK, aU);
      aG = mfma16x16x32(aW, bB, aG);
      const int i0r = mt*16 + kg*4, col = nt*16 + lm;
      float dl = dll[col];
      uint2 up;
      up.x = (unsigned int)bfbits(aU[0]*dl) | ((unsigned int)bfbits(aU[1]*dl) << 16);
      up.y = (unsigned int)bfbits(aU[2]*dl) | ((unsigned int)bfbits(aU[3]*dl) << 16);
      *(uint2*)(ubufP + (size_t)ch*4096 + (mt*4 + nt)*256 + ln*4) = up;
      float m0 = (aG[0] + (i0r+0 == col ? 1.f : 0.f)) * dl;
      float m1 = (aG[1] + (i0r+1 == col ? 1.f : 0.f)) * dl;
      float m2 = (aG[2] + (i0r+2 == col ? 1.f : 0.f)) * dl;
      float m3 = (aG[3] + (i0r+3 == col ? 1.f : 0.f)) * dl;
      uint2 mp;
      mp.x = (unsigned int)bfbits(m0) | ((unsigned int)bfbits(m1) << 16);
      mp.y = (unsigned int)bfbits(m2) | ((unsigned int)bfbits(m3) << 16);
      const int laned = (((mt*2) + (kg >> 1)) & 3) * 16 + lm;
      *(uint2*)(mbufT + (size_t)ch*4096 + (nt*2 + (mt >> 1))*512
                + laned*8 + (kg & 1)*4) = mp;
    }
  }
}

// Phase B: serial over chunks; 32 blocks (one per bh) x 4 waves, no barriers.
__global__ __launch_bounds__(256) void rwkv_chunk_state(
    const bf16* __restrict__ mbufT, const bf16* __restrict__ ubufP,
    bf16* __restrict__ s0bufb)
{
  __shared__ bf16 Sst[4][16][72];
  const int bh = blockIdx.x;
  const int tid = threadIdx.x, wv = tid >> 6, ln = tid & 63;
  const int lm = ln & 15, kg = ln >> 4;

#pragma unroll
  for (int r = 0; r < 16; ++r) {
    Sst[wv][r][ln] = tobf(0.f);
    if (ln < 8) Sst[wv][r][64 + ln] = tobf(0.f);
  }

  bf16x8 BfA[4][2], BfB[4][2];
  uint2 UpA[4], UpB[4];
  auto prefetch = [&](bf16x8 (&Bf)[4][2], uint2 (&Up)[4], int c) {
    const size_t chp = (size_t)(bh*NCH + c) * 4096;
#pragma unroll
    for (int nt = 0; nt < 4; ++nt) {
      Bf[nt][0] = *(const bf16x8*)(mbufT + chp + (nt*2 + 0)*512 + ln*8);
      Bf[nt][1] = *(const bf16x8*)(mbufT + chp + (nt*2 + 1)*512 + ln*8);
      Up[nt]    = *(const uint2*) (ubufP + chp + (wv*4 + nt)*256 + ln*4);
    }
  };
  prefetch(BfA, UpA, 0);
  prefetch(BfB, UpB, 1);

  auto body = [&](bf16x8 (&Bf)[4][2], uint2 (&Up)[4], int c) {
    const size_t ch4 = (size_t)(bh*NCH + c) * 4096;
    const int sr = ln >> 2, sc = (ln & 3) * 16;
    uint4 v0 = *(const uint4*)&Sst[wv][sr][sc];
    uint4 v1 = *(const uint4*)&Sst[wv][sr][sc + 8];
    *(uint4*)(s0bufb + ch4 + (size_t)(wv*16 + sr)*64 + sc) = v0;
    *(uint4*)(s0bufb + ch4 + (size_t)(wv*16 + sr)*64 + sc + 8) = v1;
    bf16x8 A0 = *(const bf16x8*)&Sst[wv][lm][kg*8];
    bf16x8 A1 = *(const bf16x8*)&Sst[wv][lm][32 + kg*8];
    f32x4 acc[4];
#pragma unroll
    for (int nt = 0; nt < 4; ++nt) {
      acc[nt][0] = bf2f((unsigned short)(Up[nt].x & 0xffff));
      acc[nt][1] = bf2f((unsigned short)(Up[nt].x >> 16));
      acc[nt][2] = bf2f((unsigned short)(Up[nt].y & 0xffff));
      acc[nt][3] = bf2f((unsigned short)(Up[nt].y >> 16));
      acc[nt] = mfma16x16x32(A0, Bf[nt][0], acc[nt]);
      acc[nt] = mfma16x16x32(A1, Bf[nt][1], acc[nt]);
    }
    int cp = c + 2; if (cp > NCH - 1) cp = NCH - 1;
    prefetch(Bf, Up, cp);
#pragma unroll
    for (int nt = 0; nt < 4; ++nt)
#pragma unroll
      for (int q = 0; q < 4; ++q)
        Sst[wv][kg*4 + q][nt*16 + lm] = tobf(acc[nt][q]);
  };

  for (int cc = 0; cc < NCH; cc += 2) {
    body(BfA, UpA, cc);
    body(BfB, UpB, cc + 1);
  }
}

// Phase C: per chunk-head: SA = W*S0^T + SAll; y = Rt*S0^T + ABl*SAo + CKl*V;
// then FUSED groupnorm (group == head, size 64) + bonus + gate -> zb (bf16).
__global__ __launch_bounds__(256, 4) void rwkv_chunk_out(
    const bf16* __restrict__ rr, const bf16* __restrict__ lw,
    const bf16* __restrict__ vv, const bf16* __restrict__ kks,
    const bf16* __restrict__ gg, const bf16* __restrict__ s0bufb,
    const bf16* __restrict__ wbufb, const bf16* __restrict__ sabufb,
    const bf16* __restrict__ abybufb, const bf16* __restrict__ ckybufb,
    const float* __restrict__ faaaa, const float* __restrict__ lnw,
    const float* __restrict__ lnb, bf16* __restrict__ zb)
{
  __shared__ bf16 S0b[64][72];                    // B^T layout: [i][j]
  __shared__ bf16 ABl[LCH][40], CKl[LCH][40];     // A layouts: [s][u]
  __shared__ bf16 SAot[64][40], VlT[64][40];      // B^T layouts: [i][u]
  __shared__ float wtot[4][64];
  __shared__ float bonus[LCH];
  __shared__ float uni2f[2304];  // {Wb,Rlb}[32][72] bf16 | Yl[32][68] f32
  bf16 (*Wb)[72]  = (bf16(*)[72])uni2f;
  bf16 (*Rlb)[72] = (bf16(*)[72])((bf16*)uni2f + 2304);
  float (*Yl)[68] = (float(*)[68])uni2f;

  const int ch = blockIdx.x;
  const int c = ch & (NCH - 1), bh = ch >> 6, b = bh >> 4, h = bh & 15;
  const int tid = threadIdx.x, wv = tid >> 6, ln = tid & 63;
  const int lm = ln & 15, kg = ln >> 4;
  const size_t base = ((size_t)(b*T_ + c*LCH) * C_) + h*N_ + ln;

  // --- prefetch rr/vv/kks rows to registers (overlap with cumsum) ----------
  bf16 pRR[8], pVV[8], pKS[8];
  float lwr[8];
#pragma unroll
  for (int q = 0; q < 8; ++q) {
    const size_t off = base + (size_t)(wv*8 + q) * C_;
    lwr[q] = frombf(lw[off]);
    pRR[q] = rr[off];  pVV[q] = vv[off];  pKS[q] = kks[off];
  }
  float lcE[8];
  {
    float run = 0.f;
#pragma unroll
    for (int q = 0; q < 8; ++q) { lcE[q] = run; run += lwr[q]; }
    wtot[wv][ln] = run;
  }
  __syncthreads();
  {
    float pre = 0.f;
    for (int w2 = 0; w2 < wv; ++w2) pre += wtot[w2][ln];
#pragma unroll
    for (int q = 0; q < 8; ++q) lcE[q] += pre;
  }
  const float fa = faaaa[h*N_ + ln];
#pragma unroll
  for (int q = 0; q < 8; ++q) {
    const int s = wv*8 + q;
    float rf = frombf(pRR[q]);
    Rlb[s][ln] = tobf(rf * __expf(lcE[q] + lwr[q]));
    VlT[ln][s] = pVV[q];
    float rk = allred64(rf * frombf(pKS[q]) * fa);   // bonus dot
    if (ln == 0) bonus[s] = rk;
  }
#pragma unroll
  for (int t = 0; t < 2; ++t) {
    int cc2 = tid*2 + t; int ri = cc2 >> 3, co = (cc2 & 7) * 8;
    *(uint4*)&S0b[ri][co] = *(const uint4*)(s0bufb + (size_t)ch*4096 + ri*64 + co);
  }
  { int ri = tid >> 3, co = (tid & 7) * 8;
    *(uint4*)&Wb[ri][co] = *(const uint4*)(wbufb + (size_t)ch*2048 + ri*64 + co); }
  if (tid < 128) {
    int ri = tid >> 2, co = (tid & 3) * 8;
    *(uint4*)&ABl[ri][co] = *(const uint4*)(abybufb + (size_t)ch*1024 + ri*32 + co);
  } else {
    int t2 = tid - 128; int ri = t2 >> 2, co = (t2 & 3) * 8;
    *(uint4*)&CKl[ri][co] = *(const uint4*)(ckybufb + (size_t)ch*1024 + ri*32 + co);
  }
  __syncthreads();

  const int mt = wv >> 1, ntb = (wv & 1) * 2;
#pragma unroll
  for (int t = 0; t < 2; ++t) {
    const int nt = ntb + t;
    const int row0 = mt*16 + kg*4, col = nt*16 + lm;
    f32x4 acc;
#pragma unroll
    for (int q = 0; q < 4; ++q)
      acc[q] = frombf(sabufb[(size_t)ch*2048 + (row0+q)*64 + col]);
#pragma unroll
    for (int ks = 0; ks < 2; ++ks) {
      bf16x8 af = *(const bf16x8*)&Wb[mt*16 + lm][ks*32 + kg*8];
      bf16x8 bq = *(const bf16x8*)&S0b[nt*16 + lm][ks*32 + kg*8];
      acc = mfma16x16x32(af, bq, acc);
    }
#pragma unroll
    for (int q = 0; q < 4; ++q) SAot[col][row0+q] = tobf(acc[q]);
  }
  __syncthreads();

  f32x4 yacc[2];
#pragma unroll
  for (int t = 0; t < 2; ++t) {
    const int nt = ntb + t;
    f32x4 acc = {};
#pragma unroll
    for (int ks = 0; ks < 2; ++ks) {
      bf16x8 af = *(const bf16x8*)&Rlb[mt*16 + lm][ks*32 + kg*8];
      bf16x8 bq = *(const bf16x8*)&S0b[nt*16 + lm][ks*32 + kg*8];
      acc = mfma16x16x32(af, bq, acc);
    }
    {
      bf16x8 af = *(const bf16x8*)&ABl[mt*16 + lm][kg*8];
      bf16x8 bq = *(const bf16x8*)&SAot[nt*16 + lm][kg*8];
      acc = mfma16x16x32(af, bq, acc);
    }
    {
      bf16x8 af = *(const bf16x8*)&CKl[mt*16 + lm][kg*8];
      bf16x8 bq = *(const bf16x8*)&VlT[nt*16 + lm][kg*8];
      acc = mfma16x16x32(af, bq, acc);
    }
    yacc[t] = acc;
  }
  __syncthreads();   // all Rlb reads done before Yl overwrites the alias

#pragma unroll
  for (int t = 0; t < 2; ++t) {
    const int nt = ntb + t;
    const int row0 = mt*16 + kg*4, col = nt*16 + lm;
#pragma unroll
    for (int q = 0; q < 4; ++q) Yl[row0 + q][col] = yacc[t][q];
  }
  __syncthreads();

  // fused groupnorm + bonus + gate: thread = (row s2, 8 cols)
  {
    const int s2 = tid >> 3, c0 = (tid & 7) * 8;
    float yv[8]; float sum = 0.f;
#pragma unroll
    for (int i = 0; i < 8; ++i) { yv[i] = Yl[s2][c0 + i]; sum += yv[i]; }
#pragma unroll
    for (int m = 1; m < 8; m <<= 1) sum += __shfl_xor(sum, m, 64);
    const float mean = sum * (1.f/64.f);
    float ss = 0.f;
#pragma unroll
    for (int i = 0; i < 8; ++i) { float d = yv[i] - mean; ss += d * d; }
#pragma unroll
    for (int m = 1; m < 8; m <<= 1) ss += __shfl_xor(ss, m, 64);
    const float inv = rsqrtf(ss * (1.f/64.f) + 6.4e-4f);
    const float bn = bonus[s2];
    const size_t trow = (size_t)(b*T_ + c*LCH + s2) * C_ + h*N_ + c0;
    bf16 zout[8];
#pragma unroll
    for (int i = 0; i < 8; ++i) {
      float gn = (yv[i] - mean) * inv * lnw[h*N_ + c0 + i] + lnb[h*N_ + c0 + i];
      float z = (gn + bn * frombf(VlT[c0 + i][s2])) * frombf(gg[trow + i]);
      zout[i] = tobf(z);
    }
    *(uint4*)(zb + trow) = *(const uint4*)&zout[0];
  }
}

// ---------------- driver ----------------------------------------------------
extern "C" void kernel_launch(void* const* d_in, const int* in_sizes, int n_in,
                              void* d_out, int out_size, void* d_ws, size_t ws_size,
                              hipStream_t stream)
{
  const float* x     = (const float*)d_in[0];
  const float* maa_x = (const float*)d_in[1];
  const float* maa_r = (const float*)d_in[2];
  const float* maa_w = (const float*)d_in[3];
  const float* maa_k = (const float*)d_in[4];
  const float* maa_v = (const float*)d_in[5];
  const float* maa_a = (const float*)d_in[6];
  const float* maa_g = (const float*)d_in[7];
  const float* tdec  = (const float*)d_in[8];
  const float* faaaa = (const float*)d_in[9];
  const float* aaaaa = (const float*)d_in[10];
  const float* maa_w1= (const float*)d_in[11];
  const float* maa_w2= (const float*)d_in[12];
  const float* dec_w1= (const float*)d_in[13];
  const float* dec_w2= (const float*)d_in[14];
  const float* aaa_w1= (const float*)d_in[15];
  const float* aaa_w2= (const float*)d_in[16];
  const float* kkk_w1= (const float*)d_in[17];
  const float* kkk_w2= (const float*)d_in[18];
  const float* gate_w1=(const float*)d_in[19];
  const float* gate_w2=(const float*)d_in[20];
  const float* W_r   = (const float*)d_in[21];
  const float* W_k   = (const float*)d_in[22];
  const float* W_v   = (const float*)d_in[23];
  const float* W_o   = (const float*)d_in[24];
  const float* lnw   = (const float*)d_in[25];
  const float* lnb   = (const float*)d_in[26];

  char* ws = (char*)d_ws;
  size_t cur = 0;
  auto alloc = [&](size_t bytes) -> void* {
    void* p = ws + cur; cur += (bytes + 255) & ~(size_t)255; return p;
  };
  const size_t HBT = (size_t)BT_ * C_ * 2;  // bf16 activation buffer

  // ---- persistent (activations bf16) ----
  bf16* rb   = (bf16*)alloc(HBT);
  bf16* kb   = (bf16*)alloc(HBT);   // UNscaled k
  bf16* ksb  = (bf16*)alloc(HBT);   // scaled k (for scan + bonus)
  bf16* vb   = (bf16*)alloc(HBT);
  bf16* gbb  = (bf16*)alloc(HBT);
  bf16* WtR  = (bf16*)alloc((size_t)C_*C_*2);
  bf16* WtK  = (bf16*)alloc((size_t)C_*C_*2);
  bf16* WtV  = (bf16*)alloc((size_t)C_*C_*2);
  bf16* WtO  = (bf16*)alloc((size_t)C_*C_*2);
  bf16* w1t  = (bf16*)alloc((size_t)192*C_*2);
  bf16* w2t  = (bf16*)alloc((size_t)6*C_*32*2);
  bf16* d1t  = (bf16*)alloc((size_t)64*C_*2);
  bf16* d2t  = (bf16*)alloc((size_t)C_*64*2);
  bf16* a1t  = (bf16*)alloc((size_t)64*C_*2);
  bf16* a2t  = (bf16*)alloc((size_t)C_*64*2);
  bf16* k1t  = (bf16*)alloc((size_t)64*C_*2);
  bf16* k2t  = (bf16*)alloc((size_t)C_*64*2);
  bf16* g1t  = (bf16*)alloc((size_t)128*C_*2);
  bf16* g2t  = (bf16*)alloc((size_t)C_*128*2);
  bf16* lwb  = (bf16*)alloc(HBT);
  bf16* kkb  = (bf16*)alloc(HBT);
  bf16* aamt = (bf16*)alloc(HBT);
  bf16* s0bufb = kkb;                 // overlay: kkb+aamt dead after chunk_pre

  // ---- union region ----
  const size_t ubase = cur;
  bf16* mtmpb = (bf16*)alloc(HBT);
  bf16* xinb = (bf16*)alloc(HBT);
  bf16* xb   = (bf16*)alloc(HBT);
  bf16* mixb = (bf16*)alloc((size_t)BT_*192*2);
  bf16* xbr[6];
  for (int s = 0; s < 6; ++s) xbr[s] = (bf16*)alloc(HBT);
  bf16* h64k = (bf16*)alloc((size_t)BT_*64*2);
  bf16* h64d = (bf16*)alloc((size_t)BT_*64*2);
  bf16* h64a = (bf16*)alloc((size_t)BT_*64*2);
  bf16* h128b= (bf16*)alloc((size_t)BT_*128*2);
  const size_t tmp_end = cur;
  cur = ubase;  // overlay
  bf16*  wbufb   = (bf16*)alloc((size_t)CHD*2048*2);
  bf16*  sabufb  = (bf16*)alloc((size_t)CHD*2048*2);
  bf16*  abybufb = (bf16*)alloc((size_t)CHD*1024*2);
  bf16*  ckybufb = (bf16*)alloc((size_t)CHD*1024*2);
  bf16*  ubufP   = (bf16*)alloc((size_t)CHD*4096*2);
  bf16*  mbufT   = (bf16*)alloc((size_t)CHD*4096*2);
  bf16*  zb      = (bf16*)ubufP;   // alias: ubufP dead after chunk_state
  if (tmp_end > cur) cur = tmp_end;
  const size_t need = cur;
  (void)in_sizes; (void)n_in; (void)out_size;

  if (ws_size < need) {
    ws_diag<<<1, 1, 0, stream>>>((float)ws_size, (float)need, (float*)d_out);
    return;
  }

  PrepArgs pa;
  pa.src[0] = W_r;  pa.dst[0] = WtR;
  pa.src[1] = W_k;  pa.dst[1] = WtK;
  pa.src[2] = W_v;  pa.dst[2] = WtV;
  pa.src[3] = W_o;  pa.dst[3] = WtO;
  pa.src[4] = maa_w1; pa.dst[4] = w1t;
  for (int s = 0; s < 6; ++s) { pa.src[5+s] = maa_w2 + (size_t)s*32*C_; pa.dst[5+s] = w2t + (size_t)s*C_*32; }
  pa.src[11] = dec_w1; pa.dst[11] = d1t;
  pa.src[12] = dec_w2; pa.dst[12] = d2t;
  pa.src[13] = aaa_w1; pa.dst[13] = a1t;
  pa.src[14] = aaa_w2; pa.dst[14] = a2t;
  pa.src[15] = kkk_w1; pa.dst[15] = k1t;
  pa.src[16] = kkk_w2; pa.dst[16] = k2t;
  pa.src[17] = gate_w1; pa.dst[17] = g1t;
  pa.src[18] = gate_w2; pa.dst[18] = g2t;
  prep_weights<<<dim3(1024, 19), 256, 0, stream>>>(pa);

  const int EW_GRID = (BT_ * C_) / 256;  // 16384
  xin_k<<<EW_GRID, 256, 0, stream>>>(x, maa_x, xinb, xb);

  gemm_bt<1><<<dim3(64, 3), 256, 0, stream>>>(xinb, C_, w1t, C_, mixb, 192, C_);

  Mix6Args ma;
  ma.maa[0] = maa_r; ma.maa[1] = maa_w; ma.maa[2] = maa_k;
  ma.maa[3] = maa_v; ma.maa[4] = maa_a; ma.maa[5] = maa_g;
  for (int s = 0; s < 6; ++s) ma.out[s] = xbr[s];
  mix_combine<<<dim3(64, 16), 256, 0, stream>>>(mixb, w2t, xb, ma);

  // r, k, v batched (one launch, bf16 out)
  RkvArgs ra;
  ra.A[0] = xbr[0]; ra.Bt[0] = WtR; ra.Cq[0] = rb;
  ra.A[1] = xbr[2]; ra.Bt[1] = WtK; ra.Cq[1] = kb;
  ra.A[2] = xbr[3]; ra.Bt[2] = WtV; ra.Cq[2] = vb;
  gemm128_rkv<<<dim3(32, 8, 3), 256, 0, stream>>>(ra);

  // batched small projections: k1 (tanh), d1 (tanh), a1 (raw), g1 (tanh)
  Proj4Args p4;
  p4.A[0] = xbr[2]; p4.Bt[0] = k1t; p4.out[0] = h64k; p4.N[0] = 64;  p4.tnh[0] = 1;
  p4.A[1] = xbr[1]; p4.Bt[1] = d1t; p4.out[1] = h64d; p4.N[1] = 64;  p4.tnh[1] = 1;
  p4.A[2] = xbr[4]; p4.Bt[2] = a1t; p4.out[2] = h64a; p4.N[2] = 64;  p4.tnh[2] = 0;
  p4.A[3] = xbr[5]; p4.Bt[3] = g1t; p4.out[3] = h128b; p4.N[3] = 128; p4.tnh[3] = 1;
  proj4<<<dim3(64, 2, 4), 256, 0, stream>>>(p4);

  // batched epilogue GEMMs: z0 kk-SUM (k+kkadd), z1 w-finalize, z2 a, z3 g
  Ep4Args ea;
  ea.A[0] = h64k;  ea.Bt[0] = k2t; ea.Cout[0] = mtmpb; ea.K[0] = 64;  ea.epi[0] = 6; ea.aux[0] = nullptr;
  ea.A[1] = h64d;  ea.Bt[1] = d2t; ea.Cout[1] = lwb;   ea.K[1] = 64;  ea.epi[1] = 5; ea.aux[1] = tdec;
  ea.A[2] = h64a;  ea.Bt[2] = a2t; ea.Cout[2] = aamt;  ea.K[2] = 64;  ea.epi[2] = 4; ea.aux[2] = aaaaa;
  ea.A[3] = h128b; ea.Bt[3] = g2t; ea.Cout[3] = gbb;   ea.K[3] = 128; ea.epi[3] = 2; ea.aux[3] = nullptr;
  ea.kin = kb; ea.ksout = ksb;
  gemm128_ep4<<<dim3(32, 8, 4), 256, 0, stream>>>(ea);

  kk_normalize<<<BT_, 256, 0, stream>>>(mtmpb, kkb);

  // ---- chunked scan (scaled k = ksb) ----
  rwkv_chunk_pre<<<CHD, 256, 0, stream>>>(rb, lwb, ksb, kkb, aamt, vb,
      wbufb, sabufb, abybufb, ckybufb, ubufP, mbufT);
  rwkv_chunk_state<<<32, 256, 0, stream>>>(mbufT, ubufP, s0bufb);
  rwkv_chunk_out<<<CHD, 256, 0, stream>>>(rb, lwb, vb, ksb, gbb, s0bufb,
      wbufb, sabufb, abybufb, ckybufb, faaaa, lnw, lnb, zb);

  gemm128<0><<<dim3(32, 8), 256, 0, stream>>>(zb, C_, WtO, C_, d_out, C_, C_);
}